// Round 7
// baseline (944.649 us; speedup 1.0000x reference)
//
#include <hip/hip_runtime.h>
#include <math.h>

#define N_NODES 50000
#define N_EDGES 1600000
#define DIM_IN  128
#define DIM_HID 64
#define NHEADS  8
#define HDIM    (NHEADS*DIM_HID)   // 512
#define DIM_OUT 128
#define SMBLK   1024               // blocks for scatter+max1 pass
#define MAXBLK  512                // blocks for max2 pass
#define LDK     72                 // padded LDS row (bf16 elems)
#define INV_N   2e-5f              // 1/N_NODES

typedef __attribute__((ext_vector_type(2))) unsigned short us2;
typedef __attribute__((ext_vector_type(4))) unsigned short us4;
typedef __attribute__((ext_vector_type(8))) unsigned short us8;
typedef __attribute__((ext_vector_type(8))) short bf16x8;
typedef __attribute__((ext_vector_type(4))) float f32x4;

__device__ __forceinline__ float leaky(float x) { return x >= 0.f ? x : 0.2f * x; }
__device__ __forceinline__ float bf2f(unsigned short h) {
  return __uint_as_float(((unsigned)h) << 16);
}
__device__ __forceinline__ unsigned short f2bf(float f) {
  unsigned u = __float_as_uint(f);
  unsigned r = (u + 0x7fffu + ((u >> 16) & 1u)) >> 16;
  return (unsigned short)r;
}
__device__ __forceinline__ float bn_scale(float sum, float sq, float g) {
  float mean = sum * INV_N;
  float var = sq * INV_N - mean * mean;
  return g * rsqrtf(var + 1e-5f);
}

// ---------- fused prep: cvt feat->bf16 | pack W_heads | pack W_res ----------
__global__ void prep_kernel(const float* __restrict__ feat, const float* __restrict__ Wh,
                            const float* __restrict__ Wres,
                            unsigned short* __restrict__ feat_bf,
                            unsigned short* __restrict__ Bt1,
                            unsigned short* __restrict__ Btr) {
  int b = blockIdx.x;
  if (b < 6250) {
    int i = b * 256 + threadIdx.x;
    float4 v = *reinterpret_cast<const float4*>(&feat[(size_t)i * 4]);
    us4 o;
    o[0] = f2bf(v.x); o[1] = f2bf(v.y); o[2] = f2bf(v.z); o[3] = f2bf(v.w);
    *reinterpret_cast<us4*>(&feat_bf[(size_t)i * 4]) = o;
  } else if (b < 6506) {
    int idx = (b - 6250) * 256 + threadIdx.x;
    int n = idx >> 7, k = idx & 127;
    Bt1[idx] = f2bf(Wh[(n >> 6) * (DIM_IN * DIM_HID) + k * DIM_HID + (n & 63)]);
  } else {
    int idx = (b - 6506) * 256 + threadIdx.x;
    int n = idx >> 7, k = idx & 127;
    Btr[idx] = f2bf(Wres[k * DIM_OUT + n]);
  }
}

// ---------- fold BN1 (inline from stats) into W_out -> Bt2 [128][512] bf16 ----------
__global__ void foldw2_kernel(const float* __restrict__ W,
                              const float* __restrict__ colsum, const float* __restrict__ colsq,
                              const float* __restrict__ gamma,
                              unsigned short* __restrict__ Bt) {
  int idx = blockIdx.x * 256 + threadIdx.x;
  if (idx >= DIM_OUT * HDIM) return;
  int n = idx >> 9, k = idx & 511;
  float sc = bn_scale(colsum[k], colsq[k], gamma[k]);
  Bt[idx] = f2bf(W[k * DIM_OUT + n] * sc);
}

// ---------- bias2 = shift1^T @ W_out (shift computed inline) ----------
__global__ void bias2_kernel(const float* __restrict__ W,
                             const float* __restrict__ colsum, const float* __restrict__ colsq,
                             const float* __restrict__ gamma, const float* __restrict__ beta,
                             float* __restrict__ bias2) {
  int j = threadIdx.x;
  if (j >= DIM_OUT) return;
  float s = 0.f;
  for (int c = 0; c < HDIM; ++c) {
    float mean = colsum[c] * INV_N;
    float sc = bn_scale(colsum[c], colsq[c], gamma[c]);
    float shift = beta[c] - mean * sc;
    s = fmaf(shift, W[c * DIM_OUT + j], s);
  }
  bias2[j] = s;
}

// ---------- bf16 MFMA GEMM: C[M,N] = A[M,K] @ Bt[N,K]^T (+bias) ----------
template<int OUTBF>
__global__ __launch_bounds__(256) void gemm_mfma(
    const unsigned short* __restrict__ A, const unsigned short* __restrict__ Bt,
    void* __restrict__ Cout, const float* __restrict__ bias,
    int M, int N, int K) {
  __shared__ unsigned short As[128 * LDK];
  __shared__ unsigned short Bs[128 * LDK];
  const int tid = threadIdx.x;
  const int lane = tid & 63, wid = tid >> 6;
  const int wr = wid >> 1, wc = wid & 1;
  const int l15 = lane & 15, lhi = lane >> 4;
  const int m0 = blockIdx.y * 128, n0 = blockIdx.x * 128;
  const int srow = tid >> 3;
  const int sc8 = (tid - srow) & 7;
  f32x4 acc[4][4];
#pragma unroll
  for (int i = 0; i < 4; ++i)
#pragma unroll
    for (int j = 0; j < 4; ++j) acc[i][j] = f32x4{0.f, 0.f, 0.f, 0.f};

  for (int k0 = 0; k0 < K; k0 += 64) {
    __syncthreads();
#pragma unroll
    for (int p = 0; p < 4; ++p) {
      int row = p * 32 + srow;
      us8 va = {0, 0, 0, 0, 0, 0, 0, 0};
      int gr = m0 + row;
      if (gr < M) va = *reinterpret_cast<const us8*>(&A[(size_t)gr * K + k0 + sc8 * 8]);
      *reinterpret_cast<us8*>(&As[row * LDK + sc8 * 8]) = va;
      us8 vb = {0, 0, 0, 0, 0, 0, 0, 0};
      int gn = n0 + row;
      if (gn < N) vb = *reinterpret_cast<const us8*>(&Bt[(size_t)gn * K + k0 + sc8 * 8]);
      *reinterpret_cast<us8*>(&Bs[row * LDK + sc8 * 8]) = vb;
    }
    __syncthreads();
#pragma unroll
    for (int kk = 0; kk < 2; ++kk) {
      bf16x8 af[4], bfr[4];
#pragma unroll
      for (int i = 0; i < 4; ++i)
        af[i] = *reinterpret_cast<const bf16x8*>(&As[(wr * 64 + i * 16 + l15) * LDK + kk * 32 + lhi * 8]);
#pragma unroll
      for (int j = 0; j < 4; ++j)
        bfr[j] = *reinterpret_cast<const bf16x8*>(&Bs[(wc * 64 + j * 16 + l15) * LDK + kk * 32 + lhi * 8]);
#pragma unroll
      for (int i = 0; i < 4; ++i)
#pragma unroll
        for (int j = 0; j < 4; ++j)
          acc[i][j] = __builtin_amdgcn_mfma_f32_16x16x32_bf16(af[i], bfr[j], acc[i][j], 0, 0, 0);
    }
  }
#pragma unroll
  for (int j = 0; j < 4; ++j) {
    int col = n0 + wc * 64 + j * 16 + l15;
    float bb = bias ? bias[col] : 0.f;
#pragma unroll
    for (int i = 0; i < 4; ++i) {
      f32x4 v = acc[i][j];
#pragma unroll
      for (int t = 0; t < 4; ++t) {
        int row = m0 + wr * 64 + i * 16 + lhi * 4 + t;
        if (row < M) {
          float o = v[t] + bb;
          if (OUTBF) ((unsigned short*)Cout)[(size_t)row * N + col] = f2bf(o);
          else       ((float*)Cout)[(size_t)row * N + col] = o;
        }
      }
    }
  }
}

// ---------- attn projections layer 1 (bf16 msg) ----------
__global__ __launch_bounds__(256) void attn1_kernel(
    const unsigned short* __restrict__ msg, const float* __restrict__ a_heads,
    float* __restrict__ asrc, float* __restrict__ adst, int Nn) {
  int lane = threadIdx.x & 63;
  int n = blockIdx.x * 4 + (threadIdx.x >> 6);
  if (n >= Nn) return;
  us8 v = *reinterpret_cast<const us8*>(&msg[(size_t)n * HDIM + lane * 8]);
  int h = lane >> 3, p0 = (lane & 7) * 8;
  float s = 0.f, d = 0.f;
#pragma unroll
  for (int j = 0; j < 8; ++j) {
    float f = bf2f(v[j]);
    s = fmaf(f, a_heads[h * 128 + p0 + j], s);
    d = fmaf(f, a_heads[h * 128 + 64 + p0 + j], d);
  }
  s += __shfl_xor(s, 1, 64); s += __shfl_xor(s, 2, 64); s += __shfl_xor(s, 4, 64);
  d += __shfl_xor(d, 1, 64); d += __shfl_xor(d, 2, 64); d += __shfl_xor(d, 4, 64);
  if ((lane & 7) == 0) { asrc[n * 8 + h] = s; adst[n * 8 + h] = d; }
}

// ---------- attn projections layer 2 (bf16 msg) ----------
__global__ __launch_bounds__(256) void attn2_kernel(
    const unsigned short* __restrict__ msg, const float* __restrict__ a_out,
    float* __restrict__ asrc, float* __restrict__ adst, int Nn) {
  int lane = threadIdx.x & 63;
  int n = blockIdx.x * 4 + (threadIdx.x >> 6);
  if (n >= Nn) return;
  us2 v = *reinterpret_cast<const us2*>(&msg[(size_t)n * 128 + lane * 2]);
  float f0 = bf2f(v[0]), f1 = bf2f(v[1]);
  float s = f0 * a_out[2 * lane] + f1 * a_out[2 * lane + 1];
  float d = f0 * a_out[128 + 2 * lane] + f1 * a_out[128 + 2 * lane + 1];
#pragma unroll
  for (int off = 32; off; off >>= 1) {
    s += __shfl_xor(s, off, 64);
    d += __shfl_xor(d, off, 64);
  }
  if (lane == 0) { asrc[n] = s; adst[n] = d; }
}

// ---------- CSR: histogram ----------
__global__ void hist_kernel(const int* __restrict__ edst, int* __restrict__ counts, int E) {
  for (int e = blockIdx.x * blockDim.x + threadIdx.x; e < E; e += gridDim.x * blockDim.x)
    atomicAdd(&counts[edst[e]], 1);
}

// ---------- CSR: 3-phase scan ----------
__global__ __launch_bounds__(256) void scan1_kernel(
    const int* __restrict__ counts, int* __restrict__ rowptr, int* __restrict__ bsum, int n) {
  __shared__ int wsum[4];
  int b0 = blockIdx.x * 1024;
  int t = threadIdx.x;
  int lane = t & 63, w = t >> 6;
  int v[4]; int s = 0;
#pragma unroll
  for (int i = 0; i < 4; ++i) {
    int idx = b0 + t * 4 + i;
    v[i] = (idx < n) ? counts[idx] : 0;
    s += v[i];
  }
  int x = s;
#pragma unroll
  for (int off = 1; off < 64; off <<= 1) {
    int y = __shfl_up(x, off, 64);
    if (lane >= off) x += y;
  }
  if (lane == 63) wsum[w] = x;
  __syncthreads();
  int wof = 0;
  for (int i = 0; i < w; ++i) wof += wsum[i];
  int run = wof + x - s;
#pragma unroll
  for (int i = 0; i < 4; ++i) {
    int idx = b0 + t * 4 + i;
    if (idx < n) rowptr[idx] = run;
    run += v[i];
  }
  if (t == 255) bsum[blockIdx.x] = wof + x;
}

__global__ void scan2_kernel(int* __restrict__ bsum, int nb) {
  int t = threadIdx.x;
  int v = (t < nb) ? bsum[t] : 0;
  int x = v;
#pragma unroll
  for (int off = 1; off < 64; off <<= 1) {
    int y = __shfl_up(x, off, 64);
    if (t >= off) x += y;
  }
  if (t < nb) bsum[t] = x - v;
}

__global__ void scan3_kernel(int* __restrict__ rowptr, const int* __restrict__ bsum, int n) {
  int i = blockIdx.x * 256 + threadIdx.x;
  if (i < n) rowptr[i] += bsum[i >> 10];
  else if (i == n) rowptr[n] = N_EDGES;
}

// ---------- fused scatter + layer-1 max partials ----------
__global__ __launch_bounds__(256) void scatter_max1_kernel(
    const int* __restrict__ esrc, const int* __restrict__ edst,
    const float* __restrict__ asrc, const float* __restrict__ adst,
    const int* __restrict__ rowptr, int* __restrict__ cursor,
    int* __restrict__ colsrc, float* __restrict__ part, int E) {
  float m[8];
#pragma unroll
  for (int h = 0; h < 8; ++h) m[h] = -3.4e38f;
  for (int e = blockIdx.x * blockDim.x + threadIdx.x; e < E; e += gridDim.x * blockDim.x) {
    int s = esrc[e], d = edst[e];
    int pos = rowptr[d] + atomicAdd(&cursor[d], 1);
    colsrc[pos] = s;
    float4 s0 = *reinterpret_cast<const float4*>(&asrc[(size_t)s * 8]);
    float4 s1 = *reinterpret_cast<const float4*>(&asrc[(size_t)s * 8 + 4]);
    float4 d0 = *reinterpret_cast<const float4*>(&adst[(size_t)d * 8]);
    float4 d1 = *reinterpret_cast<const float4*>(&adst[(size_t)d * 8 + 4]);
    float xs[8] = {s0.x + d0.x, s0.y + d0.y, s0.z + d0.z, s0.w + d0.w,
                   s1.x + d1.x, s1.y + d1.y, s1.z + d1.z, s1.w + d1.w};
#pragma unroll
    for (int h = 0; h < 8; ++h) m[h] = fmaxf(m[h], leaky(xs[h]));
  }
#pragma unroll
  for (int h = 0; h < 8; ++h)
#pragma unroll
    for (int off = 32; off; off >>= 1) m[h] = fmaxf(m[h], __shfl_xor(m[h], off, 64));
  __shared__ float sm[4][8];
  int wv = threadIdx.x >> 6, ln = threadIdx.x & 63;
  if (ln == 0)
#pragma unroll
    for (int h = 0; h < 8; ++h) sm[wv][h] = m[h];
  __syncthreads();
  if (threadIdx.x < 8) {
    int h = threadIdx.x;
    part[blockIdx.x * 8 + h] =
        fmaxf(fmaxf(sm[0][h], sm[1][h]), fmaxf(sm[2][h], sm[3][h]));
  }
}

__global__ void max1_final_kernel(const float* __restrict__ part, float* __restrict__ maxv, int nblk) {
  int t = threadIdx.x;
  int h = t & 7, k = t >> 3;
  float m = -3.4e38f;
  for (int i = k; i < nblk; i += 8) m = fmaxf(m, part[i * 8 + h]);
  m = fmaxf(m, __shfl_xor(m, 8, 64));
  m = fmaxf(m, __shfl_xor(m, 16, 64));
  m = fmaxf(m, __shfl_xor(m, 32, 64));
  if (t < 8) maxv[t] = m;
}

// ---------- layer-2 max, two-stage ----------
__global__ __launch_bounds__(256) void max2_part_kernel(
    const int* __restrict__ esrc, const int* __restrict__ edst,
    const float* __restrict__ asrc, const float* __restrict__ adst,
    float* __restrict__ part, int E) {
  float m = -3.4e38f;
  for (int e = blockIdx.x * blockDim.x + threadIdx.x; e < E; e += gridDim.x * blockDim.x) {
    float x = asrc[esrc[e]] + adst[edst[e]];
    m = fmaxf(m, leaky(x));
  }
#pragma unroll
  for (int off = 32; off; off >>= 1) m = fmaxf(m, __shfl_xor(m, off, 64));
  __shared__ float sm[4];
  int wv = threadIdx.x >> 6, ln = threadIdx.x & 63;
  if (ln == 0) sm[wv] = m;
  __syncthreads();
  if (threadIdx.x == 0)
    part[blockIdx.x] = fmaxf(fmaxf(sm[0], sm[1]), fmaxf(sm[2], sm[3]));
}

__global__ void max2_final_kernel(const float* __restrict__ part, float* __restrict__ maxv, int nblk) {
  int t = threadIdx.x;
  float m = -3.4e38f;
  for (int i = t; i < nblk; i += 64) m = fmaxf(m, part[i]);
#pragma unroll
  for (int off = 32; off; off >>= 1) m = fmaxf(m, __shfl_xor(m, off, 64));
  if (t == 0) maxv[0] = m;
}

// ---------- layer-1 aggregation (R4 structure: block-per-node, LDS coef, unroll 4) ----------
__global__ __launch_bounds__(128) void agg1_kernel(
    const unsigned short* __restrict__ msg, const float* __restrict__ asrc,
    const float* __restrict__ adst, const float* __restrict__ maxv,
    const int* __restrict__ rowptr, const int* __restrict__ colsrc,
    unsigned short* __restrict__ out, int nbase) {
  int n = nbase + blockIdx.x;
  int tid = threadIdx.x;
  __shared__ int s_sh[64];
  __shared__ float coef_sh[64][8];
  __shared__ float hdr[16];
  if (tid < 8) {
    hdr[tid] = maxv[tid];
    hdr[8 + tid] = adst[(size_t)n * 8 + tid];
  }
  __syncthreads();
  const int h = tid >> 4;
  const int e0 = rowptr[n], e1 = rowptr[n + 1];
  float4 acc = make_float4(0.f, 0.f, 0.f, 0.f);
  float dsum = 0.f;
  for (int base = e0; base < e1; base += 64) {
    int cnt = min(64, e1 - base);
    __syncthreads();
#pragma unroll
    for (int q = 0; q < 4; ++q) {
      int slot = q * 128 + tid;
      int el = slot >> 3, hh = slot & 7;
      if (el < cnt) {
        int s = colsrc[base + el];
        if (hh == 0) s_sh[el] = s;
        float x = asrc[(size_t)s * 8 + hh] + hdr[8 + hh];
        x = x >= 0.f ? x : 0.2f * x;
        coef_sh[el][hh] = __expf(x - hdr[hh]);
      }
    }
    __syncthreads();
    int e = 0;
    for (; e + 4 <= cnt; e += 4) {
      int sA = s_sh[e], sB = s_sh[e + 1], sC = s_sh[e + 2], sD = s_sh[e + 3];
      us4 ma = *reinterpret_cast<const us4*>(&msg[(size_t)sA * HDIM + tid * 4]);
      us4 mb = *reinterpret_cast<const us4*>(&msg[(size_t)sB * HDIM + tid * 4]);
      us4 mc = *reinterpret_cast<const us4*>(&msg[(size_t)sC * HDIM + tid * 4]);
      us4 md = *reinterpret_cast<const us4*>(&msg[(size_t)sD * HDIM + tid * 4]);
      float ca = coef_sh[e][h], cb = coef_sh[e + 1][h];
      float cc = coef_sh[e + 2][h], cd = coef_sh[e + 3][h];
      dsum += (ca + cb) + (cc + cd);
      acc.x = fmaf(bf2f(ma[0]), ca, acc.x); acc.y = fmaf(bf2f(ma[1]), ca, acc.y);
      acc.z = fmaf(bf2f(ma[2]), ca, acc.z); acc.w = fmaf(bf2f(ma[3]), ca, acc.w);
      acc.x = fmaf(bf2f(mb[0]), cb, acc.x); acc.y = fmaf(bf2f(mb[1]), cb, acc.y);
      acc.z = fmaf(bf2f(mb[2]), cb, acc.z); acc.w = fmaf(bf2f(mb[3]), cb, acc.w);
      acc.x = fmaf(bf2f(mc[0]), cc, acc.x); acc.y = fmaf(bf2f(mc[1]), cc, acc.y);
      acc.z = fmaf(bf2f(mc[2]), cc, acc.z); acc.w = fmaf(bf2f(mc[3]), cc, acc.w);
      acc.x = fmaf(bf2f(md[0]), cd, acc.x); acc.y = fmaf(bf2f(md[1]), cd, acc.y);
      acc.z = fmaf(bf2f(md[2]), cd, acc.z); acc.w = fmaf(bf2f(md[3]), cd, acc.w);
    }
    for (; e < cnt; ++e) {
      int s = s_sh[e];
      float c = coef_sh[e][h];
      dsum += c;
      us4 m4 = *reinterpret_cast<const us4*>(&msg[(size_t)s * HDIM + tid * 4]);
      acc.x = fmaf(bf2f(m4[0]), c, acc.x); acc.y = fmaf(bf2f(m4[1]), c, acc.y);
      acc.z = fmaf(bf2f(m4[2]), c, acc.z); acc.w = fmaf(bf2f(m4[3]), c, acc.w);
    }
  }
  float inv = 1.0f / (dsum + 1e-10f);
  us4 o;
  o[0] = f2bf(acc.x * inv); o[1] = f2bf(acc.y * inv);
  o[2] = f2bf(acc.z * inv); o[3] = f2bf(acc.w * inv);
  *reinterpret_cast<us4*>(&out[(size_t)n * HDIM + tid * 4]) = o;
}

// ---------- layer-2 aggregation: wave-per-node, shfl-broadcast coefs, unroll 4 ----------
__global__ __launch_bounds__(256) void agg2_kernel(
    const unsigned short* __restrict__ msg, const float* __restrict__ asrc,
    const float* __restrict__ adst, const float* __restrict__ maxv,
    const int* __restrict__ rowptr, const int* __restrict__ colsrc,
    float* __restrict__ out) {
  int wv = threadIdx.x >> 6, ln = threadIdx.x & 63;
  int n = blockIdx.x * 4 + wv;
  float M = maxv[0];
  float ad = adst[n];
  int e0 = rowptr[n], e1 = rowptr[n + 1];
  float a0 = 0.f, a1 = 0.f, ds = 0.f;
  for (int base = e0; base < e1; base += 64) {
    int cnt = min(64, e1 - base);
    int s_reg = 0; float c_reg = 0.f;
    if (ln < cnt) {
      s_reg = colsrc[base + ln];
      float x = asrc[s_reg] + ad;
      x = x >= 0.f ? x : 0.2f * x;
      c_reg = __expf(x - M);
    }
    int e = 0;
    for (; e + 4 <= cnt; e += 4) {
      int s0 = __shfl(s_reg, e, 64),     s1 = __shfl(s_reg, e + 1, 64);
      int s2 = __shfl(s_reg, e + 2, 64), s3 = __shfl(s_reg, e + 3, 64);
      float c0 = __shfl(c_reg, e, 64),     c1 = __shfl(c_reg, e + 1, 64);
      float c2 = __shfl(c_reg, e + 2, 64), c3 = __shfl(c_reg, e + 3, 64);
      us2 m0 = *reinterpret_cast<const us2*>(&msg[(size_t)s0 * 128 + 2 * ln]);
      us2 m1 = *reinterpret_cast<const us2*>(&msg[(size_t)s1 * 128 + 2 * ln]);
      us2 m2 = *reinterpret_cast<const us2*>(&msg[(size_t)s2 * 128 + 2 * ln]);
      us2 m3 = *reinterpret_cast<const us2*>(&msg[(size_t)s3 * 128 + 2 * ln]);
      ds += (c0 + c1) + (c2 + c3);
      a0 = fmaf(bf2f(m0[0]), c0, a0); a1 = fmaf(bf2f(m0[1]), c0, a1);
      a0 = fmaf(bf2f(m1[0]), c1, a0); a1 = fmaf(bf2f(m1[1]), c1, a1);
      a0 = fmaf(bf2f(m2[0]), c2, a0); a1 = fmaf(bf2f(m2[1]), c2, a1);
      a0 = fmaf(bf2f(m3[0]), c3, a0); a1 = fmaf(bf2f(m3[1]), c3, a1);
    }
    for (; e < cnt; ++e) {
      int s = __shfl(s_reg, e, 64);
      float c = __shfl(c_reg, e, 64);
      us2 m = *reinterpret_cast<const us2*>(&msg[(size_t)s * 128 + 2 * ln]);
      ds += c;
      a0 = fmaf(bf2f(m[0]), c, a0);
      a1 = fmaf(bf2f(m[1]), c, a1);
    }
  }
  float inv = 1.0f / (ds + 1e-10f);
  float2 r; r.x = a0 * inv; r.y = a1 * inv;
  *reinterpret_cast<float2*>(&out[(size_t)n * 128 + 2 * ln]) = r;
}

// ---------- BN statistics ----------
__global__ void colstats_kernel(const float* __restrict__ X, float* __restrict__ sums,
                                float* __restrict__ sqs, int M, int C, int rowsPerBlock) {
  int c = blockIdx.x * blockDim.x + threadIdx.x;
  if (c >= C) return;
  int r0 = blockIdx.y * rowsPerBlock;
  int r1 = min(M, r0 + rowsPerBlock);
  float s = 0.f, s2 = 0.f;
  for (int r = r0; r < r1; ++r) {
    float v = X[(size_t)r * C + c];
    s += v; s2 = fmaf(v, v, s2);
  }
  atomicAdd(&sums[c], s);
  atomicAdd(&sqs[c], s2);
}

__global__ void colstats_bf_kernel(const unsigned short* __restrict__ X, float* __restrict__ sums,
                                   float* __restrict__ sqs, int M, int C, int rowsPerBlock) {
  int c = blockIdx.x * blockDim.x + threadIdx.x;
  if (c >= C) return;
  int r0 = blockIdx.y * rowsPerBlock;
  int r1 = min(M, r0 + rowsPerBlock);
  float s = 0.f, s2 = 0.f;
  for (int r = r0; r < r1; ++r) {
    float v = bf2f(X[(size_t)r * C + c]);
    s += v; s2 = fmaf(v, v, s2);
  }
  atomicAdd(&sums[c], s);
  atomicAdd(&sqs[c], s2);
}

// ---------- final: BN(out2) (inline stats) + residual ----------
__global__ void final_kernel(float* __restrict__ out, const float* __restrict__ resid,
                             const float* __restrict__ colsum, const float* __restrict__ colsq,
                             const float* __restrict__ gamma, const float* __restrict__ beta,
                             int total) {
  for (int i = blockIdx.x * blockDim.x + threadIdx.x; i < total; i += gridDim.x * blockDim.x) {
    int c = i & 127;
    float mean = colsum[c] * INV_N;
    float sc = bn_scale(colsum[c], colsq[c], gamma[c]);
    float sh = beta[c] - mean * sc;
    out[i] = fmaf(out[i], sc, sh) + resid[i];
  }
}

// ==================== host ====================
extern "C" void kernel_launch(void* const* d_in, const int* in_sizes, int n_in,
                              void* d_out, int out_size, void* d_ws, size_t ws_size,
                              hipStream_t stream) {
  const float* feat    = (const float*)d_in[0];
  const int*   edges   = (const int*)d_in[1];
  const int*   esrc    = edges;
  const int*   edst    = edges + N_EDGES;
  const float* W_heads = (const float*)d_in[2];
  const float* a_heads = (const float*)d_in[3];
  const float* gamma_h = (const float*)d_in[4];
  const float* beta_h  = (const float*)d_in[5];
  const float* W_out   = (const float*)d_in[6];
  const float* a_out   = (const float*)d_in[7];
  const float* gamma_o = (const float*)d_in[8];
  const float* beta_o  = (const float*)d_in[9];
  const float* W_res   = (const float*)d_in[10];
  const float* b_res   = (const float*)d_in[11];
  float* out = (float*)d_out;

  char* ws = (char*)d_ws;
  size_t off = 0;
  auto alloc = [&](size_t bytes) {
    void* p = ws + off;
    off = (off + bytes + 255) & ~(size_t)255;
    return p;
  };
  unsigned short* msg1    = (unsigned short*)alloc((size_t)N_NODES * HDIM * 2);  // reused as msg2
  unsigned short* out1_bf = (unsigned short*)alloc((size_t)N_NODES * HDIM * 2);
  unsigned short* feat_bf = (unsigned short*)alloc((size_t)N_NODES * DIM_IN * 2);
  float*    resid  = (float*)alloc((size_t)N_NODES * DIM_OUT * 4);
  float*    asrc1  = (float*)alloc((size_t)N_NODES * NHEADS * 4); // reused as asrc2
  float*    adst1  = (float*)alloc((size_t)N_NODES * NHEADS * 4); // reused as adst2
  int*      counts = (int*)alloc((size_t)N_NODES * 4);
  int*      cursor = (int*)alloc((size_t)N_NODES * 4);   // adjacent to counts
  int*      rowptr = (int*)alloc((size_t)(N_NODES + 1) * 4);
  int*      colsrc = (int*)alloc((size_t)N_EDGES * 4);
  int*      bsum   = (int*)alloc(64 * 4);
  float*    part   = (float*)alloc((size_t)SMBLK * 8 * 4);
  float*    maxv1  = (float*)alloc(8 * 4);
  float*    maxv2  = (float*)alloc(4);
  float*    colsum = (float*)alloc(HDIM * 4);
  float*    colsq  = (float*)alloc(HDIM * 4);   // adjacent to colsum (2048B each, 256-aligned)
  unsigned short* Bt1 = (unsigned short*)alloc((size_t)HDIM * DIM_IN * 2);
  unsigned short* Bt2 = (unsigned short*)alloc((size_t)DIM_OUT * HDIM * 2);
  unsigned short* Btr = (unsigned short*)alloc((size_t)DIM_OUT * DIM_IN * 2);
  float*    bias2  = (float*)alloc(DIM_OUT * 4);
  unsigned short* msg2 = msg1;
  float* asrc2 = asrc1; float* adst2 = adst1;
  (void)n_in; (void)in_sizes; (void)out_size; (void)ws_size;

  // merged zero-init: counts+cursor contiguous; colsum+colsq contiguous
  hipMemsetAsync(counts, 0, (char*)rowptr - (char*)counts, stream);
  hipMemsetAsync(colsum, 0, 4096, stream);

  // ---- prep (cvt + packs fused) ----
  prep_kernel<<<6570, 256, 0, stream>>>(feat, W_heads, W_res, feat_bf, Bt1, Btr);

  // ---- layer 1 ----
  dim3 g1(HDIM / 128, (N_NODES + 127) / 128);
  gemm_mfma<1><<<g1, 256, 0, stream>>>(feat_bf, Bt1, msg1, nullptr, N_NODES, HDIM, DIM_IN);
  attn1_kernel<<<(N_NODES + 3) / 4, 256, 0, stream>>>(msg1, a_heads, asrc1, adst1, N_NODES);

  hist_kernel<<<2048, 256, 0, stream>>>(edst, counts, N_EDGES);
  int nsb = (N_NODES + 1023) / 1024;   // 49
  scan1_kernel<<<nsb, 256, 0, stream>>>(counts, rowptr, bsum, N_NODES);
  scan2_kernel<<<1, 64, 0, stream>>>(bsum, nsb);
  scan3_kernel<<<(N_NODES + 256) / 256, 256, 0, stream>>>(rowptr, bsum, N_NODES);

  scatter_max1_kernel<<<SMBLK, 256, 0, stream>>>(esrc, edst, asrc1, adst1, rowptr,
                                                 cursor, colsrc, part, N_EDGES);
  max1_final_kernel<<<1, 64, 0, stream>>>(part, maxv1, SMBLK);
  for (int q = 0; q < 4; ++q)
    agg1_kernel<<<N_NODES / 4, 128, 0, stream>>>(msg1, asrc1, adst1, maxv1, rowptr, colsrc,
                                                 out1_bf, q * (N_NODES / 4));

  colstats_bf_kernel<<<dim3(HDIM / 128, 98), 128, 0, stream>>>(out1_bf, colsum, colsq, N_NODES, HDIM, 512);
  foldw2_kernel<<<(DIM_OUT * HDIM + 255) / 256, 256, 0, stream>>>(W_out, colsum, colsq, gamma_h, Bt2);
  bias2_kernel<<<1, 128, 0, stream>>>(W_out, colsum, colsq, gamma_h, beta_h, bias2);

  // ---- layer 2 ----
  dim3 g2(DIM_OUT / 128, (N_NODES + 127) / 128);
  gemm_mfma<1><<<g2, 256, 0, stream>>>(out1_bf, Bt2, msg2, bias2, N_NODES, DIM_OUT, HDIM);
  attn2_kernel<<<(N_NODES + 3) / 4, 256, 0, stream>>>(msg2, a_out, asrc2, adst2, N_NODES);

  max2_part_kernel<<<MAXBLK, 256, 0, stream>>>(esrc, edst, asrc2, adst2, part, N_EDGES);
  max2_final_kernel<<<1, 64, 0, stream>>>(part, maxv2, MAXBLK);
  agg2_kernel<<<N_NODES / 4, 256, 0, stream>>>(msg2, asrc2, adst2, maxv2, rowptr, colsrc, out);

  // residual GEMM (bf16 MFMA, fp32 out)
  gemm_mfma<0><<<g2, 256, 0, stream>>>(feat_bf, Btr, resid, b_res, N_NODES, DIM_OUT, DIM_IN);

  // layer-2 BN stats + fused BN+residual epilogue
  hipMemsetAsync(colsum, 0, 4096, stream);
  colstats_kernel<<<dim3(1, 98), 128, 0, stream>>>(out, colsum, colsq, N_NODES, DIM_OUT, 512);
  final_kernel<<<2048, 256, 0, stream>>>(out, resid, colsum, colsq, gamma_o, beta_o,
                                         N_NODES * DIM_OUT);
}

// Round 8
// 796.276 us; speedup vs baseline: 1.1863x; 1.1863x over previous
//
#include <hip/hip_runtime.h>
#include <math.h>

#define N_NODES 50000
#define N_EDGES 1600000
#define DIM_IN  128
#define DIM_HID 64
#define NHEADS  8
#define HDIM    (NHEADS*DIM_HID)   // 512
#define DIM_OUT 128
#define SMBLK   1024               // blocks for scatter+max1 pass
#define MAXBLK  512                // blocks for max2 pass
#define LDK     72                 // padded LDS row (bf16 elems)
#define INV_N   2e-5f              // 1/N_NODES
#define CSBLK   400                // blocks for column-stats kernels

typedef __attribute__((ext_vector_type(2))) unsigned short us2;
typedef __attribute__((ext_vector_type(4))) unsigned short us4;
typedef __attribute__((ext_vector_type(8))) unsigned short us8;
typedef __attribute__((ext_vector_type(8))) short bf16x8;
typedef __attribute__((ext_vector_type(4))) float f32x4;

__device__ __forceinline__ float leaky(float x) { return x >= 0.f ? x : 0.2f * x; }
__device__ __forceinline__ float bf2f(unsigned short h) {
  return __uint_as_float(((unsigned)h) << 16);
}
__device__ __forceinline__ unsigned short f2bf(float f) {
  unsigned u = __float_as_uint(f);
  unsigned r = (u + 0x7fffu + ((u >> 16) & 1u)) >> 16;
  return (unsigned short)r;
}
__device__ __forceinline__ float bn_scale(float sum, float sq, float g) {
  float mean = sum * INV_N;
  float var = sq * INV_N - mean * mean;
  return g * rsqrtf(var + 1e-5f);
}

// ---------- fused prep: cvt feat->bf16 | pack W_heads | pack W_res ----------
__global__ void prep_kernel(const float* __restrict__ feat, const float* __restrict__ Wh,
                            const float* __restrict__ Wres,
                            unsigned short* __restrict__ feat_bf,
                            unsigned short* __restrict__ Bt1,
                            unsigned short* __restrict__ Btr) {
  int b = blockIdx.x;
  if (b < 6250) {
    int i = b * 256 + threadIdx.x;
    float4 v = *reinterpret_cast<const float4*>(&feat[(size_t)i * 4]);
    us4 o;
    o[0] = f2bf(v.x); o[1] = f2bf(v.y); o[2] = f2bf(v.z); o[3] = f2bf(v.w);
    *reinterpret_cast<us4*>(&feat_bf[(size_t)i * 4]) = o;
  } else if (b < 6506) {
    int idx = (b - 6250) * 256 + threadIdx.x;
    int n = idx >> 7, k = idx & 127;
    Bt1[idx] = f2bf(Wh[(n >> 6) * (DIM_IN * DIM_HID) + k * DIM_HID + (n & 63)]);
  } else {
    int idx = (b - 6506) * 256 + threadIdx.x;
    int n = idx >> 7, k = idx & 127;
    Btr[idx] = f2bf(Wres[k * DIM_OUT + n]);
  }
}

// ---------- fold BN1 (inline from stats) into W_out -> Bt2 [128][512] bf16 ----------
__global__ void foldw2_kernel(const float* __restrict__ W,
                              const float* __restrict__ colsum, const float* __restrict__ colsq,
                              const float* __restrict__ gamma,
                              unsigned short* __restrict__ Bt) {
  int idx = blockIdx.x * 256 + threadIdx.x;
  if (idx >= DIM_OUT * HDIM) return;
  int n = idx >> 9, k = idx & 511;
  float sc = bn_scale(colsum[k], colsq[k], gamma[k]);
  Bt[idx] = f2bf(W[k * DIM_OUT + n] * sc);
}

// ---------- bias2 = shift1^T @ W_out (shift computed inline) ----------
__global__ void bias2_kernel(const float* __restrict__ W,
                             const float* __restrict__ colsum, const float* __restrict__ colsq,
                             const float* __restrict__ gamma, const float* __restrict__ beta,
                             float* __restrict__ bias2) {
  int j = threadIdx.x;
  if (j >= DIM_OUT) return;
  float s = 0.f;
  for (int c = 0; c < HDIM; ++c) {
    float mean = colsum[c] * INV_N;
    float sc = bn_scale(colsum[c], colsq[c], gamma[c]);
    float shift = beta[c] - mean * sc;
    s = fmaf(shift, W[c * DIM_OUT + j], s);
  }
  bias2[j] = s;
}

// ---------- bf16 MFMA GEMM: C[M,N] = A[M,K] @ Bt[N,K]^T (+bias) ----------
template<int OUTBF>
__global__ __launch_bounds__(256) void gemm_mfma(
    const unsigned short* __restrict__ A, const unsigned short* __restrict__ Bt,
    void* __restrict__ Cout, const float* __restrict__ bias,
    int M, int N, int K) {
  __shared__ unsigned short As[128 * LDK];
  __shared__ unsigned short Bs[128 * LDK];
  const int tid = threadIdx.x;
  const int lane = tid & 63, wid = tid >> 6;
  const int wr = wid >> 1, wc = wid & 1;
  const int l15 = lane & 15, lhi = lane >> 4;
  const int m0 = blockIdx.y * 128, n0 = blockIdx.x * 128;
  const int srow = tid >> 3;
  const int sc8 = (tid - srow) & 7;
  f32x4 acc[4][4];
#pragma unroll
  for (int i = 0; i < 4; ++i)
#pragma unroll
    for (int j = 0; j < 4; ++j) acc[i][j] = f32x4{0.f, 0.f, 0.f, 0.f};

  for (int k0 = 0; k0 < K; k0 += 64) {
    __syncthreads();
#pragma unroll
    for (int p = 0; p < 4; ++p) {
      int row = p * 32 + srow;
      us8 va = {0, 0, 0, 0, 0, 0, 0, 0};
      int gr = m0 + row;
      if (gr < M) va = *reinterpret_cast<const us8*>(&A[(size_t)gr * K + k0 + sc8 * 8]);
      *reinterpret_cast<us8*>(&As[row * LDK + sc8 * 8]) = va;
      us8 vb = {0, 0, 0, 0, 0, 0, 0, 0};
      int gn = n0 + row;
      if (gn < N) vb = *reinterpret_cast<const us8*>(&Bt[(size_t)gn * K + k0 + sc8 * 8]);
      *reinterpret_cast<us8*>(&Bs[row * LDK + sc8 * 8]) = vb;
    }
    __syncthreads();
#pragma unroll
    for (int kk = 0; kk < 2; ++kk) {
      bf16x8 af[4], bfr[4];
#pragma unroll
      for (int i = 0; i < 4; ++i)
        af[i] = *reinterpret_cast<const bf16x8*>(&As[(wr * 64 + i * 16 + l15) * LDK + kk * 32 + lhi * 8]);
#pragma unroll
      for (int j = 0; j < 4; ++j)
        bfr[j] = *reinterpret_cast<const bf16x8*>(&Bs[(wc * 64 + j * 16 + l15) * LDK + kk * 32 + lhi * 8]);
#pragma unroll
      for (int i = 0; i < 4; ++i)
#pragma unroll
        for (int j = 0; j < 4; ++j)
          acc[i][j] = __builtin_amdgcn_mfma_f32_16x16x32_bf16(af[i], bfr[j], acc[i][j], 0, 0, 0);
    }
  }
#pragma unroll
  for (int j = 0; j < 4; ++j) {
    int col = n0 + wc * 64 + j * 16 + l15;
    float bb = bias ? bias[col] : 0.f;
#pragma unroll
    for (int i = 0; i < 4; ++i) {
      f32x4 v = acc[i][j];
#pragma unroll
      for (int t = 0; t < 4; ++t) {
        int row = m0 + wr * 64 + i * 16 + lhi * 4 + t;
        if (row < M) {
          float o = v[t] + bb;
          if (OUTBF) ((unsigned short*)Cout)[(size_t)row * N + col] = f2bf(o);
          else       ((float*)Cout)[(size_t)row * N + col] = o;
        }
      }
    }
  }
}

// ---------- attn projections layer 1 (bf16 msg) ----------
__global__ __launch_bounds__(256) void attn1_kernel(
    const unsigned short* __restrict__ msg, const float* __restrict__ a_heads,
    float* __restrict__ asrc, float* __restrict__ adst, int Nn) {
  int lane = threadIdx.x & 63;
  int n = blockIdx.x * 4 + (threadIdx.x >> 6);
  if (n >= Nn) return;
  us8 v = *reinterpret_cast<const us8*>(&msg[(size_t)n * HDIM + lane * 8]);
  int h = lane >> 3, p0 = (lane & 7) * 8;
  float s = 0.f, d = 0.f;
#pragma unroll
  for (int j = 0; j < 8; ++j) {
    float f = bf2f(v[j]);
    s = fmaf(f, a_heads[h * 128 + p0 + j], s);
    d = fmaf(f, a_heads[h * 128 + 64 + p0 + j], d);
  }
  s += __shfl_xor(s, 1, 64); s += __shfl_xor(s, 2, 64); s += __shfl_xor(s, 4, 64);
  d += __shfl_xor(d, 1, 64); d += __shfl_xor(d, 2, 64); d += __shfl_xor(d, 4, 64);
  if ((lane & 7) == 0) { asrc[n * 8 + h] = s; adst[n * 8 + h] = d; }
}

// ---------- attn projections layer 2 (bf16 msg) ----------
__global__ __launch_bounds__(256) void attn2_kernel(
    const unsigned short* __restrict__ msg, const float* __restrict__ a_out,
    float* __restrict__ asrc, float* __restrict__ adst, int Nn) {
  int lane = threadIdx.x & 63;
  int n = blockIdx.x * 4 + (threadIdx.x >> 6);
  if (n >= Nn) return;
  us2 v = *reinterpret_cast<const us2*>(&msg[(size_t)n * 128 + lane * 2]);
  float f0 = bf2f(v[0]), f1 = bf2f(v[1]);
  float s = f0 * a_out[2 * lane] + f1 * a_out[2 * lane + 1];
  float d = f0 * a_out[128 + 2 * lane] + f1 * a_out[128 + 2 * lane + 1];
#pragma unroll
  for (int off = 32; off; off >>= 1) {
    s += __shfl_xor(s, off, 64);
    d += __shfl_xor(d, off, 64);
  }
  if (lane == 0) { asrc[n] = s; adst[n] = d; }
}

// ---------- CSR: histogram ----------
__global__ void hist_kernel(const int* __restrict__ edst, int* __restrict__ counts, int E) {
  for (int e = blockIdx.x * blockDim.x + threadIdx.x; e < E; e += gridDim.x * blockDim.x)
    atomicAdd(&counts[edst[e]], 1);
}

// ---------- CSR: 3-phase scan ----------
__global__ __launch_bounds__(256) void scan1_kernel(
    const int* __restrict__ counts, int* __restrict__ rowptr, int* __restrict__ bsum, int n) {
  __shared__ int wsum[4];
  int b0 = blockIdx.x * 1024;
  int t = threadIdx.x;
  int lane = t & 63, w = t >> 6;
  int v[4]; int s = 0;
#pragma unroll
  for (int i = 0; i < 4; ++i) {
    int idx = b0 + t * 4 + i;
    v[i] = (idx < n) ? counts[idx] : 0;
    s += v[i];
  }
  int x = s;
#pragma unroll
  for (int off = 1; off < 64; off <<= 1) {
    int y = __shfl_up(x, off, 64);
    if (lane >= off) x += y;
  }
  if (lane == 63) wsum[w] = x;
  __syncthreads();
  int wof = 0;
  for (int i = 0; i < w; ++i) wof += wsum[i];
  int run = wof + x - s;
#pragma unroll
  for (int i = 0; i < 4; ++i) {
    int idx = b0 + t * 4 + i;
    if (idx < n) rowptr[idx] = run;
    run += v[i];
  }
  if (t == 255) bsum[blockIdx.x] = wof + x;
}

__global__ void scan2_kernel(int* __restrict__ bsum, int nb) {
  int t = threadIdx.x;
  int v = (t < nb) ? bsum[t] : 0;
  int x = v;
#pragma unroll
  for (int off = 1; off < 64; off <<= 1) {
    int y = __shfl_up(x, off, 64);
    if (t >= off) x += y;
  }
  if (t < nb) bsum[t] = x - v;
}

__global__ void scan3_kernel(int* __restrict__ rowptr, const int* __restrict__ bsum, int n) {
  int i = blockIdx.x * 256 + threadIdx.x;
  if (i < n) rowptr[i] += bsum[i >> 10];
  else if (i == n) rowptr[n] = N_EDGES;
}

// ---------- fused scatter + layer-1 max partials ----------
__global__ __launch_bounds__(256) void scatter_max1_kernel(
    const int* __restrict__ esrc, const int* __restrict__ edst,
    const float* __restrict__ asrc, const float* __restrict__ adst,
    const int* __restrict__ rowptr, int* __restrict__ cursor,
    int* __restrict__ colsrc, float* __restrict__ part, int E) {
  float m[8];
#pragma unroll
  for (int h = 0; h < 8; ++h) m[h] = -3.4e38f;
  for (int e = blockIdx.x * blockDim.x + threadIdx.x; e < E; e += gridDim.x * blockDim.x) {
    int s = esrc[e], d = edst[e];
    int pos = rowptr[d] + atomicAdd(&cursor[d], 1);
    colsrc[pos] = s;
    float4 s0 = *reinterpret_cast<const float4*>(&asrc[(size_t)s * 8]);
    float4 s1 = *reinterpret_cast<const float4*>(&asrc[(size_t)s * 8 + 4]);
    float4 d0 = *reinterpret_cast<const float4*>(&adst[(size_t)d * 8]);
    float4 d1 = *reinterpret_cast<const float4*>(&adst[(size_t)d * 8 + 4]);
    float xs[8] = {s0.x + d0.x, s0.y + d0.y, s0.z + d0.z, s0.w + d0.w,
                   s1.x + d1.x, s1.y + d1.y, s1.z + d1.z, s1.w + d1.w};
#pragma unroll
    for (int h = 0; h < 8; ++h) m[h] = fmaxf(m[h], leaky(xs[h]));
  }
#pragma unroll
  for (int h = 0; h < 8; ++h)
#pragma unroll
    for (int off = 32; off; off >>= 1) m[h] = fmaxf(m[h], __shfl_xor(m[h], off, 64));
  __shared__ float sm[4][8];
  int wv = threadIdx.x >> 6, ln = threadIdx.x & 63;
  if (ln == 0)
#pragma unroll
    for (int h = 0; h < 8; ++h) sm[wv][h] = m[h];
  __syncthreads();
  if (threadIdx.x < 8) {
    int h = threadIdx.x;
    part[blockIdx.x * 8 + h] =
        fmaxf(fmaxf(sm[0][h], sm[1][h]), fmaxf(sm[2][h], sm[3][h]));
  }
}

__global__ void max1_final_kernel(const float* __restrict__ part, float* __restrict__ maxv, int nblk) {
  int t = threadIdx.x;
  int h = t & 7, k = t >> 3;
  float m = -3.4e38f;
  for (int i = k; i < nblk; i += 8) m = fmaxf(m, part[i * 8 + h]);
  m = fmaxf(m, __shfl_xor(m, 8, 64));
  m = fmaxf(m, __shfl_xor(m, 16, 64));
  m = fmaxf(m, __shfl_xor(m, 32, 64));
  if (t < 8) maxv[t] = m;
}

// ---------- layer-2 max, two-stage ----------
__global__ __launch_bounds__(256) void max2_part_kernel(
    const int* __restrict__ esrc, const int* __restrict__ edst,
    const float* __restrict__ asrc, const float* __restrict__ adst,
    float* __restrict__ part, int E) {
  float m = -3.4e38f;
  for (int e = blockIdx.x * blockDim.x + threadIdx.x; e < E; e += gridDim.x * blockDim.x) {
    float x = asrc[esrc[e]] + adst[edst[e]];
    m = fmaxf(m, leaky(x));
  }
#pragma unroll
  for (int off = 32; off; off >>= 1) m = fmaxf(m, __shfl_xor(m, off, 64));
  __shared__ float sm[4];
  int wv = threadIdx.x >> 6, ln = threadIdx.x & 63;
  if (ln == 0) sm[wv] = m;
  __syncthreads();
  if (threadIdx.x == 0)
    part[blockIdx.x] = fmaxf(fmaxf(sm[0], sm[1]), fmaxf(sm[2], sm[3]));
}

__global__ void max2_final_kernel(const float* __restrict__ part, float* __restrict__ maxv, int nblk) {
  int t = threadIdx.x;
  float m = -3.4e38f;
  for (int i = t; i < nblk; i += 64) m = fmaxf(m, part[i]);
#pragma unroll
  for (int off = 32; off; off >>= 1) m = fmaxf(m, __shfl_xor(m, off, 64));
  if (t == 0) maxv[0] = m;
}

// ---------- layer-1 aggregation (block-per-node, LDS coef, unroll 4) ----------
__global__ __launch_bounds__(128) void agg1_kernel(
    const unsigned short* __restrict__ msg, const float* __restrict__ asrc,
    const float* __restrict__ adst, const float* __restrict__ maxv,
    const int* __restrict__ rowptr, const int* __restrict__ colsrc,
    unsigned short* __restrict__ out) {
  int n = blockIdx.x;
  int tid = threadIdx.x;
  __shared__ int s_sh[64];
  __shared__ float coef_sh[64][8];
  __shared__ float hdr[16];
  if (tid < 8) {
    hdr[tid] = maxv[tid];
    hdr[8 + tid] = adst[(size_t)n * 8 + tid];
  }
  __syncthreads();
  const int h = tid >> 4;
  const int e0 = rowptr[n], e1 = rowptr[n + 1];
  float4 acc = make_float4(0.f, 0.f, 0.f, 0.f);
  float dsum = 0.f;
  for (int base = e0; base < e1; base += 64) {
    int cnt = min(64, e1 - base);
    __syncthreads();
#pragma unroll
    for (int q = 0; q < 4; ++q) {
      int slot = q * 128 + tid;
      int el = slot >> 3, hh = slot & 7;
      if (el < cnt) {
        int s = colsrc[base + el];
        if (hh == 0) s_sh[el] = s;
        float x = asrc[(size_t)s * 8 + hh] + hdr[8 + hh];
        x = x >= 0.f ? x : 0.2f * x;
        coef_sh[el][hh] = __expf(x - hdr[hh]);
      }
    }
    __syncthreads();
    int e = 0;
    for (; e + 4 <= cnt; e += 4) {
      int sA = s_sh[e], sB = s_sh[e + 1], sC = s_sh[e + 2], sD = s_sh[e + 3];
      us4 ma = *reinterpret_cast<const us4*>(&msg[(size_t)sA * HDIM + tid * 4]);
      us4 mb = *reinterpret_cast<const us4*>(&msg[(size_t)sB * HDIM + tid * 4]);
      us4 mc = *reinterpret_cast<const us4*>(&msg[(size_t)sC * HDIM + tid * 4]);
      us4 md = *reinterpret_cast<const us4*>(&msg[(size_t)sD * HDIM + tid * 4]);
      float ca = coef_sh[e][h], cb = coef_sh[e + 1][h];
      float cc = coef_sh[e + 2][h], cd = coef_sh[e + 3][h];
      dsum += (ca + cb) + (cc + cd);
      acc.x = fmaf(bf2f(ma[0]), ca, acc.x); acc.y = fmaf(bf2f(ma[1]), ca, acc.y);
      acc.z = fmaf(bf2f(ma[2]), ca, acc.z); acc.w = fmaf(bf2f(ma[3]), ca, acc.w);
      acc.x = fmaf(bf2f(mb[0]), cb, acc.x); acc.y = fmaf(bf2f(mb[1]), cb, acc.y);
      acc.z = fmaf(bf2f(mb[2]), cb, acc.z); acc.w = fmaf(bf2f(mb[3]), cb, acc.w);
      acc.x = fmaf(bf2f(mc[0]), cc, acc.x); acc.y = fmaf(bf2f(mc[1]), cc, acc.y);
      acc.z = fmaf(bf2f(mc[2]), cc, acc.z); acc.w = fmaf(bf2f(mc[3]), cc, acc.w);
      acc.x = fmaf(bf2f(md[0]), cd, acc.x); acc.y = fmaf(bf2f(md[1]), cd, acc.y);
      acc.z = fmaf(bf2f(md[2]), cd, acc.z); acc.w = fmaf(bf2f(md[3]), cd, acc.w);
    }
    for (; e < cnt; ++e) {
      int s = s_sh[e];
      float c = coef_sh[e][h];
      dsum += c;
      us4 m4 = *reinterpret_cast<const us4*>(&msg[(size_t)s * HDIM + tid * 4]);
      acc.x = fmaf(bf2f(m4[0]), c, acc.x); acc.y = fmaf(bf2f(m4[1]), c, acc.y);
      acc.z = fmaf(bf2f(m4[2]), c, acc.z); acc.w = fmaf(bf2f(m4[3]), c, acc.w);
    }
  }
  float inv = 1.0f / (dsum + 1e-10f);
  us4 o;
  o[0] = f2bf(acc.x * inv); o[1] = f2bf(acc.y * inv);
  o[2] = f2bf(acc.z * inv); o[3] = f2bf(acc.w * inv);
  *reinterpret_cast<us4*>(&out[(size_t)n * HDIM + tid * 4]) = o;
}

// ---------- layer-2 aggregation: wave-per-node, shfl-broadcast coefs, unroll 4 ----------
__global__ __launch_bounds__(256) void agg2_kernel(
    const unsigned short* __restrict__ msg, const float* __restrict__ asrc,
    const float* __restrict__ adst, const float* __restrict__ maxv,
    const int* __restrict__ rowptr, const int* __restrict__ colsrc,
    float* __restrict__ out) {
  int wv = threadIdx.x >> 6, ln = threadIdx.x & 63;
  int n = blockIdx.x * 4 + wv;
  float M = maxv[0];
  float ad = adst[n];
  int e0 = rowptr[n], e1 = rowptr[n + 1];
  float a0 = 0.f, a1 = 0.f, ds = 0.f;
  for (int base = e0; base < e1; base += 64) {
    int cnt = min(64, e1 - base);
    int s_reg = 0; float c_reg = 0.f;
    if (ln < cnt) {
      s_reg = colsrc[base + ln];
      float x = asrc[s_reg] + ad;
      x = x >= 0.f ? x : 0.2f * x;
      c_reg = __expf(x - M);
    }
    int e = 0;
    for (; e + 4 <= cnt; e += 4) {
      int s0 = __shfl(s_reg, e, 64),     s1 = __shfl(s_reg, e + 1, 64);
      int s2 = __shfl(s_reg, e + 2, 64), s3 = __shfl(s_reg, e + 3, 64);
      float c0 = __shfl(c_reg, e, 64),     c1 = __shfl(c_reg, e + 1, 64);
      float c2 = __shfl(c_reg, e + 2, 64), c3 = __shfl(c_reg, e + 3, 64);
      us2 m0 = *reinterpret_cast<const us2*>(&msg[(size_t)s0 * 128 + 2 * ln]);
      us2 m1 = *reinterpret_cast<const us2*>(&msg[(size_t)s1 * 128 + 2 * ln]);
      us2 m2 = *reinterpret_cast<const us2*>(&msg[(size_t)s2 * 128 + 2 * ln]);
      us2 m3 = *reinterpret_cast<const us2*>(&msg[(size_t)s3 * 128 + 2 * ln]);
      ds += (c0 + c1) + (c2 + c3);
      a0 = fmaf(bf2f(m0[0]), c0, a0); a1 = fmaf(bf2f(m0[1]), c0, a1);
      a0 = fmaf(bf2f(m1[0]), c1, a0); a1 = fmaf(bf2f(m1[1]), c1, a1);
      a0 = fmaf(bf2f(m2[0]), c2, a0); a1 = fmaf(bf2f(m2[1]), c2, a1);
      a0 = fmaf(bf2f(m3[0]), c3, a0); a1 = fmaf(bf2f(m3[1]), c3, a1);
    }
    for (; e < cnt; ++e) {
      int s = __shfl(s_reg, e, 64);
      float c = __shfl(c_reg, e, 64);
      us2 m = *reinterpret_cast<const us2*>(&msg[(size_t)s * 128 + 2 * ln]);
      ds += c;
      a0 = fmaf(bf2f(m[0]), c, a0);
      a1 = fmaf(bf2f(m[1]), c, a1);
    }
  }
  float inv = 1.0f / (ds + 1e-10f);
  float2 r; r.x = a0 * inv; r.y = a1 * inv;
  *reinterpret_cast<float2*>(&out[(size_t)n * 128 + 2 * ln]) = r;
}

// ---------- column stats, bf16 [M][512]: wave reads full 1KB row ----------
__global__ __launch_bounds__(256) void colstats_bf512_kernel(
    const unsigned short* __restrict__ X, float* __restrict__ sums,
    float* __restrict__ sqs, int M) {
  int tid = threadIdx.x;
  int cg = tid & 63;            // column group (8 bf16 = 16B)
  int wv = tid >> 6;            // wave = row slot (4 rows in flight)
  int rows = (M + gridDim.x - 1) / gridDim.x;
  int r0 = blockIdx.x * rows;
  int r1 = min(M, r0 + rows);
  float s[8], q[8];
#pragma unroll
  for (int j = 0; j < 8; ++j) { s[j] = 0.f; q[j] = 0.f; }
  for (int r = r0 + wv; r < r1; r += 4) {
    us8 v = *reinterpret_cast<const us8*>(&X[(size_t)r * 512 + cg * 8]);
#pragma unroll
    for (int j = 0; j < 8; ++j) {
      float f = bf2f(v[j]);
      s[j] += f; q[j] = fmaf(f, f, q[j]);
    }
  }
  __shared__ float shs[3][512];
  __shared__ float shq[3][512];
  if (wv > 0) {
#pragma unroll
    for (int j = 0; j < 8; ++j) {
      shs[wv - 1][cg * 8 + j] = s[j];
      shq[wv - 1][cg * 8 + j] = q[j];
    }
  }
  __syncthreads();
  if (wv == 0) {
#pragma unroll
    for (int j = 0; j < 8; ++j) {
      int c = cg * 8 + j;
      atomicAdd(&sums[c], s[j] + shs[0][c] + shs[1][c] + shs[2][c]);
      atomicAdd(&sqs[c],  q[j] + shq[0][c] + shq[1][c] + shq[2][c]);
    }
  }
}

// ---------- column stats, fp32 [M][128]: half-wave reads full 512B row ----------
__global__ __launch_bounds__(256) void colstats_f128_kernel(
    const float* __restrict__ X, float* __restrict__ sums,
    float* __restrict__ sqs, int M) {
  int tid = threadIdx.x;
  int g = tid & 31;             // float4 group
  int slot = tid >> 5;          // 8 row slots
  int rows = (M + gridDim.x - 1) / gridDim.x;
  int r0 = blockIdx.x * rows;
  int r1 = min(M, r0 + rows);
  float s[4] = {0.f, 0.f, 0.f, 0.f}, q[4] = {0.f, 0.f, 0.f, 0.f};
  for (int r = r0 + slot; r < r1; r += 8) {
    float4 v = *reinterpret_cast<const float4*>(&X[(size_t)r * 128 + g * 4]);
    s[0] += v.x; q[0] = fmaf(v.x, v.x, q[0]);
    s[1] += v.y; q[1] = fmaf(v.y, v.y, q[1]);
    s[2] += v.z; q[2] = fmaf(v.z, v.z, q[2]);
    s[3] += v.w; q[3] = fmaf(v.w, v.w, q[3]);
  }
#pragma unroll
  for (int j = 0; j < 4; ++j) {           // reduce slot pairs within wave
    s[j] += __shfl_xor(s[j], 32, 64);
    q[j] += __shfl_xor(q[j], 32, 64);
  }
  __shared__ float shs[3][128];
  __shared__ float shq[3][128];
  int wv = tid >> 6, ln = tid & 63;
  if (wv > 0 && ln < 32) {
#pragma unroll
    for (int j = 0; j < 4; ++j) {
      shs[wv - 1][g * 4 + j] = s[j];
      shq[wv - 1][g * 4 + j] = q[j];
    }
  }
  __syncthreads();
  if (wv == 0 && ln < 32) {
#pragma unroll
    for (int j = 0; j < 4; ++j) {
      int c = g * 4 + j;
      atomicAdd(&sums[c], s[j] + shs[0][c] + shs[1][c] + shs[2][c]);
      atomicAdd(&sqs[c],  q[j] + shq[0][c] + shq[1][c] + shq[2][c]);
    }
  }
}

// ---------- final: BN(out2) (inline stats) + residual ----------
__global__ void final_kernel(float* __restrict__ out, const float* __restrict__ resid,
                             const float* __restrict__ colsum, const float* __restrict__ colsq,
                             const float* __restrict__ gamma, const float* __restrict__ beta,
                             int total) {
  for (int i = blockIdx.x * blockDim.x + threadIdx.x; i < total; i += gridDim.x * blockDim.x) {
    int c = i & 127;
    float mean = colsum[c] * INV_N;
    float sc = bn_scale(colsum[c], colsq[c], gamma[c]);
    float sh = beta[c] - mean * sc;
    out[i] = fmaf(out[i], sc, sh) + resid[i];
  }
}

// ==================== host ====================
extern "C" void kernel_launch(void* const* d_in, const int* in_sizes, int n_in,
                              void* d_out, int out_size, void* d_ws, size_t ws_size,
                              hipStream_t stream) {
  const float* feat    = (const float*)d_in[0];
  const int*   edges   = (const int*)d_in[1];
  const int*   esrc    = edges;
  const int*   edst    = edges + N_EDGES;
  const float* W_heads = (const float*)d_in[2];
  const float* a_heads = (const float*)d_in[3];
  const float* gamma_h = (const float*)d_in[4];
  const float* beta_h  = (const float*)d_in[5];
  const float* W_out   = (const float*)d_in[6];
  const float* a_out   = (const float*)d_in[7];
  const float* gamma_o = (const float*)d_in[8];
  const float* beta_o  = (const float*)d_in[9];
  const float* W_res   = (const float*)d_in[10];
  const float* b_res   = (const float*)d_in[11];
  float* out = (float*)d_out;

  char* ws = (char*)d_ws;
  size_t off = 0;
  auto alloc = [&](size_t bytes) {
    void* p = ws + off;
    off = (off + bytes + 255) & ~(size_t)255;
    return p;
  };
  unsigned short* msg1    = (unsigned short*)alloc((size_t)N_NODES * HDIM * 2);  // reused as msg2
  unsigned short* out1_bf = (unsigned short*)alloc((size_t)N_NODES * HDIM * 2);
  unsigned short* feat_bf = (unsigned short*)alloc((size_t)N_NODES * DIM_IN * 2);
  float*    resid  = (float*)alloc((size_t)N_NODES * DIM_OUT * 4);
  float*    asrc1  = (float*)alloc((size_t)N_NODES * NHEADS * 4); // reused as asrc2
  float*    adst1  = (float*)alloc((size_t)N_NODES * NHEADS * 4); // reused as adst2
  int*      counts = (int*)alloc((size_t)N_NODES * 4);
  int*      cursor = (int*)alloc((size_t)N_NODES * 4);   // adjacent to counts
  int*      rowptr = (int*)alloc((size_t)(N_NODES + 1) * 4);
  int*      colsrc = (int*)alloc((size_t)N_EDGES * 4);
  int*      bsum   = (int*)alloc(64 * 4);
  float*    part   = (float*)alloc((size_t)SMBLK * 8 * 4);
  float*    maxv1  = (float*)alloc(8 * 4);
  float*    maxv2  = (float*)alloc(4);
  float*    colsum = (float*)alloc(HDIM * 4);
  float*    colsq  = (float*)alloc(HDIM * 4);   // adjacent to colsum
  unsigned short* Bt1 = (unsigned short*)alloc((size_t)HDIM * DIM_IN * 2);
  unsigned short* Bt2 = (unsigned short*)alloc((size_t)DIM_OUT * HDIM * 2);
  unsigned short* Btr = (unsigned short*)alloc((size_t)DIM_OUT * DIM_IN * 2);
  float*    bias2  = (float*)alloc(DIM_OUT * 4);
  unsigned short* msg2 = msg1;
  float* asrc2 = asrc1; float* adst2 = adst1;
  (void)n_in; (void)in_sizes; (void)out_size; (void)ws_size;

  // merged zero-init: counts+cursor contiguous; colsum+colsq contiguous
  hipMemsetAsync(counts, 0, (char*)rowptr - (char*)counts, stream);
  hipMemsetAsync(colsum, 0, 4096, stream);

  // ---- prep (cvt + packs fused) ----
  prep_kernel<<<6570, 256, 0, stream>>>(feat, W_heads, W_res, feat_bf, Bt1, Btr);

  // ---- layer 1 ----
  dim3 g1(HDIM / 128, (N_NODES + 127) / 128);
  gemm_mfma<1><<<g1, 256, 0, stream>>>(feat_bf, Bt1, msg1, nullptr, N_NODES, HDIM, DIM_IN);
  attn1_kernel<<<(N_NODES + 3) / 4, 256, 0, stream>>>(msg1, a_heads, asrc1, adst1, N_NODES);

  hist_kernel<<<2048, 256, 0, stream>>>(edst, counts, N_EDGES);
  int nsb = (N_NODES + 1023) / 1024;   // 49
  scan1_kernel<<<nsb, 256, 0, stream>>>(counts, rowptr, bsum, N_NODES);
  scan2_kernel<<<1, 64, 0, stream>>>(bsum, nsb);
  scan3_kernel<<<(N_NODES + 256) / 256, 256, 0, stream>>>(rowptr, bsum, N_NODES);

  scatter_max1_kernel<<<SMBLK, 256, 0, stream>>>(esrc, edst, asrc1, adst1, rowptr,
                                                 cursor, colsrc, part, N_EDGES);
  max1_final_kernel<<<1, 64, 0, stream>>>(part, maxv1, SMBLK);
  agg1_kernel<<<N_NODES, 128, 0, stream>>>(msg1, asrc1, adst1, maxv1, rowptr, colsrc, out1_bf);

  colstats_bf512_kernel<<<CSBLK, 256, 0, stream>>>(out1_bf, colsum, colsq, N_NODES);
  foldw2_kernel<<<(DIM_OUT * HDIM + 255) / 256, 256, 0, stream>>>(W_out, colsum, colsq, gamma_h, Bt2);
  bias2_kernel<<<1, 128, 0, stream>>>(W_out, colsum, colsq, gamma_h, beta_h, bias2);

  // ---- layer 2 ----
  dim3 g2(DIM_OUT / 128, (N_NODES + 127) / 128);
  gemm_mfma<1><<<g2, 256, 0, stream>>>(out1_bf, Bt2, msg2, bias2, N_NODES, DIM_OUT, HDIM);
  attn2_kernel<<<(N_NODES + 3) / 4, 256, 0, stream>>>(msg2, a_out, asrc2, adst2, N_NODES);

  max2_part_kernel<<<MAXBLK, 256, 0, stream>>>(esrc, edst, asrc2, adst2, part, N_EDGES);
  max2_final_kernel<<<1, 64, 0, stream>>>(part, maxv2, MAXBLK);
  agg2_kernel<<<N_NODES / 4, 256, 0, stream>>>(msg2, asrc2, adst2, maxv2, rowptr, colsrc, out);

  // residual GEMM (bf16 MFMA, fp32 out)
  gemm_mfma<0><<<g2, 256, 0, stream>>>(feat_bf, Btr, resid, b_res, N_NODES, DIM_OUT, DIM_IN);

  // layer-2 BN stats + fused BN+residual epilogue
  hipMemsetAsync(colsum, 0, 4096, stream);
  colstats_f128_kernel<<<CSBLK, 256, 0, stream>>>(out, colsum, colsq, N_NODES);
  final_kernel<<<2048, 256, 0, stream>>>(out, resid, colsum, colsq, gamma_o, beta_o,
                                         N_NODES * DIM_OUT);
}

// Round 9
// 780.915 us; speedup vs baseline: 1.2097x; 1.0197x over previous
//
#include <hip/hip_runtime.h>
#include <math.h>

#define N_NODES 50000
#define N_EDGES 1600000
#define DIM_IN  128
#define DIM_HID 64
#define NHEADS  8
#define HDIM    (NHEADS*DIM_HID)   // 512
#define DIM_OUT 128
#define SMBLK   1024               // blocks for scatter+max1 pass
#define MAXBLK  512                // blocks for max2 pass
#define HISTBLK 2048               // hist sub-grid inside prep
#define LDK     72                 // padded LDS row (bf16 elems)
#define INV_N   2e-5f              // 1/N_NODES
#define CSBLK   400                // blocks for column-stats kernels

typedef __attribute__((ext_vector_type(2))) unsigned short us2;
typedef __attribute__((ext_vector_type(4))) unsigned short us4;
typedef __attribute__((ext_vector_type(8))) unsigned short us8;
typedef __attribute__((ext_vector_type(8))) short bf16x8;
typedef __attribute__((ext_vector_type(4))) float f32x4;

__device__ __forceinline__ float leaky(float x) { return x >= 0.f ? x : 0.2f * x; }
__device__ __forceinline__ float bf2f(unsigned short h) {
  return __uint_as_float(((unsigned)h) << 16);
}
__device__ __forceinline__ unsigned short f2bf(float f) {
  unsigned u = __float_as_uint(f);
  unsigned r = (u + 0x7fffu + ((u >> 16) & 1u)) >> 16;
  return (unsigned short)r;
}
__device__ __forceinline__ float bn_scale(float sum, float sq, float g) {
  float mean = sum * INV_N;
  float var = sq * INV_N - mean * mean;
  return g * rsqrtf(var + 1e-5f);
}

// ---------- fused prep: cvt feat->bf16 | pack W_heads | pack W_res | edge histogram ----------
__global__ void prep_kernel(const float* __restrict__ feat, const float* __restrict__ Wh,
                            const float* __restrict__ Wres, const int* __restrict__ edst,
                            unsigned short* __restrict__ feat_bf,
                            unsigned short* __restrict__ Bt1,
                            unsigned short* __restrict__ Btr,
                            int* __restrict__ counts) {
  int b = blockIdx.x;
  if (b < 6250) {
    int i = b * 256 + threadIdx.x;
    float4 v = *reinterpret_cast<const float4*>(&feat[(size_t)i * 4]);
    us4 o;
    o[0] = f2bf(v.x); o[1] = f2bf(v.y); o[2] = f2bf(v.z); o[3] = f2bf(v.w);
    *reinterpret_cast<us4*>(&feat_bf[(size_t)i * 4]) = o;
  } else if (b < 6506) {
    int idx = (b - 6250) * 256 + threadIdx.x;
    int n = idx >> 7, k = idx & 127;
    Bt1[idx] = f2bf(Wh[(n >> 6) * (DIM_IN * DIM_HID) + k * DIM_HID + (n & 63)]);
  } else if (b < 6570) {
    int idx = (b - 6506) * 256 + threadIdx.x;
    int n = idx >> 7, k = idx & 127;
    Btr[idx] = f2bf(Wres[k * DIM_OUT + n]);
  } else {
    int bid = b - 6570;   // hist over HISTBLK virtual blocks
    for (int e = bid * 256 + threadIdx.x; e < N_EDGES; e += HISTBLK * 256)
      atomicAdd(&counts[edst[e]], 1);
  }
}

// ---------- fold BN1 (inline from stats) into W_out -> Bt2 [128][512] bf16 ----------
__global__ void foldw2_kernel(const float* __restrict__ W,
                              const float* __restrict__ colsum, const float* __restrict__ colsq,
                              const float* __restrict__ gamma,
                              unsigned short* __restrict__ Bt) {
  int idx = blockIdx.x * 256 + threadIdx.x;
  if (idx >= DIM_OUT * HDIM) return;
  int n = idx >> 9, k = idx & 511;
  float sc = bn_scale(colsum[k], colsq[k], gamma[k]);
  Bt[idx] = f2bf(W[k * DIM_OUT + n] * sc);
}

// ---------- bias2 = shift1^T @ W_out (shift computed inline) ----------
__global__ void bias2_kernel(const float* __restrict__ W,
                             const float* __restrict__ colsum, const float* __restrict__ colsq,
                             const float* __restrict__ gamma, const float* __restrict__ beta,
                             float* __restrict__ bias2) {
  int j = threadIdx.x;
  if (j >= DIM_OUT) return;
  float s = 0.f;
  for (int c = 0; c < HDIM; ++c) {
    float mean = colsum[c] * INV_N;
    float sc = bn_scale(colsum[c], colsq[c], gamma[c]);
    float shift = beta[c] - mean * sc;
    s = fmaf(shift, W[c * DIM_OUT + j], s);
  }
  bias2[j] = s;
}

// ---------- bf16 MFMA GEMM body: C[M,N] = A[M,K] @ Bt[N,K]^T (+bias) ----------
__device__ __forceinline__ void gemm_body(
    const unsigned short* __restrict__ A, const unsigned short* __restrict__ Bt,
    void* __restrict__ Cout, const float* __restrict__ bias,
    int M, int N, int K, int outbf) {
  __shared__ unsigned short As[128 * LDK];
  __shared__ unsigned short Bs[128 * LDK];
  const int tid = threadIdx.x;
  const int lane = tid & 63, wid = tid >> 6;
  const int wr = wid >> 1, wc = wid & 1;
  const int l15 = lane & 15, lhi = lane >> 4;
  const int m0 = blockIdx.y * 128, n0 = blockIdx.x * 128;
  const int srow = tid >> 3;
  const int sc8 = (tid - srow) & 7;
  f32x4 acc[4][4];
#pragma unroll
  for (int i = 0; i < 4; ++i)
#pragma unroll
    for (int j = 0; j < 4; ++j) acc[i][j] = f32x4{0.f, 0.f, 0.f, 0.f};

  for (int k0 = 0; k0 < K; k0 += 64) {
    __syncthreads();
#pragma unroll
    for (int p = 0; p < 4; ++p) {
      int row = p * 32 + srow;
      us8 va = {0, 0, 0, 0, 0, 0, 0, 0};
      int gr = m0 + row;
      if (gr < M) va = *reinterpret_cast<const us8*>(&A[(size_t)gr * K + k0 + sc8 * 8]);
      *reinterpret_cast<us8*>(&As[row * LDK + sc8 * 8]) = va;
      us8 vb = {0, 0, 0, 0, 0, 0, 0, 0};
      int gn = n0 + row;
      if (gn < N) vb = *reinterpret_cast<const us8*>(&Bt[(size_t)gn * K + k0 + sc8 * 8]);
      *reinterpret_cast<us8*>(&Bs[row * LDK + sc8 * 8]) = vb;
    }
    __syncthreads();
#pragma unroll
    for (int kk = 0; kk < 2; ++kk) {
      bf16x8 af[4], bfr[4];
#pragma unroll
      for (int i = 0; i < 4; ++i)
        af[i] = *reinterpret_cast<const bf16x8*>(&As[(wr * 64 + i * 16 + l15) * LDK + kk * 32 + lhi * 8]);
#pragma unroll
      for (int j = 0; j < 4; ++j)
        bfr[j] = *reinterpret_cast<const bf16x8*>(&Bs[(wc * 64 + j * 16 + l15) * LDK + kk * 32 + lhi * 8]);
#pragma unroll
      for (int i = 0; i < 4; ++i)
#pragma unroll
        for (int j = 0; j < 4; ++j)
          acc[i][j] = __builtin_amdgcn_mfma_f32_16x16x32_bf16(af[i], bfr[j], acc[i][j], 0, 0, 0);
    }
  }
#pragma unroll
  for (int j = 0; j < 4; ++j) {
    int col = n0 + wc * 64 + j * 16 + l15;
    float bb = bias ? bias[col] : 0.f;
#pragma unroll
    for (int i = 0; i < 4; ++i) {
      f32x4 v = acc[i][j];
#pragma unroll
      for (int t = 0; t < 4; ++t) {
        int row = m0 + wr * 64 + i * 16 + lhi * 4 + t;
        if (row < M) {
          float o = v[t] + bb;
          if (outbf) ((unsigned short*)Cout)[(size_t)row * N + col] = f2bf(o);
          else       ((float*)Cout)[(size_t)row * N + col] = o;
        }
      }
    }
  }
}

__global__ __launch_bounds__(256) void gemm_single(
    const unsigned short* __restrict__ A, const unsigned short* __restrict__ Bt,
    void* __restrict__ Cout, const float* __restrict__ bias,
    int M, int N, int K, int outbf) {
  gemm_body(A, Bt, Cout, bias, M, N, K, outbf);
}

// z=0: gemm2 (out1_bf @ Bt2 + bias2 -> msg2 bf16); z=1: residual (feat_bf @ Btr + b_res -> resid f32)
__global__ __launch_bounds__(256) void gemm_dual(
    const unsigned short* __restrict__ A0, const unsigned short* __restrict__ Bt0,
    void* __restrict__ C0, const float* __restrict__ b0, int K0,
    const unsigned short* __restrict__ A1, const unsigned short* __restrict__ Bt1,
    void* __restrict__ C1, const float* __restrict__ b1, int K1) {
  if (blockIdx.z == 0) gemm_body(A0, Bt0, C0, b0, N_NODES, DIM_OUT, K0, 1);
  else                 gemm_body(A1, Bt1, C1, b1, N_NODES, DIM_OUT, K1, 0);
}

// ---------- attn projections layer 1 (bf16 msg) ----------
__global__ __launch_bounds__(256) void attn1_kernel(
    const unsigned short* __restrict__ msg, const float* __restrict__ a_heads,
    float* __restrict__ asrc, float* __restrict__ adst, int Nn) {
  int lane = threadIdx.x & 63;
  int n = blockIdx.x * 4 + (threadIdx.x >> 6);
  if (n >= Nn) return;
  us8 v = *reinterpret_cast<const us8*>(&msg[(size_t)n * HDIM + lane * 8]);
  int h = lane >> 3, p0 = (lane & 7) * 8;
  float s = 0.f, d = 0.f;
#pragma unroll
  for (int j = 0; j < 8; ++j) {
    float f = bf2f(v[j]);
    s = fmaf(f, a_heads[h * 128 + p0 + j], s);
    d = fmaf(f, a_heads[h * 128 + 64 + p0 + j], d);
  }
  s += __shfl_xor(s, 1, 64); s += __shfl_xor(s, 2, 64); s += __shfl_xor(s, 4, 64);
  d += __shfl_xor(d, 1, 64); d += __shfl_xor(d, 2, 64); d += __shfl_xor(d, 4, 64);
  if ((lane & 7) == 0) { asrc[n * 8 + h] = s; adst[n * 8 + h] = d; }
}

// ---------- attn projections layer 2 (bf16 msg) ----------
__global__ __launch_bounds__(256) void attn2_kernel(
    const unsigned short* __restrict__ msg, const float* __restrict__ a_out,
    float* __restrict__ asrc, float* __restrict__ adst, int Nn) {
  int lane = threadIdx.x & 63;
  int n = blockIdx.x * 4 + (threadIdx.x >> 6);
  if (n >= Nn) return;
  us2 v = *reinterpret_cast<const us2*>(&msg[(size_t)n * 128 + lane * 2]);
  float f0 = bf2f(v[0]), f1 = bf2f(v[1]);
  float s = f0 * a_out[2 * lane] + f1 * a_out[2 * lane + 1];
  float d = f0 * a_out[128 + 2 * lane] + f1 * a_out[128 + 2 * lane + 1];
#pragma unroll
  for (int off = 32; off; off >>= 1) {
    s += __shfl_xor(s, off, 64);
    d += __shfl_xor(d, off, 64);
  }
  if (lane == 0) { asrc[n] = s; adst[n] = d; }
}

// ---------- CSR: local scan ----------
__global__ __launch_bounds__(256) void scan1_kernel(
    const int* __restrict__ counts, int* __restrict__ rowptr, int* __restrict__ bsum, int n) {
  __shared__ int wsum[4];
  int b0 = blockIdx.x * 1024;
  int t = threadIdx.x;
  int lane = t & 63, w = t >> 6;
  int v[4]; int s = 0;
#pragma unroll
  for (int i = 0; i < 4; ++i) {
    int idx = b0 + t * 4 + i;
    v[i] = (idx < n) ? counts[idx] : 0;
    s += v[i];
  }
  int x = s;
#pragma unroll
  for (int off = 1; off < 64; off <<= 1) {
    int y = __shfl_up(x, off, 64);
    if (lane >= off) x += y;
  }
  if (lane == 63) wsum[w] = x;
  __syncthreads();
  int wof = 0;
  for (int i = 0; i < w; ++i) wof += wsum[i];
  int run = wof + x - s;
#pragma unroll
  for (int i = 0; i < 4; ++i) {
    int idx = b0 + t * 4 + i;
    if (idx < n) rowptr[idx] = run;
    run += v[i];
  }
  if (t == 255) bsum[blockIdx.x] = wof + x;
}

// ---------- CSR: carry propagate (merged scan2+scan3); block b adds sum(bsum[0..b)) ----------
__global__ __launch_bounds__(256) void scan23_kernel(
    int* __restrict__ rowptr, const int* __restrict__ bsum, int n) {
  __shared__ int carry_sh;
  int b = blockIdx.x, t = threadIdx.x;
  if (t < 64) {
    int v = (t < b) ? bsum[t] : 0;
#pragma unroll
    for (int off = 32; off; off >>= 1) v += __shfl_xor(v, off, 64);
    if (t == 0) carry_sh = v;
  }
  __syncthreads();
  int carry = carry_sh;
  int i0 = b * 1024;
#pragma unroll
  for (int q = 0; q < 4; ++q) {
    int i = i0 + q * 256 + t;
    if (i < n) rowptr[i] += carry;
  }
  if (b == gridDim.x - 1 && t == 0) rowptr[n] = N_EDGES;
}

// ---------- fused scatter + layer-1 max partials ----------
__global__ __launch_bounds__(256) void scatter_max1_kernel(
    const int* __restrict__ esrc, const int* __restrict__ edst,
    const float* __restrict__ asrc, const float* __restrict__ adst,
    const int* __restrict__ rowptr, int* __restrict__ cursor,
    int* __restrict__ colsrc, float* __restrict__ part, int E) {
  float m[8];
#pragma unroll
  for (int h = 0; h < 8; ++h) m[h] = -3.4e38f;
  for (int e = blockIdx.x * blockDim.x + threadIdx.x; e < E; e += gridDim.x * blockDim.x) {
    int s = esrc[e], d = edst[e];
    int pos = rowptr[d] + atomicAdd(&cursor[d], 1);
    colsrc[pos] = s;
    float4 s0 = *reinterpret_cast<const float4*>(&asrc[(size_t)s * 8]);
    float4 s1 = *reinterpret_cast<const float4*>(&asrc[(size_t)s * 8 + 4]);
    float4 d0 = *reinterpret_cast<const float4*>(&adst[(size_t)d * 8]);
    float4 d1 = *reinterpret_cast<const float4*>(&adst[(size_t)d * 8 + 4]);
    float xs[8] = {s0.x + d0.x, s0.y + d0.y, s0.z + d0.z, s0.w + d0.w,
                   s1.x + d1.x, s1.y + d1.y, s1.z + d1.z, s1.w + d1.w};
#pragma unroll
    for (int h = 0; h < 8; ++h) m[h] = fmaxf(m[h], leaky(xs[h]));
  }
#pragma unroll
  for (int h = 0; h < 8; ++h)
#pragma unroll
    for (int off = 32; off; off >>= 1) m[h] = fmaxf(m[h], __shfl_xor(m[h], off, 64));
  __shared__ float sm[4][8];
  int wv = threadIdx.x >> 6, ln = threadIdx.x & 63;
  if (ln == 0)
#pragma unroll
    for (int h = 0; h < 8; ++h) sm[wv][h] = m[h];
  __syncthreads();
  if (threadIdx.x < 8) {
    int h = threadIdx.x;
    part[blockIdx.x * 8 + h] =
        fmaxf(fmaxf(sm[0][h], sm[1][h]), fmaxf(sm[2][h], sm[3][h]));
  }
}

__global__ void max1_final_kernel(const float* __restrict__ part, float* __restrict__ maxv, int nblk) {
  int t = threadIdx.x;
  int h = t & 7, k = t >> 3;
  float m = -3.4e38f;
  for (int i = k; i < nblk; i += 8) m = fmaxf(m, part[i * 8 + h]);
  m = fmaxf(m, __shfl_xor(m, 8, 64));
  m = fmaxf(m, __shfl_xor(m, 16, 64));
  m = fmaxf(m, __shfl_xor(m, 32, 64));
  if (t < 8) maxv[t] = m;
}

// ---------- layer-2 max, two-stage ----------
__global__ __launch_bounds__(256) void max2_part_kernel(
    const int* __restrict__ esrc, const int* __restrict__ edst,
    const float* __restrict__ asrc, const float* __restrict__ adst,
    float* __restrict__ part, int E) {
  float m = -3.4e38f;
  for (int e = blockIdx.x * blockDim.x + threadIdx.x; e < E; e += gridDim.x * blockDim.x) {
    float x = asrc[esrc[e]] + adst[edst[e]];
    m = fmaxf(m, leaky(x));
  }
#pragma unroll
  for (int off = 32; off; off >>= 1) m = fmaxf(m, __shfl_xor(m, off, 64));
  __shared__ float sm[4];
  int wv = threadIdx.x >> 6, ln = threadIdx.x & 63;
  if (ln == 0) sm[wv] = m;
  __syncthreads();
  if (threadIdx.x == 0)
    part[blockIdx.x] = fmaxf(fmaxf(sm[0], sm[1]), fmaxf(sm[2], sm[3]));
}

__global__ void max2_final_kernel(const float* __restrict__ part, float* __restrict__ maxv, int nblk) {
  int t = threadIdx.x;
  float m = -3.4e38f;
  for (int i = t; i < nblk; i += 64) m = fmaxf(m, part[i]);
#pragma unroll
  for (int off = 32; off; off >>= 1) m = fmaxf(m, __shfl_xor(m, off, 64));
  if (t == 0) maxv[0] = m;
}

// ---------- layer-1 aggregation: wave-per-node, us8 gathers, shfl coefs, barrier-free ----------
// lane l: gathers cols l*8..l*8+7 (head h=l>>3); computes coef for (edge=l&7, head=l>>3)
// per 8-edge chunk; coef(e, h) lives in lane h*8+e.
__global__ __launch_bounds__(256) void agg1_kernel(
    const unsigned short* __restrict__ msg, const float* __restrict__ asrc,
    const float* __restrict__ adst, const float* __restrict__ maxv,
    const int* __restrict__ rowptr, const int* __restrict__ colsrc,
    unsigned short* __restrict__ out) {
  int wv = threadIdx.x >> 6, l = threadIdx.x & 63;
  int n = blockIdx.x * 4 + wv;
  const int h = l >> 3;
  const int eloc = l & 7;
  const int hbase = l & 56;            // h*8
  float M = maxv[h];
  float ad = adst[(size_t)n * 8 + h];
  int e0 = rowptr[n], e1 = rowptr[n + 1];
  float acc[8];
#pragma unroll
  for (int j = 0; j < 8; ++j) acc[j] = 0.f;
  float ds = 0.f;
  int base = e0;
  for (; base + 8 <= e1; base += 8) {
    int sreg = colsrc[base + eloc];
    float x = asrc[(size_t)sreg * 8 + h] + ad;
    x = x >= 0.f ? x : 0.2f * x;
    float creg = __expf(x - M);
#pragma unroll
    for (int e = 0; e < 8; ++e) {
      float c = __shfl(creg, hbase | e, 64);
      int s = __shfl(sreg, e, 64);
      ds += c;
      us8 m = *reinterpret_cast<const us8*>(&msg[(size_t)s * HDIM + l * 8]);
#pragma unroll
      for (int j = 0; j < 8; ++j) acc[j] = fmaf(bf2f(m[j]), c, acc[j]);
    }
  }
  if (base < e1) {
    int cnt = e1 - base;
    int sreg = 0; float creg = 0.f;
    if (eloc < cnt) {
      sreg = colsrc[base + eloc];
      float x = asrc[(size_t)sreg * 8 + h] + ad;
      x = x >= 0.f ? x : 0.2f * x;
      creg = __expf(x - M);
    }
    for (int e = 0; e < cnt; ++e) {
      float c = __shfl(creg, hbase | e, 64);
      int s = __shfl(sreg, e, 64);
      ds += c;
      us8 m = *reinterpret_cast<const us8*>(&msg[(size_t)s * HDIM + l * 8]);
#pragma unroll
      for (int j = 0; j < 8; ++j) acc[j] = fmaf(bf2f(m[j]), c, acc[j]);
    }
  }
  float inv = 1.0f / (ds + 1e-10f);
  us8 o;
#pragma unroll
  for (int j = 0; j < 8; ++j) o[j] = f2bf(acc[j] * inv);
  *reinterpret_cast<us8*>(&out[(size_t)n * HDIM + l * 8]) = o;
}

// ---------- layer-2 aggregation: wave-per-node, shfl-broadcast coefs, unroll 4 ----------
__global__ __launch_bounds__(256) void agg2_kernel(
    const unsigned short* __restrict__ msg, const float* __restrict__ asrc,
    const float* __restrict__ adst, const float* __restrict__ maxv,
    const int* __restrict__ rowptr, const int* __restrict__ colsrc,
    float* __restrict__ out) {
  int wv = threadIdx.x >> 6, ln = threadIdx.x & 63;
  int n = blockIdx.x * 4 + wv;
  float M = maxv[0];
  float ad = adst[n];
  int e0 = rowptr[n], e1 = rowptr[n + 1];
  float a0 = 0.f, a1 = 0.f, ds = 0.f;
  for (int base = e0; base < e1; base += 64) {
    int cnt = min(64, e1 - base);
    int s_reg = 0; float c_reg = 0.f;
    if (ln < cnt) {
      s_reg = colsrc[base + ln];
      float x = asrc[s_reg] + ad;
      x = x >= 0.f ? x : 0.2f * x;
      c_reg = __expf(x - M);
    }
    int e = 0;
    for (; e + 4 <= cnt; e += 4) {
      int s0 = __shfl(s_reg, e, 64),     s1 = __shfl(s_reg, e + 1, 64);
      int s2 = __shfl(s_reg, e + 2, 64), s3 = __shfl(s_reg, e + 3, 64);
      float c0 = __shfl(c_reg, e, 64),     c1 = __shfl(c_reg, e + 1, 64);
      float c2 = __shfl(c_reg, e + 2, 64), c3 = __shfl(c_reg, e + 3, 64);
      us2 m0 = *reinterpret_cast<const us2*>(&msg[(size_t)s0 * 128 + 2 * ln]);
      us2 m1 = *reinterpret_cast<const us2*>(&msg[(size_t)s1 * 128 + 2 * ln]);
      us2 m2 = *reinterpret_cast<const us2*>(&msg[(size_t)s2 * 128 + 2 * ln]);
      us2 m3 = *reinterpret_cast<const us2*>(&msg[(size_t)s3 * 128 + 2 * ln]);
      ds += (c0 + c1) + (c2 + c3);
      a0 = fmaf(bf2f(m0[0]), c0, a0); a1 = fmaf(bf2f(m0[1]), c0, a1);
      a0 = fmaf(bf2f(m1[0]), c1, a0); a1 = fmaf(bf2f(m1[1]), c1, a1);
      a0 = fmaf(bf2f(m2[0]), c2, a0); a1 = fmaf(bf2f(m2[1]), c2, a1);
      a0 = fmaf(bf2f(m3[0]), c3, a0); a1 = fmaf(bf2f(m3[1]), c3, a1);
    }
    for (; e < cnt; ++e) {
      int s = __shfl(s_reg, e, 64);
      float c = __shfl(c_reg, e, 64);
      us2 m = *reinterpret_cast<const us2*>(&msg[(size_t)s * 128 + 2 * ln]);
      ds += c;
      a0 = fmaf(bf2f(m[0]), c, a0);
      a1 = fmaf(bf2f(m[1]), c, a1);
    }
  }
  float inv = 1.0f / (ds + 1e-10f);
  float2 r; r.x = a0 * inv; r.y = a1 * inv;
  *reinterpret_cast<float2*>(&out[(size_t)n * 128 + 2 * ln]) = r;
}

// ---------- column stats, bf16 [M][512]: wave reads full 1KB row ----------
__global__ __launch_bounds__(256) void colstats_bf512_kernel(
    const unsigned short* __restrict__ X, float* __restrict__ sums,
    float* __restrict__ sqs, int M) {
  int tid = threadIdx.x;
  int cg = tid & 63;
  int wv = tid >> 6;
  int rows = (M + gridDim.x - 1) / gridDim.x;
  int r0 = blockIdx.x * rows;
  int r1 = min(M, r0 + rows);
  float s[8], q[8];
#pragma unroll
  for (int j = 0; j < 8; ++j) { s[j] = 0.f; q[j] = 0.f; }
  for (int r = r0 + wv; r < r1; r += 4) {
    us8 v = *reinterpret_cast<const us8*>(&X[(size_t)r * 512 + cg * 8]);
#pragma unroll
    for (int j = 0; j < 8; ++j) {
      float f = bf2f(v[j]);
      s[j] += f; q[j] = fmaf(f, f, q[j]);
    }
  }
  __shared__ float shs[3][512];
  __shared__ float shq[3][512];
  if (wv > 0) {
#pragma unroll
    for (int j = 0; j < 8; ++j) {
      shs[wv - 1][cg * 8 + j] = s[j];
      shq[wv - 1][cg * 8 + j] = q[j];
    }
  }
  __syncthreads();
  if (wv == 0) {
#pragma unroll
    for (int j = 0; j < 8; ++j) {
      int c = cg * 8 + j;
      atomicAdd(&sums[c], s[j] + shs[0][c] + shs[1][c] + shs[2][c]);
      atomicAdd(&sqs[c],  q[j] + shq[0][c] + shq[1][c] + shq[2][c]);
    }
  }
}

// ---------- column stats, fp32 [M][128]: half-wave reads full 512B row ----------
__global__ __launch_bounds__(256) void colstats_f128_kernel(
    const float* __restrict__ X, float* __restrict__ sums,
    float* __restrict__ sqs, int M) {
  int tid = threadIdx.x;
  int g = tid & 31;
  int slot = tid >> 5;
  int rows = (M + gridDim.x - 1) / gridDim.x;
  int r0 = blockIdx.x * rows;
  int r1 = min(M, r0 + rows);
  float s[4] = {0.f, 0.f, 0.f, 0.f}, q[4] = {0.f, 0.f, 0.f, 0.f};
  for (int r = r0 + slot; r < r1; r += 8) {
    float4 v = *reinterpret_cast<const float4*>(&X[(size_t)r * 128 + g * 4]);
    s[0] += v.x; q[0] = fmaf(v.x, v.x, q[0]);
    s[1] += v.y; q[1] = fmaf(v.y, v.y, q[1]);
    s[2] += v.z; q[2] = fmaf(v.z, v.z, q[2]);
    s[3] += v.w; q[3] = fmaf(v.w, v.w, q[3]);
  }
#pragma unroll
  for (int j = 0; j < 4; ++j) {
    s[j] += __shfl_xor(s[j], 32, 64);
    q[j] += __shfl_xor(q[j], 32, 64);
  }
  __shared__ float shs[3][128];
  __shared__ float shq[3][128];
  int wv = tid >> 6, ln = tid & 63;
  if (wv > 0 && ln < 32) {
#pragma unroll
    for (int j = 0; j < 4; ++j) {
      shs[wv - 1][g * 4 + j] = s[j];
      shq[wv - 1][g * 4 + j] = q[j];
    }
  }
  __syncthreads();
  if (wv == 0 && ln < 32) {
#pragma unroll
    for (int j = 0; j < 4; ++j) {
      int c = g * 4 + j;
      atomicAdd(&sums[c], s[j] + shs[0][c] + shs[1][c] + shs[2][c]);
      atomicAdd(&sqs[c],  q[j] + shq[0][c] + shq[1][c] + shq[2][c]);
    }
  }
}

// ---------- final: BN(out2) (inline stats) + residual ----------
__global__ void final_kernel(float* __restrict__ out, const float* __restrict__ resid,
                             const float* __restrict__ colsum, const float* __restrict__ colsq,
                             const float* __restrict__ gamma, const float* __restrict__ beta,
                             int total) {
  for (int i = blockIdx.x * blockDim.x + threadIdx.x; i < total; i += gridDim.x * blockDim.x) {
    int c = i & 127;
    float mean = colsum[c] * INV_N;
    float sc = bn_scale(colsum[c], colsq[c], gamma[c]);
    float sh = beta[c] - mean * sc;
    out[i] = fmaf(out[i], sc, sh) + resid[i];
  }
}

// ==================== host ====================
extern "C" void kernel_launch(void* const* d_in, const int* in_sizes, int n_in,
                              void* d_out, int out_size, void* d_ws, size_t ws_size,
                              hipStream_t stream) {
  const float* feat    = (const float*)d_in[0];
  const int*   edges   = (const int*)d_in[1];
  const int*   esrc    = edges;
  const int*   edst    = edges + N_EDGES;
  const float* W_heads = (const float*)d_in[2];
  const float* a_heads = (const float*)d_in[3];
  const float* gamma_h = (const float*)d_in[4];
  const float* beta_h  = (const float*)d_in[5];
  const float* W_out   = (const float*)d_in[6];
  const float* a_out   = (const float*)d_in[7];
  const float* gamma_o = (const float*)d_in[8];
  const float* beta_o  = (const float*)d_in[9];
  const float* W_res   = (const float*)d_in[10];
  const float* b_res   = (const float*)d_in[11];
  float* out = (float*)d_out;

  char* ws = (char*)d_ws;
  size_t off = 0;
  auto alloc = [&](size_t bytes) {
    void* p = ws + off;
    off = (off + bytes + 255) & ~(size_t)255;
    return p;
  };
  unsigned short* msg1    = (unsigned short*)alloc((size_t)N_NODES * HDIM * 2);  // reused as msg2
  unsigned short* out1_bf = (unsigned short*)alloc((size_t)N_NODES * HDIM * 2);
  unsigned short* feat_bf = (unsigned short*)alloc((size_t)N_NODES * DIM_IN * 2);
  float*    resid  = (float*)alloc((size_t)N_NODES * DIM_OUT * 4);
  float*    asrc1  = (float*)alloc((size_t)N_NODES * NHEADS * 4); // reused as asrc2
  float*    adst1  = (float*)alloc((size_t)N_NODES * NHEADS * 4); // reused as adst2
  int*      counts = (int*)alloc((size_t)N_NODES * 4);
  int*      cursor = (int*)alloc((size_t)N_NODES * 4);   // adjacent to counts
  int*      rowptr = (int*)alloc((size_t)(N_NODES + 1) * 4);
  int*      colsrc = (int*)alloc((size_t)N_EDGES * 4);
  int*      bsum   = (int*)alloc(64 * 4);
  float*    part   = (float*)alloc((size_t)SMBLK * 8 * 4);
  float*    maxv1  = (float*)alloc(8 * 4);
  float*    maxv2  = (float*)alloc(4);
  float*    colsum = (float*)alloc(HDIM * 4);
  float*    colsq  = (float*)alloc(HDIM * 4);   // adjacent to colsum
  unsigned short* Bt1 = (unsigned short*)alloc((size_t)HDIM * DIM_IN * 2);
  unsigned short* Bt2 = (unsigned short*)alloc((size_t)DIM_OUT * HDIM * 2);
  unsigned short* Btr = (unsigned short*)alloc((size_t)DIM_OUT * DIM_IN * 2);
  float*    bias2  = (float*)alloc(DIM_OUT * 4);
  unsigned short* msg2 = msg1;
  float* asrc2 = asrc1; float* adst2 = adst1;
  (void)n_in; (void)in_sizes; (void)out_size; (void)ws_size;

  hipMemsetAsync(counts, 0, (char*)rowptr - (char*)counts, stream);
  hipMemsetAsync(colsum, 0, 4096, stream);

  // ---- prep (cvt + packs + hist fused) ----
  prep_kernel<<<6570 + HISTBLK, 256, 0, stream>>>(feat, W_heads, W_res, edst,
                                                  feat_bf, Bt1, Btr, counts);

  // ---- layer 1 ----
  dim3 g1(HDIM / 128, (N_NODES + 127) / 128);
  gemm_single<<<g1, 256, 0, stream>>>(feat_bf, Bt1, msg1, nullptr, N_NODES, HDIM, DIM_IN, 1);
  attn1_kernel<<<(N_NODES + 3) / 4, 256, 0, stream>>>(msg1, a_heads, asrc1, adst1, N_NODES);

  int nsb = (N_NODES + 1023) / 1024;   // 49
  scan1_kernel<<<nsb, 256, 0, stream>>>(counts, rowptr, bsum, N_NODES);
  scan23_kernel<<<nsb, 256, 0, stream>>>(rowptr, bsum, N_NODES);

  scatter_max1_kernel<<<SMBLK, 256, 0, stream>>>(esrc, edst, asrc1, adst1, rowptr,
                                                 cursor, colsrc, part, N_EDGES);
  max1_final_kernel<<<1, 64, 0, stream>>>(part, maxv1, SMBLK);
  agg1_kernel<<<N_NODES / 4, 256, 0, stream>>>(msg1, asrc1, adst1, maxv1, rowptr, colsrc, out1_bf);

  colstats_bf512_kernel<<<CSBLK, 256, 0, stream>>>(out1_bf, colsum, colsq, N_NODES);
  foldw2_kernel<<<(DIM_OUT * HDIM + 255) / 256, 256, 0, stream>>>(W_out, colsum, colsq, gamma_h, Bt2);
  bias2_kernel<<<1, 128, 0, stream>>>(W_out, colsum, colsq, gamma_h, beta_h, bias2);

  // ---- layer 2 (gemm2 + residual gemm in one launch) ----
  dim3 g2d(1, (N_NODES + 127) / 128, 2);
  gemm_dual<<<g2d, 256, 0, stream>>>(out1_bf, Bt2, msg2, bias2, HDIM,
                                     feat_bf, Btr, resid, b_res, DIM_IN);
  attn2_kernel<<<(N_NODES + 3) / 4, 256, 0, stream>>>(msg2, a_out, asrc2, adst2, N_NODES);

  max2_part_kernel<<<MAXBLK, 256, 0, stream>>>(esrc, edst, asrc2, adst2, part, N_EDGES);
  max2_final_kernel<<<1, 64, 0, stream>>>(part, maxv2, MAXBLK);
  agg2_kernel<<<N_NODES / 4, 256, 0, stream>>>(msg2, asrc2, adst2, maxv2, rowptr, colsrc, out);

  // layer-2 BN stats + fused BN+residual epilogue
  hipMemsetAsync(colsum, 0, 4096, stream);
  colstats_f128_kernel<<<CSBLK, 256, 0, stream>>>(out, colsum, colsq, N_NODES);
  final_kernel<<<2048, 256, 0, stream>>>(out, resid, colsum, colsq, gamma_o, beta_o,
                                         N_NODES * DIM_OUT);
}

// Round 10
// 755.386 us; speedup vs baseline: 1.2506x; 1.0338x over previous
//
#include <hip/hip_runtime.h>
#include <math.h>

#define N_NODES 50000
#define N_EDGES 1600000
#define DIM_IN  128
#define DIM_HID 64
#define NHEADS  8
#define HDIM    (NHEADS*DIM_HID)   // 512
#define DIM_OUT 128
#define SCBLK   1024               // blocks for scatter pass
#define HISTBLK 2048               // hist sub-grid inside prep
#define NMBLK   64                 // blocks for node-max partial pass
#define LDK     72                 // padded LDS row (bf16 elems)
#define INV_N   2e-5f              // 1/N_NODES
#define CSBLK   400                // blocks for column-stats kernels

typedef __attribute__((ext_vector_type(2))) unsigned short us2;
typedef __attribute__((ext_vector_type(4))) unsigned short us4;
typedef __attribute__((ext_vector_type(8))) unsigned short us8;
typedef __attribute__((ext_vector_type(8))) short bf16x8;
typedef __attribute__((ext_vector_type(4))) float f32x4;

__device__ __forceinline__ float leaky(float x) { return x >= 0.f ? x : 0.2f * x; }
__device__ __forceinline__ float bf2f(unsigned short h) {
  return __uint_as_float(((unsigned)h) << 16);
}
__device__ __forceinline__ unsigned short f2bf(float f) {
  unsigned u = __float_as_uint(f);
  unsigned r = (u + 0x7fffu + ((u >> 16) & 1u)) >> 16;
  return (unsigned short)r;
}
__device__ __forceinline__ float bn_scale(float sum, float sq, float g) {
  float mean = sum * INV_N;
  float var = sq * INV_N - mean * mean;
  return g * rsqrtf(var + 1e-5f);
}

// ---------- fused prep: cvt feat->bf16 | pack W_heads | pack W_res | edge histogram ----------
__global__ void prep_kernel(const float* __restrict__ feat, const float* __restrict__ Wh,
                            const float* __restrict__ Wres, const int* __restrict__ edst,
                            unsigned short* __restrict__ feat_bf,
                            unsigned short* __restrict__ Bt1,
                            unsigned short* __restrict__ Btr,
                            int* __restrict__ counts) {
  int b = blockIdx.x;
  if (b < 6250) {
    int i = b * 256 + threadIdx.x;
    float4 v = *reinterpret_cast<const float4*>(&feat[(size_t)i * 4]);
    us4 o;
    o[0] = f2bf(v.x); o[1] = f2bf(v.y); o[2] = f2bf(v.z); o[3] = f2bf(v.w);
    *reinterpret_cast<us4*>(&feat_bf[(size_t)i * 4]) = o;
  } else if (b < 6506) {
    int idx = (b - 6250) * 256 + threadIdx.x;
    int n = idx >> 7, k = idx & 127;
    Bt1[idx] = f2bf(Wh[(n >> 6) * (DIM_IN * DIM_HID) + k * DIM_HID + (n & 63)]);
  } else if (b < 6570) {
    int idx = (b - 6506) * 256 + threadIdx.x;
    int n = idx >> 7, k = idx & 127;
    Btr[idx] = f2bf(Wres[k * DIM_OUT + n]);
  } else {
    int bid = b - 6570;
    for (int e = bid * 256 + threadIdx.x; e < N_EDGES; e += HISTBLK * 256)
      atomicAdd(&counts[edst[e]], 1);
  }
}

// ---------- fold BN1 (inline from stats) into W_out -> Bt2 [128][512] bf16 ----------
__global__ void foldw2_kernel(const float* __restrict__ W,
                              const float* __restrict__ colsum, const float* __restrict__ colsq,
                              const float* __restrict__ gamma,
                              unsigned short* __restrict__ Bt) {
  int idx = blockIdx.x * 256 + threadIdx.x;
  if (idx >= DIM_OUT * HDIM) return;
  int n = idx >> 9, k = idx & 511;
  float sc = bn_scale(colsum[k], colsq[k], gamma[k]);
  Bt[idx] = f2bf(W[k * DIM_OUT + n] * sc);
}

// ---------- bias2 = shift1^T @ W_out ----------
__global__ void bias2_kernel(const float* __restrict__ W,
                             const float* __restrict__ colsum, const float* __restrict__ colsq,
                             const float* __restrict__ gamma, const float* __restrict__ beta,
                             float* __restrict__ bias2) {
  int j = threadIdx.x;
  if (j >= DIM_OUT) return;
  float s = 0.f;
  for (int c = 0; c < HDIM; ++c) {
    float mean = colsum[c] * INV_N;
    float sc = bn_scale(colsum[c], colsq[c], gamma[c]);
    float shift = beta[c] - mean * sc;
    s = fmaf(shift, W[c * DIM_OUT + j], s);
  }
  bias2[j] = s;
}

// ---------- bf16 MFMA GEMM body ----------
__device__ __forceinline__ void gemm_body(
    const unsigned short* __restrict__ A, const unsigned short* __restrict__ Bt,
    void* __restrict__ Cout, const float* __restrict__ bias,
    int M, int N, int K, int outbf) {
  __shared__ unsigned short As[128 * LDK];
  __shared__ unsigned short Bs[128 * LDK];
  const int tid = threadIdx.x;
  const int lane = tid & 63, wid = tid >> 6;
  const int wr = wid >> 1, wc = wid & 1;
  const int l15 = lane & 15, lhi = lane >> 4;
  const int m0 = blockIdx.y * 128, n0 = blockIdx.x * 128;
  const int srow = tid >> 3;
  const int sc8 = (tid - srow) & 7;
  f32x4 acc[4][4];
#pragma unroll
  for (int i = 0; i < 4; ++i)
#pragma unroll
    for (int j = 0; j < 4; ++j) acc[i][j] = f32x4{0.f, 0.f, 0.f, 0.f};

  for (int k0 = 0; k0 < K; k0 += 64) {
    __syncthreads();
#pragma unroll
    for (int p = 0; p < 4; ++p) {
      int row = p * 32 + srow;
      us8 va = {0, 0, 0, 0, 0, 0, 0, 0};
      int gr = m0 + row;
      if (gr < M) va = *reinterpret_cast<const us8*>(&A[(size_t)gr * K + k0 + sc8 * 8]);
      *reinterpret_cast<us8*>(&As[row * LDK + sc8 * 8]) = va;
      us8 vb = {0, 0, 0, 0, 0, 0, 0, 0};
      int gn = n0 + row;
      if (gn < N) vb = *reinterpret_cast<const us8*>(&Bt[(size_t)gn * K + k0 + sc8 * 8]);
      *reinterpret_cast<us8*>(&Bs[row * LDK + sc8 * 8]) = vb;
    }
    __syncthreads();
#pragma unroll
    for (int kk = 0; kk < 2; ++kk) {
      bf16x8 af[4], bfr[4];
#pragma unroll
      for (int i = 0; i < 4; ++i)
        af[i] = *reinterpret_cast<const bf16x8*>(&As[(wr * 64 + i * 16 + l15) * LDK + kk * 32 + lhi * 8]);
#pragma unroll
      for (int j = 0; j < 4; ++j)
        bfr[j] = *reinterpret_cast<const bf16x8*>(&Bs[(wc * 64 + j * 16 + l15) * LDK + kk * 32 + lhi * 8]);
#pragma unroll
      for (int i = 0; i < 4; ++i)
#pragma unroll
        for (int j = 0; j < 4; ++j)
          acc[i][j] = __builtin_amdgcn_mfma_f32_16x16x32_bf16(af[i], bfr[j], acc[i][j], 0, 0, 0);
    }
  }
#pragma unroll
  for (int j = 0; j < 4; ++j) {
    int col = n0 + wc * 64 + j * 16 + l15;
    float bb = bias ? bias[col] : 0.f;
#pragma unroll
    for (int i = 0; i < 4; ++i) {
      f32x4 v = acc[i][j];
#pragma unroll
      for (int t = 0; t < 4; ++t) {
        int row = m0 + wr * 64 + i * 16 + lhi * 4 + t;
        if (row < M) {
          float o = v[t] + bb;
          if (outbf) ((unsigned short*)Cout)[(size_t)row * N + col] = f2bf(o);
          else       ((float*)Cout)[(size_t)row * N + col] = o;
        }
      }
    }
  }
}

// ---------- gemm1 with fused attn projections (each wave owns 64 rows x one full head) ----------
__global__ __launch_bounds__(256) void gemm1_attn_kernel(
    const unsigned short* __restrict__ A, const unsigned short* __restrict__ Bt,
    unsigned short* __restrict__ Cout, const float* __restrict__ a_heads,
    float* __restrict__ asrc, float* __restrict__ adst) {
  __shared__ unsigned short As[128 * LDK];
  __shared__ unsigned short Bs[128 * LDK];
  const int M = N_NODES, N = HDIM, K = DIM_IN;
  const int tid = threadIdx.x;
  const int lane = tid & 63, wid = tid >> 6;
  const int wr = wid >> 1, wc = wid & 1;
  const int l15 = lane & 15, lhi = lane >> 4;
  const int m0 = blockIdx.y * 128, n0 = blockIdx.x * 128;
  const int srow = tid >> 3;
  const int sc8 = (tid - srow) & 7;
  f32x4 acc[4][4];
#pragma unroll
  for (int i = 0; i < 4; ++i)
#pragma unroll
    for (int j = 0; j < 4; ++j) acc[i][j] = f32x4{0.f, 0.f, 0.f, 0.f};

  for (int k0 = 0; k0 < K; k0 += 64) {
    __syncthreads();
#pragma unroll
    for (int p = 0; p < 4; ++p) {
      int row = p * 32 + srow;
      us8 va = {0, 0, 0, 0, 0, 0, 0, 0};
      int gr = m0 + row;
      if (gr < M) va = *reinterpret_cast<const us8*>(&A[(size_t)gr * K + k0 + sc8 * 8]);
      *reinterpret_cast<us8*>(&As[row * LDK + sc8 * 8]) = va;
      us8 vb = {0, 0, 0, 0, 0, 0, 0, 0};
      int gn = n0 + row;
      if (gn < N) vb = *reinterpret_cast<const us8*>(&Bt[(size_t)gn * K + k0 + sc8 * 8]);
      *reinterpret_cast<us8*>(&Bs[row * LDK + sc8 * 8]) = vb;
    }
    __syncthreads();
#pragma unroll
    for (int kk = 0; kk < 2; ++kk) {
      bf16x8 af[4], bfr[4];
#pragma unroll
      for (int i = 0; i < 4; ++i)
        af[i] = *reinterpret_cast<const bf16x8*>(&As[(wr * 64 + i * 16 + l15) * LDK + kk * 32 + lhi * 8]);
#pragma unroll
      for (int j = 0; j < 4; ++j)
        bfr[j] = *reinterpret_cast<const bf16x8*>(&Bs[(wc * 64 + j * 16 + l15) * LDK + kk * 32 + lhi * 8]);
#pragma unroll
      for (int i = 0; i < 4; ++i)
#pragma unroll
        for (int j = 0; j < 4; ++j)
          acc[i][j] = __builtin_amdgcn_mfma_f32_16x16x32_bf16(af[i], bfr[j], acc[i][j], 0, 0, 0);
    }
  }
  // C store
#pragma unroll
  for (int j = 0; j < 4; ++j) {
    int col = n0 + wc * 64 + j * 16 + l15;
#pragma unroll
    for (int i = 0; i < 4; ++i) {
      f32x4 v = acc[i][j];
#pragma unroll
      for (int t = 0; t < 4; ++t) {
        int row = m0 + wr * 64 + i * 16 + lhi * 4 + t;
        if (row < M) Cout[(size_t)row * N + col] = f2bf(v[t]);
      }
    }
  }
  // fused attn: head h for this wave; p = j*16+l15 within head
  const int h = blockIdx.x * 2 + wc;
  float aS[4], aD[4];
#pragma unroll
  for (int j = 0; j < 4; ++j) {
    aS[j] = a_heads[h * 128 + j * 16 + l15];
    aD[j] = a_heads[h * 128 + 64 + j * 16 + l15];
  }
#pragma unroll
  for (int i = 0; i < 4; ++i) {
#pragma unroll
    for (int t = 0; t < 4; ++t) {
      float s = 0.f, d = 0.f;
#pragma unroll
      for (int j = 0; j < 4; ++j) {
        float v = acc[i][j][t];
        s = fmaf(v, aS[j], s);
        d = fmaf(v, aD[j], d);
      }
      s += __shfl_xor(s, 1, 64); s += __shfl_xor(s, 2, 64);
      s += __shfl_xor(s, 4, 64); s += __shfl_xor(s, 8, 64);
      d += __shfl_xor(d, 1, 64); d += __shfl_xor(d, 2, 64);
      d += __shfl_xor(d, 4, 64); d += __shfl_xor(d, 8, 64);
      int row = m0 + wr * 64 + i * 16 + lhi * 4 + t;
      if (l15 == 0 && row < M) {
        asrc[(size_t)row * 8 + h] = s;
        adst[(size_t)row * 8 + h] = d;
      }
    }
  }
}

// z=0: gemm2 -> msg2 bf16; z=1: residual -> resid f32
__global__ __launch_bounds__(256) void gemm_dual(
    const unsigned short* __restrict__ A0, const unsigned short* __restrict__ Bt0,
    void* __restrict__ C0, const float* __restrict__ b0, int K0,
    const unsigned short* __restrict__ A1, const unsigned short* __restrict__ Bt1,
    void* __restrict__ C1, const float* __restrict__ b1, int K1) {
  if (blockIdx.z == 0) gemm_body(A0, Bt0, C0, b0, N_NODES, DIM_OUT, K0, 1);
  else                 gemm_body(A1, Bt1, C1, b1, N_NODES, DIM_OUT, K1, 0);
}

// ---------- attn projections layer 2 (bf16 msg) ----------
__global__ __launch_bounds__(256) void attn2_kernel(
    const unsigned short* __restrict__ msg, const float* __restrict__ a_out,
    float* __restrict__ asrc, float* __restrict__ adst, int Nn) {
  int lane = threadIdx.x & 63;
  int n = blockIdx.x * 4 + (threadIdx.x >> 6);
  if (n >= Nn) return;
  us2 v = *reinterpret_cast<const us2*>(&msg[(size_t)n * 128 + lane * 2]);
  float f0 = bf2f(v[0]), f1 = bf2f(v[1]);
  float s = f0 * a_out[2 * lane] + f1 * a_out[2 * lane + 1];
  float d = f0 * a_out[128 + 2 * lane] + f1 * a_out[128 + 2 * lane + 1];
#pragma unroll
  for (int off = 32; off; off >>= 1) {
    s += __shfl_xor(s, off, 64);
    d += __shfl_xor(d, off, 64);
  }
  if (lane == 0) { asrc[n] = s; adst[n] = d; }
}

// ---------- node-max partial: per-stripe (idx&7) max of a[] and b[] ----------
__global__ __launch_bounds__(256) void nodemax_part_kernel(
    const float* __restrict__ a, const float* __restrict__ b,
    float* __restrict__ part, int total) {
  int t = threadIdx.x;
  float ms = -3.4e38f, md = -3.4e38f;
  for (int i = blockIdx.x * 256 + t; i < total; i += NMBLK * 256) {
    ms = fmaxf(ms, a[i]);
    md = fmaxf(md, b[i]);
  }
  // stride NMBLK*256 is a multiple of 8 -> each thread's stripe = t&7
  ms = fmaxf(ms, __shfl_xor(ms, 8, 64));
  ms = fmaxf(ms, __shfl_xor(ms, 16, 64));
  ms = fmaxf(ms, __shfl_xor(ms, 32, 64));
  md = fmaxf(md, __shfl_xor(md, 8, 64));
  md = fmaxf(md, __shfl_xor(md, 16, 64));
  md = fmaxf(md, __shfl_xor(md, 32, 64));
  __shared__ float sh[4][8][2];
  int wv = t >> 6, ln = t & 63;
  if (ln < 8) { sh[wv][ln][0] = ms; sh[wv][ln][1] = md; }
  __syncthreads();
  if (t < 8) {
    float s4 = fmaxf(fmaxf(sh[0][t][0], sh[1][t][0]), fmaxf(sh[2][t][0], sh[3][t][0]));
    float d4 = fmaxf(fmaxf(sh[0][t][1], sh[1][t][1]), fmaxf(sh[2][t][1], sh[3][t][1]));
    part[blockIdx.x * 16 + t * 2] = s4;
    part[blockIdx.x * 16 + t * 2 + 1] = d4;
  }
}

// ---------- node-max final: maxv[h] = smax[h] + dmax[h]  (H=8) or maxv[0]=Smax+Dmax (H=1) ----------
__global__ void nodemax_final_kernel(const float* __restrict__ part, float* __restrict__ maxv, int H) {
  int t = threadIdx.x;          // 64
  int ch = t & 15, k = t >> 4;  // 16 chains x 4-way stride
  float m = -3.4e38f;
  for (int i = k; i < NMBLK; i += 4) m = fmaxf(m, part[i * 16 + ch]);
  m = fmaxf(m, __shfl_xor(m, 16, 64));
  m = fmaxf(m, __shfl_xor(m, 32, 64));
  float S = __shfl(m, (t & 7) * 2, 64);
  float D = __shfl(m, (t & 7) * 2 + 1, 64);
  if (H == 8) {
    if (t < 8) maxv[t] = S + D;
  } else {
    float Sm = S, Dm = D;   // lanes 0..7 hold distinct stripes
    Sm = fmaxf(Sm, __shfl_xor(Sm, 1, 64)); Sm = fmaxf(Sm, __shfl_xor(Sm, 2, 64));
    Sm = fmaxf(Sm, __shfl_xor(Sm, 4, 64));
    Dm = fmaxf(Dm, __shfl_xor(Dm, 1, 64)); Dm = fmaxf(Dm, __shfl_xor(Dm, 2, 64));
    Dm = fmaxf(Dm, __shfl_xor(Dm, 4, 64));
    if (t == 0) maxv[0] = Sm + Dm;
  }
}

// ---------- CSR: local scan ----------
__global__ __launch_bounds__(256) void scan1_kernel(
    const int* __restrict__ counts, int* __restrict__ rowptr, int* __restrict__ bsum, int n) {
  __shared__ int wsum[4];
  int b0 = blockIdx.x * 1024;
  int t = threadIdx.x;
  int lane = t & 63, w = t >> 6;
  int v[4]; int s = 0;
#pragma unroll
  for (int i = 0; i < 4; ++i) {
    int idx = b0 + t * 4 + i;
    v[i] = (idx < n) ? counts[idx] : 0;
    s += v[i];
  }
  int x = s;
#pragma unroll
  for (int off = 1; off < 64; off <<= 1) {
    int y = __shfl_up(x, off, 64);
    if (lane >= off) x += y;
  }
  if (lane == 63) wsum[w] = x;
  __syncthreads();
  int wof = 0;
  for (int i = 0; i < w; ++i) wof += wsum[i];
  int run = wof + x - s;
#pragma unroll
  for (int i = 0; i < 4; ++i) {
    int idx = b0 + t * 4 + i;
    if (idx < n) rowptr[idx] = run;
    run += v[i];
  }
  if (t == 255) bsum[blockIdx.x] = wof + x;
}

// ---------- CSR: carry propagate ----------
__global__ __launch_bounds__(256) void scan23_kernel(
    int* __restrict__ rowptr, const int* __restrict__ bsum, int n) {
  __shared__ int carry_sh;
  int b = blockIdx.x, t = threadIdx.x;
  if (t < 64) {
    int v = (t < b) ? bsum[t] : 0;
#pragma unroll
    for (int off = 32; off; off >>= 1) v += __shfl_xor(v, off, 64);
    if (t == 0) carry_sh = v;
  }
  __syncthreads();
  int carry = carry_sh;
  int i0 = b * 1024;
#pragma unroll
  for (int q = 0; q < 4; ++q) {
    int i = i0 + q * 256 + t;
    if (i < n) rowptr[i] += carry;
  }
  if (b == gridDim.x - 1 && t == 0) rowptr[n] = N_EDGES;
}

// ---------- pure scatter (max fusion removed) ----------
__global__ __launch_bounds__(256) void scatter_kernel(
    const int* __restrict__ esrc, const int* __restrict__ edst,
    const int* __restrict__ rowptr, int* __restrict__ cursor,
    int* __restrict__ colsrc, int E) {
  for (int e = blockIdx.x * blockDim.x + threadIdx.x; e < E; e += gridDim.x * blockDim.x) {
    int d = edst[e];
    int pos = rowptr[d] + atomicAdd(&cursor[d], 1);
    colsrc[pos] = esrc[e];
  }
}

// ---------- layer-1 aggregation: wave-per-node, us8 gathers, shfl coefs ----------
__global__ __launch_bounds__(256) void agg1_kernel(
    const unsigned short* __restrict__ msg, const float* __restrict__ asrc,
    const float* __restrict__ adst, const float* __restrict__ maxv,
    const int* __restrict__ rowptr, const int* __restrict__ colsrc,
    unsigned short* __restrict__ out) {
  int wv = threadIdx.x >> 6, l = threadIdx.x & 63;
  int n = blockIdx.x * 4 + wv;
  const int h = l >> 3;
  const int eloc = l & 7;
  const int hbase = l & 56;
  float M = maxv[h];
  float ad = adst[(size_t)n * 8 + h];
  int e0 = rowptr[n], e1 = rowptr[n + 1];
  float acc[8];
#pragma unroll
  for (int j = 0; j < 8; ++j) acc[j] = 0.f;
  float ds = 0.f;
  int base = e0;
  for (; base + 8 <= e1; base += 8) {
    int sreg = colsrc[base + eloc];
    float x = asrc[(size_t)sreg * 8 + h] + ad;
    x = x >= 0.f ? x : 0.2f * x;
    float creg = __expf(x - M);
#pragma unroll
    for (int e = 0; e < 8; ++e) {
      float c = __shfl(creg, hbase | e, 64);
      int s = __shfl(sreg, e, 64);
      ds += c;
      us8 m = *reinterpret_cast<const us8*>(&msg[(size_t)s * HDIM + l * 8]);
#pragma unroll
      for (int j = 0; j < 8; ++j) acc[j] = fmaf(bf2f(m[j]), c, acc[j]);
    }
  }
  if (base < e1) {
    int cnt = e1 - base;
    int sreg = 0; float creg = 0.f;
    if (eloc < cnt) {
      sreg = colsrc[base + eloc];
      float x = asrc[(size_t)sreg * 8 + h] + ad;
      x = x >= 0.f ? x : 0.2f * x;
      creg = __expf(x - M);
    }
    for (int e = 0; e < cnt; ++e) {
      float c = __shfl(creg, hbase | e, 64);
      int s = __shfl(sreg, e, 64);
      ds += c;
      us8 m = *reinterpret_cast<const us8*>(&msg[(size_t)s * HDIM + l * 8]);
#pragma unroll
      for (int j = 0; j < 8; ++j) acc[j] = fmaf(bf2f(m[j]), c, acc[j]);
    }
  }
  float inv = 1.0f / (ds + 1e-10f);
  us8 o;
#pragma unroll
  for (int j = 0; j < 8; ++j) o[j] = f2bf(acc[j] * inv);
  *reinterpret_cast<us8*>(&out[(size_t)n * HDIM + l * 8]) = o;
}

// ---------- layer-2 aggregation: wave-per-node, shfl-broadcast coefs ----------
__global__ __launch_bounds__(256) void agg2_kernel(
    const unsigned short* __restrict__ msg, const float* __restrict__ asrc,
    const float* __restrict__ adst, const float* __restrict__ maxv,
    const int* __restrict__ rowptr, const int* __restrict__ colsrc,
    float* __restrict__ out) {
  int wv = threadIdx.x >> 6, ln = threadIdx.x & 63;
  int n = blockIdx.x * 4 + wv;
  float M = maxv[0];
  float ad = adst[n];
  int e0 = rowptr[n], e1 = rowptr[n + 1];
  float a0 = 0.f, a1 = 0.f, ds = 0.f;
  for (int base = e0; base < e1; base += 64) {
    int cnt = min(64, e1 - base);
    int s_reg = 0; float c_reg = 0.f;
    if (ln < cnt) {
      s_reg = colsrc[base + ln];
      float x = asrc[s_reg] + ad;
      x = x >= 0.f ? x : 0.2f * x;
      c_reg = __expf(x - M);
    }
    int e = 0;
    for (; e + 4 <= cnt; e += 4) {
      int s0 = __shfl(s_reg, e, 64),     s1 = __shfl(s_reg, e + 1, 64);
      int s2 = __shfl(s_reg, e + 2, 64), s3 = __shfl(s_reg, e + 3, 64);
      float c0 = __shfl(c_reg, e, 64),     c1 = __shfl(c_reg, e + 1, 64);
      float c2 = __shfl(c_reg, e + 2, 64), c3 = __shfl(c_reg, e + 3, 64);
      us2 m0 = *reinterpret_cast<const us2*>(&msg[(size_t)s0 * 128 + 2 * ln]);
      us2 m1 = *reinterpret_cast<const us2*>(&msg[(size_t)s1 * 128 + 2 * ln]);
      us2 m2 = *reinterpret_cast<const us2*>(&msg[(size_t)s2 * 128 + 2 * ln]);
      us2 m3 = *reinterpret_cast<const us2*>(&msg[(size_t)s3 * 128 + 2 * ln]);
      ds += (c0 + c1) + (c2 + c3);
      a0 = fmaf(bf2f(m0[0]), c0, a0); a1 = fmaf(bf2f(m0[1]), c0, a1);
      a0 = fmaf(bf2f(m1[0]), c1, a0); a1 = fmaf(bf2f(m1[1]), c1, a1);
      a0 = fmaf(bf2f(m2[0]), c2, a0); a1 = fmaf(bf2f(m2[1]), c2, a1);
      a0 = fmaf(bf2f(m3[0]), c3, a0); a1 = fmaf(bf2f(m3[1]), c3, a1);
    }
    for (; e < cnt; ++e) {
      int s = __shfl(s_reg, e, 64);
      float c = __shfl(c_reg, e, 64);
      us2 m = *reinterpret_cast<const us2*>(&msg[(size_t)s * 128 + 2 * ln]);
      ds += c;
      a0 = fmaf(bf2f(m[0]), c, a0);
      a1 = fmaf(bf2f(m[1]), c, a1);
    }
  }
  float inv = 1.0f / (ds + 1e-10f);
  float2 r; r.x = a0 * inv; r.y = a1 * inv;
  *reinterpret_cast<float2*>(&out[(size_t)n * 128 + 2 * ln]) = r;
}

// ---------- column stats, bf16 [M][512] ----------
__global__ __launch_bounds__(256) void colstats_bf512_kernel(
    const unsigned short* __restrict__ X, float* __restrict__ sums,
    float* __restrict__ sqs, int M) {
  int tid = threadIdx.x;
  int cg = tid & 63;
  int wv = tid >> 6;
  int rows = (M + gridDim.x - 1) / gridDim.x;
  int r0 = blockIdx.x * rows;
  int r1 = min(M, r0 + rows);
  float s[8], q[8];
#pragma unroll
  for (int j = 0; j < 8; ++j) { s[j] = 0.f; q[j] = 0.f; }
  for (int r = r0 + wv; r < r1; r += 4) {
    us8 v = *reinterpret_cast<const us8*>(&X[(size_t)r * 512 + cg * 8]);
#pragma unroll
    for (int j = 0; j < 8; ++j) {
      float f = bf2f(v[j]);
      s[j] += f; q[j] = fmaf(f, f, q[j]);
    }
  }
  __shared__ float shs[3][512];
  __shared__ float shq[3][512];
  if (wv > 0) {
#pragma unroll
    for (int j = 0; j < 8; ++j) {
      shs[wv - 1][cg * 8 + j] = s[j];
      shq[wv - 1][cg * 8 + j] = q[j];
    }
  }
  __syncthreads();
  if (wv == 0) {
#pragma unroll
    for (int j = 0; j < 8; ++j) {
      int c = cg * 8 + j;
      atomicAdd(&sums[c], s[j] + shs[0][c] + shs[1][c] + shs[2][c]);
      atomicAdd(&sqs[c],  q[j] + shq[0][c] + shq[1][c] + shq[2][c]);
    }
  }
}

// ---------- column stats, fp32 [M][128] ----------
__global__ __launch_bounds__(256) void colstats_f128_kernel(
    const float* __restrict__ X, float* __restrict__ sums,
    float* __restrict__ sqs, int M) {
  int tid = threadIdx.x;
  int g = tid & 31;
  int slot = tid >> 5;
  int rows = (M + gridDim.x - 1) / gridDim.x;
  int r0 = blockIdx.x * rows;
  int r1 = min(M, r0 + rows);
  float s[4] = {0.f, 0.f, 0.f, 0.f}, q[4] = {0.f, 0.f, 0.f, 0.f};
  for (int r = r0 + slot; r < r1; r += 8) {
    float4 v = *reinterpret_cast<const float4*>(&X[(size_t)r * 128 + g * 4]);
    s[0] += v.x; q[0] = fmaf(v.x, v.x, q[0]);
    s[1] += v.y; q[1] = fmaf(v.y, v.y, q[1]);
    s[2] += v.z; q[2] = fmaf(v.z, v.z, q[2]);
    s[3] += v.w; q[3] = fmaf(v.w, v.w, q[3]);
  }
#pragma unroll
  for (int j = 0; j < 4; ++j) {
    s[j] += __shfl_xor(s[j], 32, 64);
    q[j] += __shfl_xor(q[j], 32, 64);
  }
  __shared__ float shs[3][128];
  __shared__ float shq[3][128];
  int wv = tid >> 6, ln = tid & 63;
  if (wv > 0 && ln < 32) {
#pragma unroll
    for (int j = 0; j < 4; ++j) {
      shs[wv - 1][g * 4 + j] = s[j];
      shq[wv - 1][g * 4 + j] = q[j];
    }
  }
  __syncthreads();
  if (wv == 0 && ln < 32) {
#pragma unroll
    for (int j = 0; j < 4; ++j) {
      int c = g * 4 + j;
      atomicAdd(&sums[c], s[j] + shs[0][c] + shs[1][c] + shs[2][c]);
      atomicAdd(&sqs[c],  q[j] + shq[0][c] + shq[1][c] + shq[2][c]);
    }
  }
}

// ---------- final: BN(out2) + residual ----------
__global__ void final_kernel(float* __restrict__ out, const float* __restrict__ resid,
                             const float* __restrict__ colsum, const float* __restrict__ colsq,
                             const float* __restrict__ gamma, const float* __restrict__ beta,
                             int total) {
  for (int i = blockIdx.x * blockDim.x + threadIdx.x; i < total; i += gridDim.x * blockDim.x) {
    int c = i & 127;
    float mean = colsum[c] * INV_N;
    float sc = bn_scale(colsum[c], colsq[c], gamma[c]);
    float sh = beta[c] - mean * sc;
    out[i] = fmaf(out[i], sc, sh) + resid[i];
  }
}

// ==================== host ====================
extern "C" void kernel_launch(void* const* d_in, const int* in_sizes, int n_in,
                              void* d_out, int out_size, void* d_ws, size_t ws_size,
                              hipStream_t stream) {
  const float* feat    = (const float*)d_in[0];
  const int*   edges   = (const int*)d_in[1];
  const int*   esrc    = edges;
  const int*   edst    = edges + N_EDGES;
  const float* W_heads = (const float*)d_in[2];
  const float* a_heads = (const float*)d_in[3];
  const float* gamma_h = (const float*)d_in[4];
  const float* beta_h  = (const float*)d_in[5];
  const float* W_out   = (const float*)d_in[6];
  const float* a_out   = (const float*)d_in[7];
  const float* gamma_o = (const float*)d_in[8];
  const float* beta_o  = (const float*)d_in[9];
  const float* W_res   = (const float*)d_in[10];
  const float* b_res   = (const float*)d_in[11];
  float* out = (float*)d_out;

  char* ws = (char*)d_ws;
  size_t off = 0;
  auto alloc = [&](size_t bytes) {
    void* p = ws + off;
    off = (off + bytes + 255) & ~(size_t)255;
    return p;
  };
  unsigned short* msg1    = (unsigned short*)alloc((size_t)N_NODES * HDIM * 2);  // reused as msg2
  unsigned short* out1_bf = (unsigned short*)alloc((size_t)N_NODES * HDIM * 2);
  unsigned short* feat_bf = (unsigned short*)alloc((size_t)N_NODES * DIM_IN * 2);
  float*    resid  = (float*)alloc((size_t)N_NODES * DIM_OUT * 4);
  float*    asrc1  = (float*)alloc((size_t)N_NODES * NHEADS * 4); // reused as asrc2
  float*    adst1  = (float*)alloc((size_t)N_NODES * NHEADS * 4); // reused as adst2
  int*      counts = (int*)alloc((size_t)N_NODES * 4);
  int*      cursor = (int*)alloc((size_t)N_NODES * 4);   // adjacent to counts
  int*      rowptr = (int*)alloc((size_t)(N_NODES + 1) * 4);
  int*      colsrc = (int*)alloc((size_t)N_EDGES * 4);
  int*      bsum   = (int*)alloc(64 * 4);
  float*    partmx = (float*)alloc((size_t)NMBLK * 16 * 4);
  float*    maxv1  = (float*)alloc(8 * 4);
  float*    maxv2  = (float*)alloc(4);
  float*    colsum = (float*)alloc(HDIM * 4);
  float*    colsq  = (float*)alloc(HDIM * 4);   // adjacent to colsum
  unsigned short* Bt1 = (unsigned short*)alloc((size_t)HDIM * DIM_IN * 2);
  unsigned short* Bt2 = (unsigned short*)alloc((size_t)DIM_OUT * HDIM * 2);
  unsigned short* Btr = (unsigned short*)alloc((size_t)DIM_OUT * DIM_IN * 2);
  float*    bias2  = (float*)alloc(DIM_OUT * 4);
  unsigned short* msg2 = msg1;
  float* asrc2 = asrc1; float* adst2 = adst1;
  (void)n_in; (void)in_sizes; (void)out_size; (void)ws_size;

  hipMemsetAsync(counts, 0, (char*)rowptr - (char*)counts, stream);
  hipMemsetAsync(colsum, 0, 4096, stream);

  // ---- prep (cvt + packs + hist fused) ----
  prep_kernel<<<6570 + HISTBLK, 256, 0, stream>>>(feat, W_heads, W_res, edst,
                                                  feat_bf, Bt1, Btr, counts);

  // ---- layer 1: GEMM with fused attn projections ----
  dim3 g1(HDIM / 128, (N_NODES + 127) / 128);
  gemm1_attn_kernel<<<g1, 256, 0, stream>>>(feat_bf, Bt1, msg1, a_heads, asrc1, adst1);
  nodemax_part_kernel<<<NMBLK, 256, 0, stream>>>(asrc1, adst1, partmx, N_NODES * 8);
  nodemax_final_kernel<<<1, 64, 0, stream>>>(partmx, maxv1, 8);

  int nsb = (N_NODES + 1023) / 1024;   // 49
  scan1_kernel<<<nsb, 256, 0, stream>>>(counts, rowptr, bsum, N_NODES);
  scan23_kernel<<<nsb, 256, 0, stream>>>(rowptr, bsum, N_NODES);

  scatter_kernel<<<SCBLK, 256, 0, stream>>>(esrc, edst, rowptr, cursor, colsrc, N_EDGES);
  agg1_kernel<<<N_NODES / 4, 256, 0, stream>>>(msg1, asrc1, adst1, maxv1, rowptr, colsrc, out1_bf);

  colstats_bf512_kernel<<<CSBLK, 256, 0, stream>>>(out1_bf, colsum, colsq, N_NODES);
  foldw2_kernel<<<(DIM_OUT * HDIM + 255) / 256, 256, 0, stream>>>(W_out, colsum, colsq, gamma_h, Bt2);
  bias2_kernel<<<1, 128, 0, stream>>>(W_out, colsum, colsq, gamma_h, beta_h, bias2);

  // ---- layer 2 (gemm2 + residual gemm in one launch) ----
  dim3 g2d(1, (N_NODES + 127) / 128, 2);
  gemm_dual<<<g2d, 256, 0, stream>>>(out1_bf, Bt2, msg2, bias2, HDIM,
                                     feat_bf, Btr, resid, b_res, DIM_IN);
  attn2_kernel<<<(N_NODES + 3) / 4, 256, 0, stream>>>(msg2, a_out, asrc2, adst2, N_NODES);
  nodemax_part_kernel<<<NMBLK, 256, 0, stream>>>(asrc2, adst2, partmx, N_NODES);
  nodemax_final_kernel<<<1, 64, 0, stream>>>(partmx, maxv2, 1);

  agg2_kernel<<<N_NODES / 4, 256, 0, stream>>>(msg2, asrc2, adst2, maxv2, rowptr, colsrc, out);

  // layer-2 BN stats + fused BN+residual epilogue
  hipMemsetAsync(colsum, 0, 4096, stream);
  colstats_f128_kernel<<<CSBLK, 256, 0, stream>>>(out, colsum, colsq, N_NODES);
  final_kernel<<<2048, 256, 0, stream>>>(out, resid, colsum, colsq, gamma_o, beta_o,
                                         N_NODES * DIM_OUT);
}

// Round 11
// 716.808 us; speedup vs baseline: 1.3179x; 1.0538x over previous
//
#include <hip/hip_runtime.h>
#include <math.h>

#define N_NODES 50000
#define N_EDGES 1600000
#define DIM_IN  128
#define DIM_HID 64
#define NHEADS  8
#define HDIM    (NHEADS*DIM_HID)   // 512
#define DIM_OUT 128
#define SCBLK   1024               // blocks for scatter pass
#define HISTBLK 2048               // hist sub-grid inside prep
#define NMBLK   64                 // blocks for node-max partial pass
#define LDK     72                 // padded LDS row (bf16 elems)
#define INV_N   2e-5f              // 1/N_NODES
#define CSBLK   400                // blocks for column-stats kernels

typedef __attribute__((ext_vector_type(2))) unsigned short us2;
typedef __attribute__((ext_vector_type(4))) unsigned short us4;
typedef __attribute__((ext_vector_type(8))) unsigned short us8;
typedef __attribute__((ext_vector_type(8))) short bf16x8;
typedef __attribute__((ext_vector_type(4))) float f32x4;

__device__ __forceinline__ float leaky(float x) { return x >= 0.f ? x : 0.2f * x; }
__device__ __forceinline__ float bf2f(unsigned short h) {
  return __uint_as_float(((unsigned)h) << 16);
}
__device__ __forceinline__ unsigned short f2bf(float f) {
  unsigned u = __float_as_uint(f);
  unsigned r = (u + 0x7fffu + ((u >> 16) & 1u)) >> 16;
  return (unsigned short)r;
}
__device__ __forceinline__ float bn_scale(float sum, float sq, float g) {
  float mean = sum * INV_N;
  float var = sq * INV_N - mean * mean;
  return g * rsqrtf(var + 1e-5f);
}

// ---------- fused prep: cvt feat->bf16 | pack W_heads | pack W_res | edge histogram ----------
__global__ void prep_kernel(const float* __restrict__ feat, const float* __restrict__ Wh,
                            const float* __restrict__ Wres, const int* __restrict__ edst,
                            unsigned short* __restrict__ feat_bf,
                            unsigned short* __restrict__ Bt1,
                            unsigned short* __restrict__ Btr,
                            int* __restrict__ counts) {
  int b = blockIdx.x;
  if (b < 6250) {
    int i = b * 256 + threadIdx.x;
    float4 v = *reinterpret_cast<const float4*>(&feat[(size_t)i * 4]);
    us4 o;
    o[0] = f2bf(v.x); o[1] = f2bf(v.y); o[2] = f2bf(v.z); o[3] = f2bf(v.w);
    *reinterpret_cast<us4*>(&feat_bf[(size_t)i * 4]) = o;
  } else if (b < 6506) {
    int idx = (b - 6250) * 256 + threadIdx.x;
    int n = idx >> 7, k = idx & 127;
    Bt1[idx] = f2bf(Wh[(n >> 6) * (DIM_IN * DIM_HID) + k * DIM_HID + (n & 63)]);
  } else if (b < 6570) {
    int idx = (b - 6506) * 256 + threadIdx.x;
    int n = idx >> 7, k = idx & 127;
    Btr[idx] = f2bf(Wres[k * DIM_OUT + n]);
  } else {
    int bid = b - 6570;
    for (int e = bid * 256 + threadIdx.x; e < N_EDGES; e += HISTBLK * 256)
      atomicAdd(&counts[edst[e]], 1);
  }
}

// ---------- fold BN1 into W_out -> Bt2 [128][512] bf16 + fused bias2 reduction ----------
// 256 blocks; each block covers one output column n (k-range half). bias2 pre-zeroed.
__global__ __launch_bounds__(256) void foldw2_kernel(
    const float* __restrict__ W,
    const float* __restrict__ colsum, const float* __restrict__ colsq,
    const float* __restrict__ gamma, const float* __restrict__ beta,
    unsigned short* __restrict__ Bt, float* __restrict__ bias2) {
  int idx = blockIdx.x * 256 + threadIdx.x;
  int n = idx >> 9, k = idx & 511;
  float mean = colsum[k] * INV_N;
  float sc = bn_scale(colsum[k], colsq[k], gamma[k]);
  float w = W[k * DIM_OUT + n];
  Bt[idx] = f2bf(w * sc);
  float shift = beta[k] - mean * sc;
  __shared__ float red[256];
  red[threadIdx.x] = shift * w;
  __syncthreads();
#pragma unroll
  for (int off = 128; off; off >>= 1) {
    if (threadIdx.x < off) red[threadIdx.x] += red[threadIdx.x + off];
    __syncthreads();
  }
  if (threadIdx.x == 0) atomicAdd(&bias2[n], red[0]);
}

// ---------- bf16 MFMA GEMM body (shared mem passed in) ----------
__device__ __forceinline__ void gemm_body(
    unsigned short* As, unsigned short* Bs,
    const unsigned short* __restrict__ A, const unsigned short* __restrict__ Bt,
    void* __restrict__ Cout, const float* __restrict__ bias,
    int M, int N, int K, int outbf) {
  const int tid = threadIdx.x;
  const int lane = tid & 63, wid = tid >> 6;
  const int wr = wid >> 1, wc = wid & 1;
  const int l15 = lane & 15, lhi = lane >> 4;
  const int m0 = blockIdx.y * 128, n0 = blockIdx.x * 128;
  const int srow = tid >> 3;
  const int sc8 = (tid - srow) & 7;
  f32x4 acc[4][4];
#pragma unroll
  for (int i = 0; i < 4; ++i)
#pragma unroll
    for (int j = 0; j < 4; ++j) acc[i][j] = f32x4{0.f, 0.f, 0.f, 0.f};

  for (int k0 = 0; k0 < K; k0 += 64) {
    __syncthreads();
#pragma unroll
    for (int p = 0; p < 4; ++p) {
      int row = p * 32 + srow;
      us8 va = {0, 0, 0, 0, 0, 0, 0, 0};
      int gr = m0 + row;
      if (gr < M) va = *reinterpret_cast<const us8*>(&A[(size_t)gr * K + k0 + sc8 * 8]);
      *reinterpret_cast<us8*>(&As[row * LDK + sc8 * 8]) = va;
      us8 vb = {0, 0, 0, 0, 0, 0, 0, 0};
      int gn = n0 + row;
      if (gn < N) vb = *reinterpret_cast<const us8*>(&Bt[(size_t)gn * K + k0 + sc8 * 8]);
      *reinterpret_cast<us8*>(&Bs[row * LDK + sc8 * 8]) = vb;
    }
    __syncthreads();
#pragma unroll
    for (int kk = 0; kk < 2; ++kk) {
      bf16x8 af[4], bfr[4];
#pragma unroll
      for (int i = 0; i < 4; ++i)
        af[i] = *reinterpret_cast<const bf16x8*>(&As[(wr * 64 + i * 16 + l15) * LDK + kk * 32 + lhi * 8]);
#pragma unroll
      for (int j = 0; j < 4; ++j)
        bfr[j] = *reinterpret_cast<const bf16x8*>(&Bs[(wc * 64 + j * 16 + l15) * LDK + kk * 32 + lhi * 8]);
#pragma unroll
      for (int i = 0; i < 4; ++i)
#pragma unroll
        for (int j = 0; j < 4; ++j)
          acc[i][j] = __builtin_amdgcn_mfma_f32_16x16x32_bf16(af[i], bfr[j], acc[i][j], 0, 0, 0);
    }
  }
#pragma unroll
  for (int j = 0; j < 4; ++j) {
    int col = n0 + wc * 64 + j * 16 + l15;
    float bb = bias ? bias[col] : 0.f;
#pragma unroll
    for (int i = 0; i < 4; ++i) {
      f32x4 v = acc[i][j];
#pragma unroll
      for (int t = 0; t < 4; ++t) {
        int row = m0 + wr * 64 + i * 16 + lhi * 4 + t;
        if (row < M) {
          float o = v[t] + bb;
          if (outbf) ((unsigned short*)Cout)[(size_t)row * N + col] = f2bf(o);
          else       ((float*)Cout)[(size_t)row * N + col] = o;
        }
      }
    }
  }
}

// ---------- gemm1 with fused attn projections (each wave owns 64 rows x one full head) ----------
__global__ __launch_bounds__(256) void gemm1_attn_kernel(
    const unsigned short* __restrict__ A, const unsigned short* __restrict__ Bt,
    unsigned short* __restrict__ Cout, const float* __restrict__ a_heads,
    float* __restrict__ asrc, float* __restrict__ adst) {
  __shared__ unsigned short As[128 * LDK];
  __shared__ unsigned short Bs[128 * LDK];
  const int M = N_NODES, N = HDIM, K = DIM_IN;
  const int tid = threadIdx.x;
  const int lane = tid & 63, wid = tid >> 6;
  const int wr = wid >> 1, wc = wid & 1;
  const int l15 = lane & 15, lhi = lane >> 4;
  const int m0 = blockIdx.y * 128, n0 = blockIdx.x * 128;
  const int srow = tid >> 3;
  const int sc8 = (tid - srow) & 7;
  f32x4 acc[4][4];
#pragma unroll
  for (int i = 0; i < 4; ++i)
#pragma unroll
    for (int j = 0; j < 4; ++j) acc[i][j] = f32x4{0.f, 0.f, 0.f, 0.f};

  for (int k0 = 0; k0 < K; k0 += 64) {
    __syncthreads();
#pragma unroll
    for (int p = 0; p < 4; ++p) {
      int row = p * 32 + srow;
      us8 va = {0, 0, 0, 0, 0, 0, 0, 0};
      int gr = m0 + row;
      if (gr < M) va = *reinterpret_cast<const us8*>(&A[(size_t)gr * K + k0 + sc8 * 8]);
      *reinterpret_cast<us8*>(&As[row * LDK + sc8 * 8]) = va;
      us8 vb = {0, 0, 0, 0, 0, 0, 0, 0};
      int gn = n0 + row;
      if (gn < N) vb = *reinterpret_cast<const us8*>(&Bt[(size_t)gn * K + k0 + sc8 * 8]);
      *reinterpret_cast<us8*>(&Bs[row * LDK + sc8 * 8]) = vb;
    }
    __syncthreads();
#pragma unroll
    for (int kk = 0; kk < 2; ++kk) {
      bf16x8 af[4], bfr[4];
#pragma unroll
      for (int i = 0; i < 4; ++i)
        af[i] = *reinterpret_cast<const bf16x8*>(&As[(wr * 64 + i * 16 + l15) * LDK + kk * 32 + lhi * 8]);
#pragma unroll
      for (int j = 0; j < 4; ++j)
        bfr[j] = *reinterpret_cast<const bf16x8*>(&Bs[(wc * 64 + j * 16 + l15) * LDK + kk * 32 + lhi * 8]);
#pragma unroll
      for (int i = 0; i < 4; ++i)
#pragma unroll
        for (int j = 0; j < 4; ++j)
          acc[i][j] = __builtin_amdgcn_mfma_f32_16x16x32_bf16(af[i], bfr[j], acc[i][j], 0, 0, 0);
    }
  }
#pragma unroll
  for (int j = 0; j < 4; ++j) {
    int col = n0 + wc * 64 + j * 16 + l15;
#pragma unroll
    for (int i = 0; i < 4; ++i) {
      f32x4 v = acc[i][j];
#pragma unroll
      for (int t = 0; t < 4; ++t) {
        int row = m0 + wr * 64 + i * 16 + lhi * 4 + t;
        if (row < M) Cout[(size_t)row * N + col] = f2bf(v[t]);
      }
    }
  }
  const int h = blockIdx.x * 2 + wc;
  float aS[4], aD[4];
#pragma unroll
  for (int j = 0; j < 4; ++j) {
    aS[j] = a_heads[h * 128 + j * 16 + l15];
    aD[j] = a_heads[h * 128 + 64 + j * 16 + l15];
  }
#pragma unroll
  for (int i = 0; i < 4; ++i) {
#pragma unroll
    for (int t = 0; t < 4; ++t) {
      float s = 0.f, d = 0.f;
#pragma unroll
      for (int j = 0; j < 4; ++j) {
        float v = acc[i][j][t];
        s = fmaf(v, aS[j], s);
        d = fmaf(v, aD[j], d);
      }
      s += __shfl_xor(s, 1, 64); s += __shfl_xor(s, 2, 64);
      s += __shfl_xor(s, 4, 64); s += __shfl_xor(s, 8, 64);
      d += __shfl_xor(d, 1, 64); d += __shfl_xor(d, 2, 64);
      d += __shfl_xor(d, 4, 64); d += __shfl_xor(d, 8, 64);
      int row = m0 + wr * 64 + i * 16 + lhi * 4 + t;
      if (l15 == 0 && row < M) {
        asrc[(size_t)row * 8 + h] = s;
        adst[(size_t)row * 8 + h] = d;
      }
    }
  }
}

// ---------- gemm_dual: z=0 gemm2 (+fused attn2) -> msg2 bf16, asrc2/adst2; z=1 residual -> f32 ----------
__global__ __launch_bounds__(256) void gemm_dual(
    const unsigned short* __restrict__ A0, const unsigned short* __restrict__ Bt0,
    unsigned short* __restrict__ C0, const float* __restrict__ b0,
    const float* __restrict__ a_out, float* __restrict__ asrc, float* __restrict__ adst,
    const unsigned short* __restrict__ A1, const unsigned short* __restrict__ Bt1,
    float* __restrict__ C1, const float* __restrict__ b1) {
  __shared__ unsigned short As[128 * LDK];
  __shared__ unsigned short Bs[128 * LDK];
  if (blockIdx.z == 1) {
    gemm_body(As, Bs, A1, Bt1, C1, b1, N_NODES, DIM_OUT, DIM_IN, 0);
    return;
  }
  // z == 0: gemm2 with fused attn2 projections
  const int M = N_NODES, N = DIM_OUT, K = HDIM;
  const int tid = threadIdx.x;
  const int lane = tid & 63, wid = tid >> 6;
  const int wr = wid >> 1, wc = wid & 1;
  const int l15 = lane & 15, lhi = lane >> 4;
  const int m0 = blockIdx.y * 128;
  const int srow = tid >> 3;
  const int sc8 = (tid - srow) & 7;
  f32x4 acc[4][4];
#pragma unroll
  for (int i = 0; i < 4; ++i)
#pragma unroll
    for (int j = 0; j < 4; ++j) acc[i][j] = f32x4{0.f, 0.f, 0.f, 0.f};

  for (int k0 = 0; k0 < K; k0 += 64) {
    __syncthreads();
#pragma unroll
    for (int p = 0; p < 4; ++p) {
      int row = p * 32 + srow;
      us8 va = {0, 0, 0, 0, 0, 0, 0, 0};
      int gr = m0 + row;
      if (gr < M) va = *reinterpret_cast<const us8*>(&A0[(size_t)gr * K + k0 + sc8 * 8]);
      *reinterpret_cast<us8*>(&As[row * LDK + sc8 * 8]) = va;
      us8 vb = {0, 0, 0, 0, 0, 0, 0, 0};
      if (row < N) vb = *reinterpret_cast<const us8*>(&Bt0[(size_t)row * K + k0 + sc8 * 8]);
      *reinterpret_cast<us8*>(&Bs[row * LDK + sc8 * 8]) = vb;
    }
    __syncthreads();
#pragma unroll
    for (int kk = 0; kk < 2; ++kk) {
      bf16x8 af[4], bfr[4];
#pragma unroll
      for (int i = 0; i < 4; ++i)
        af[i] = *reinterpret_cast<const bf16x8*>(&As[(wr * 64 + i * 16 + l15) * LDK + kk * 32 + lhi * 8]);
#pragma unroll
      for (int j = 0; j < 4; ++j)
        bfr[j] = *reinterpret_cast<const bf16x8*>(&Bs[(wc * 64 + j * 16 + l15) * LDK + kk * 32 + lhi * 8]);
#pragma unroll
      for (int i = 0; i < 4; ++i)
#pragma unroll
        for (int j = 0; j < 4; ++j)
          acc[i][j] = __builtin_amdgcn_mfma_f32_16x16x32_bf16(af[i], bfr[j], acc[i][j], 0, 0, 0);
    }
  }
  // C store (bf16, +bias)
#pragma unroll
  for (int j = 0; j < 4; ++j) {
    int col = wc * 64 + j * 16 + l15;
    float bb = b0[col];
#pragma unroll
    for (int i = 0; i < 4; ++i) {
      f32x4 v = acc[i][j];
#pragma unroll
      for (int t = 0; t < 4; ++t) {
        int row = m0 + wr * 64 + i * 16 + lhi * 4 + t;
        if (row < M) C0[(size_t)row * N + col] = f2bf(v[t] + bb);
      }
    }
  }
  // fused attn2: per-row dot with a_out over this wave's 64-col half, then LDS combine
  __shared__ float att_sh[2][64][2][2];   // [wr][row64][wc][s/d]
  float aS[4], aD[4];
#pragma unroll
  for (int j = 0; j < 4; ++j) {
    int col = wc * 64 + j * 16 + l15;
    float bb = b0[col];
    aS[j] = a_out[col];
    aD[j] = a_out[128 + col];
    // fold bias contribution into the dot: (v+bb)*a -> acc*a + bb*a; handle bb via constant add below
    (void)bb;
  }
#pragma unroll
  for (int i = 0; i < 4; ++i) {
#pragma unroll
    for (int t = 0; t < 4; ++t) {
      float s = 0.f, d = 0.f;
#pragma unroll
      for (int j = 0; j < 4; ++j) {
        int col = wc * 64 + j * 16 + l15;
        float v = acc[i][j][t] + b0[col];
        s = fmaf(v, aS[j], s);
        d = fmaf(v, aD[j], d);
      }
      s += __shfl_xor(s, 1, 64); s += __shfl_xor(s, 2, 64);
      s += __shfl_xor(s, 4, 64); s += __shfl_xor(s, 8, 64);
      d += __shfl_xor(d, 1, 64); d += __shfl_xor(d, 2, 64);
      d += __shfl_xor(d, 4, 64); d += __shfl_xor(d, 8, 64);
      if (l15 == 0) {
        att_sh[wr][i * 16 + lhi * 4 + t][wc][0] = s;
        att_sh[wr][i * 16 + lhi * 4 + t][wc][1] = d;
      }
    }
  }
  __syncthreads();
  if (tid < 128) {
    int wrr = tid >> 6, r = tid & 63;
    int row = m0 + wrr * 64 + r;
    if (row < M) {
      asrc[row] = att_sh[wrr][r][0][0] + att_sh[wrr][r][1][0];
      adst[row] = att_sh[wrr][r][0][1] + att_sh[wrr][r][1][1];
    }
  }
}

// ---------- node-max partial ----------
__global__ __launch_bounds__(256) void nodemax_part_kernel(
    const float* __restrict__ a, const float* __restrict__ b,
    float* __restrict__ part, int total) {
  int t = threadIdx.x;
  float ms = -3.4e38f, md = -3.4e38f;
  for (int i = blockIdx.x * 256 + t; i < total; i += NMBLK * 256) {
    ms = fmaxf(ms, a[i]);
    md = fmaxf(md, b[i]);
  }
  ms = fmaxf(ms, __shfl_xor(ms, 8, 64));
  ms = fmaxf(ms, __shfl_xor(ms, 16, 64));
  ms = fmaxf(ms, __shfl_xor(ms, 32, 64));
  md = fmaxf(md, __shfl_xor(md, 8, 64));
  md = fmaxf(md, __shfl_xor(md, 16, 64));
  md = fmaxf(md, __shfl_xor(md, 32, 64));
  __shared__ float sh[4][8][2];
  int wv = t >> 6, ln = t & 63;
  if (ln < 8) { sh[wv][ln][0] = ms; sh[wv][ln][1] = md; }
  __syncthreads();
  if (t < 8) {
    float s4 = fmaxf(fmaxf(sh[0][t][0], sh[1][t][0]), fmaxf(sh[2][t][0], sh[3][t][0]));
    float d4 = fmaxf(fmaxf(sh[0][t][1], sh[1][t][1]), fmaxf(sh[2][t][1], sh[3][t][1]));
    part[blockIdx.x * 16 + t * 2] = s4;
    part[blockIdx.x * 16 + t * 2 + 1] = d4;
  }
}

__global__ void nodemax_final_kernel(const float* __restrict__ part, float* __restrict__ maxv, int H) {
  int t = threadIdx.x;
  int ch = t & 15, k = t >> 4;
  float m = -3.4e38f;
  for (int i = k; i < NMBLK; i += 4) m = fmaxf(m, part[i * 16 + ch]);
  m = fmaxf(m, __shfl_xor(m, 16, 64));
  m = fmaxf(m, __shfl_xor(m, 32, 64));
  float S = __shfl(m, (t & 7) * 2, 64);
  float D = __shfl(m, (t & 7) * 2 + 1, 64);
  if (H == 8) {
    if (t < 8) maxv[t] = S + D;
  } else {
    float Sm = S, Dm = D;
    Sm = fmaxf(Sm, __shfl_xor(Sm, 1, 64)); Sm = fmaxf(Sm, __shfl_xor(Sm, 2, 64));
    Sm = fmaxf(Sm, __shfl_xor(Sm, 4, 64));
    Dm = fmaxf(Dm, __shfl_xor(Dm, 1, 64)); Dm = fmaxf(Dm, __shfl_xor(Dm, 2, 64));
    Dm = fmaxf(Dm, __shfl_xor(Dm, 4, 64));
    if (t == 0) maxv[0] = Sm + Dm;
  }
}

// ---------- CSR: local scan ----------
__global__ __launch_bounds__(256) void scan1_kernel(
    const int* __restrict__ counts, int* __restrict__ rowptr, int* __restrict__ bsum, int n) {
  __shared__ int wsum[4];
  int b0 = blockIdx.x * 1024;
  int t = threadIdx.x;
  int lane = t & 63, w = t >> 6;
  int v[4]; int s = 0;
#pragma unroll
  for (int i = 0; i < 4; ++i) {
    int idx = b0 + t * 4 + i;
    v[i] = (idx < n) ? counts[idx] : 0;
    s += v[i];
  }
  int x = s;
#pragma unroll
  for (int off = 1; off < 64; off <<= 1) {
    int y = __shfl_up(x, off, 64);
    if (lane >= off) x += y;
  }
  if (lane == 63) wsum[w] = x;
  __syncthreads();
  int wof = 0;
  for (int i = 0; i < w; ++i) wof += wsum[i];
  int run = wof + x - s;
#pragma unroll
  for (int i = 0; i < 4; ++i) {
    int idx = b0 + t * 4 + i;
    if (idx < n) rowptr[idx] = run;
    run += v[i];
  }
  if (t == 255) bsum[blockIdx.x] = wof + x;
}

// ---------- CSR: carry propagate ----------
__global__ __launch_bounds__(256) void scan23_kernel(
    int* __restrict__ rowptr, const int* __restrict__ bsum, int n) {
  __shared__ int carry_sh;
  int b = blockIdx.x, t = threadIdx.x;
  if (t < 64) {
    int v = (t < b) ? bsum[t] : 0;
#pragma unroll
    for (int off = 32; off; off >>= 1) v += __shfl_xor(v, off, 64);
    if (t == 0) carry_sh = v;
  }
  __syncthreads();
  int carry = carry_sh;
  int i0 = b * 1024;
#pragma unroll
  for (int q = 0; q < 4; ++q) {
    int i = i0 + q * 256 + t;
    if (i < n) rowptr[i] += carry;
  }
  if (b == gridDim.x - 1 && t == 0) rowptr[n] = N_EDGES;
}

// ---------- pure scatter ----------
__global__ __launch_bounds__(256) void scatter_kernel(
    const int* __restrict__ esrc, const int* __restrict__ edst,
    const int* __restrict__ rowptr, int* __restrict__ cursor,
    int* __restrict__ colsrc, int E) {
  for (int e = blockIdx.x * blockDim.x + threadIdx.x; e < E; e += gridDim.x * blockDim.x) {
    int d = edst[e];
    int pos = rowptr[d] + atomicAdd(&cursor[d], 1);
    colsrc[pos] = esrc[e];
  }
}

// ---------- layer-1 aggregation: wave-per-node, us8 gathers, shfl coefs ----------
__global__ __launch_bounds__(256) void agg1_kernel(
    const unsigned short* __restrict__ msg, const float* __restrict__ asrc,
    const float* __restrict__ adst, const float* __restrict__ maxv,
    const int* __restrict__ rowptr, const int* __restrict__ colsrc,
    unsigned short* __restrict__ out) {
  int wv = threadIdx.x >> 6, l = threadIdx.x & 63;
  int n = blockIdx.x * 4 + wv;
  const int h = l >> 3;
  const int eloc = l & 7;
  const int hbase = l & 56;
  float M = maxv[h];
  float ad = adst[(size_t)n * 8 + h];
  int e0 = rowptr[n], e1 = rowptr[n + 1];
  float acc[8];
#pragma unroll
  for (int j = 0; j < 8; ++j) acc[j] = 0.f;
  float ds = 0.f;
  int base = e0;
  for (; base + 8 <= e1; base += 8) {
    int sreg = colsrc[base + eloc];
    float x = asrc[(size_t)sreg * 8 + h] + ad;
    x = x >= 0.f ? x : 0.2f * x;
    float creg = __expf(x - M);
#pragma unroll
    for (int e = 0; e < 8; ++e) {
      float c = __shfl(creg, hbase | e, 64);
      int s = __shfl(sreg, e, 64);
      ds += c;
      us8 m = *reinterpret_cast<const us8*>(&msg[(size_t)s * HDIM + l * 8]);
#pragma unroll
      for (int j = 0; j < 8; ++j) acc[j] = fmaf(bf2f(m[j]), c, acc[j]);
    }
  }
  if (base < e1) {
    int cnt = e1 - base;
    int sreg = 0; float creg = 0.f;
    if (eloc < cnt) {
      sreg = colsrc[base + eloc];
      float x = asrc[(size_t)sreg * 8 + h] + ad;
      x = x >= 0.f ? x : 0.2f * x;
      creg = __expf(x - M);
    }
    for (int e = 0; e < cnt; ++e) {
      float c = __shfl(creg, hbase | e, 64);
      int s = __shfl(sreg, e, 64);
      ds += c;
      us8 m = *reinterpret_cast<const us8*>(&msg[(size_t)s * HDIM + l * 8]);
#pragma unroll
      for (int j = 0; j < 8; ++j) acc[j] = fmaf(bf2f(m[j]), c, acc[j]);
    }
  }
  float inv = 1.0f / (ds + 1e-10f);
  us8 o;
#pragma unroll
  for (int j = 0; j < 8; ++j) o[j] = f2bf(acc[j] * inv);
  *reinterpret_cast<us8*>(&out[(size_t)n * HDIM + l * 8]) = o;
}

// ---------- layer-2 aggregation ----------
__global__ __launch_bounds__(256) void agg2_kernel(
    const unsigned short* __restrict__ msg, const float* __restrict__ asrc,
    const float* __restrict__ adst, const float* __restrict__ maxv,
    const int* __restrict__ rowptr, const int* __restrict__ colsrc,
    float* __restrict__ out) {
  int wv = threadIdx.x >> 6, ln = threadIdx.x & 63;
  int n = blockIdx.x * 4 + wv;
  float M = maxv[0];
  float ad = adst[n];
  int e0 = rowptr[n], e1 = rowptr[n + 1];
  float a0 = 0.f, a1 = 0.f, ds = 0.f;
  for (int base = e0; base < e1; base += 64) {
    int cnt = min(64, e1 - base);
    int s_reg = 0; float c_reg = 0.f;
    if (ln < cnt) {
      s_reg = colsrc[base + ln];
      float x = asrc[s_reg] + ad;
      x = x >= 0.f ? x : 0.2f * x;
      c_reg = __expf(x - M);
    }
    int e = 0;
    for (; e + 4 <= cnt; e += 4) {
      int s0 = __shfl(s_reg, e, 64),     s1 = __shfl(s_reg, e + 1, 64);
      int s2 = __shfl(s_reg, e + 2, 64), s3 = __shfl(s_reg, e + 3, 64);
      float c0 = __shfl(c_reg, e, 64),     c1 = __shfl(c_reg, e + 1, 64);
      float c2 = __shfl(c_reg, e + 2, 64), c3 = __shfl(c_reg, e + 3, 64);
      us2 m0 = *reinterpret_cast<const us2*>(&msg[(size_t)s0 * 128 + 2 * ln]);
      us2 m1 = *reinterpret_cast<const us2*>(&msg[(size_t)s1 * 128 + 2 * ln]);
      us2 m2 = *reinterpret_cast<const us2*>(&msg[(size_t)s2 * 128 + 2 * ln]);
      us2 m3 = *reinterpret_cast<const us2*>(&msg[(size_t)s3 * 128 + 2 * ln]);
      ds += (c0 + c1) + (c2 + c3);
      a0 = fmaf(bf2f(m0[0]), c0, a0); a1 = fmaf(bf2f(m0[1]), c0, a1);
      a0 = fmaf(bf2f(m1[0]), c1, a0); a1 = fmaf(bf2f(m1[1]), c1, a1);
      a0 = fmaf(bf2f(m2[0]), c2, a0); a1 = fmaf(bf2f(m2[1]), c2, a1);
      a0 = fmaf(bf2f(m3[0]), c3, a0); a1 = fmaf(bf2f(m3[1]), c3, a1);
    }
    for (; e < cnt; ++e) {
      int s = __shfl(s_reg, e, 64);
      float c = __shfl(c_reg, e, 64);
      us2 m = *reinterpret_cast<const us2*>(&msg[(size_t)s * 128 + 2 * ln]);
      ds += c;
      a0 = fmaf(bf2f(m[0]), c, a0);
      a1 = fmaf(bf2f(m[1]), c, a1);
    }
  }
  float inv = 1.0f / (ds + 1e-10f);
  float2 r; r.x = a0 * inv; r.y = a1 * inv;
  *reinterpret_cast<float2*>(&out[(size_t)n * 128 + 2 * ln]) = r;
}

// ---------- column stats, bf16 [M][512] ----------
__global__ __launch_bounds__(256) void colstats_bf512_kernel(
    const unsigned short* __restrict__ X, float* __restrict__ sums,
    float* __restrict__ sqs, int M) {
  int tid = threadIdx.x;
  int cg = tid & 63;
  int wv = tid >> 6;
  int rows = (M + gridDim.x - 1) / gridDim.x;
  int r0 = blockIdx.x * rows;
  int r1 = min(M, r0 + rows);
  float s[8], q[8];
#pragma unroll
  for (int j = 0; j < 8; ++j) { s[j] = 0.f; q[j] = 0.f; }
  for (int r = r0 + wv; r < r1; r += 4) {
    us8 v = *reinterpret_cast<const us8*>(&X[(size_t)r * 512 + cg * 8]);
#pragma unroll
    for (int j = 0; j < 8; ++j) {
      float f = bf2f(v[j]);
      s[j] += f; q[j] = fmaf(f, f, q[j]);
    }
  }
  __shared__ float shs[3][512];
  __shared__ float shq[3][512];
  if (wv > 0) {
#pragma unroll
    for (int j = 0; j < 8; ++j) {
      shs[wv - 1][cg * 8 + j] = s[j];
      shq[wv - 1][cg * 8 + j] = q[j];
    }
  }
  __syncthreads();
  if (wv == 0) {
#pragma unroll
    for (int j = 0; j < 8; ++j) {
      int c = cg * 8 + j;
      atomicAdd(&sums[c], s[j] + shs[0][c] + shs[1][c] + shs[2][c]);
      atomicAdd(&sqs[c],  q[j] + shq[0][c] + shq[1][c] + shq[2][c]);
    }
  }
}

// ---------- column stats, fp32 [M][128] ----------
__global__ __launch_bounds__(256) void colstats_f128_kernel(
    const float* __restrict__ X, float* __restrict__ sums,
    float* __restrict__ sqs, int M) {
  int tid = threadIdx.x;
  int g = tid & 31;
  int slot = tid >> 5;
  int rows = (M + gridDim.x - 1) / gridDim.x;
  int r0 = blockIdx.x * rows;
  int r1 = min(M, r0 + rows);
  float s[4] = {0.f, 0.f, 0.f, 0.f}, q[4] = {0.f, 0.f, 0.f, 0.f};
  for (int r = r0 + slot; r < r1; r += 8) {
    float4 v = *reinterpret_cast<const float4*>(&X[(size_t)r * 128 + g * 4]);
    s[0] += v.x; q[0] = fmaf(v.x, v.x, q[0]);
    s[1] += v.y; q[1] = fmaf(v.y, v.y, q[1]);
    s[2] += v.z; q[2] = fmaf(v.z, v.z, q[2]);
    s[3] += v.w; q[3] = fmaf(v.w, v.w, q[3]);
  }
#pragma unroll
  for (int j = 0; j < 4; ++j) {
    s[j] += __shfl_xor(s[j], 32, 64);
    q[j] += __shfl_xor(q[j], 32, 64);
  }
  __shared__ float shs[3][128];
  __shared__ float shq[3][128];
  int wv = tid >> 6, ln = tid & 63;
  if (wv > 0 && ln < 32) {
#pragma unroll
    for (int j = 0; j < 4; ++j) {
      shs[wv - 1][g * 4 + j] = s[j];
      shq[wv - 1][g * 4 + j] = q[j];
    }
  }
  __syncthreads();
  if (wv == 0 && ln < 32) {
#pragma unroll
    for (int j = 0; j < 4; ++j) {
      int c = g * 4 + j;
      atomicAdd(&sums[c], s[j] + shs[0][c] + shs[1][c] + shs[2][c]);
      atomicAdd(&sqs[c],  q[j] + shq[0][c] + shq[1][c] + shq[2][c]);
    }
  }
}

// ---------- final: BN(out2) + residual ----------
__global__ void final_kernel(float* __restrict__ out, const float* __restrict__ resid,
                             const float* __restrict__ colsum, const float* __restrict__ colsq,
                             const float* __restrict__ gamma, const float* __restrict__ beta,
                             int total) {
  for (int i = blockIdx.x * blockDim.x + threadIdx.x; i < total; i += gridDim.x * blockDim.x) {
    int c = i & 127;
    float mean = colsum[c] * INV_N;
    float sc = bn_scale(colsum[c], colsq[c], gamma[c]);
    float sh = beta[c] - mean * sc;
    out[i] = fmaf(out[i], sc, sh) + resid[i];
  }
}

// ==================== host ====================
extern "C" void kernel_launch(void* const* d_in, const int* in_sizes, int n_in,
                              void* d_out, int out_size, void* d_ws, size_t ws_size,
                              hipStream_t stream) {
  const float* feat    = (const float*)d_in[0];
  const int*   edges   = (const int*)d_in[1];
  const int*   esrc    = edges;
  const int*   edst    = edges + N_EDGES;
  const float* W_heads = (const float*)d_in[2];
  const float* a_heads = (const float*)d_in[3];
  const float* gamma_h = (const float*)d_in[4];
  const float* beta_h  = (const float*)d_in[5];
  const float* W_out   = (const float*)d_in[6];
  const float* a_out   = (const float*)d_in[7];
  const float* gamma_o = (const float*)d_in[8];
  const float* beta_o  = (const float*)d_in[9];
  const float* W_res   = (const float*)d_in[10];
  const float* b_res   = (const float*)d_in[11];
  float* out = (float*)d_out;

  char* ws = (char*)d_ws;
  size_t off = 0;
  auto alloc = [&](size_t bytes) {
    void* p = ws + off;
    off = (off + bytes + 255) & ~(size_t)255;
    return p;
  };
  unsigned short* msg1    = (unsigned short*)alloc((size_t)N_NODES * HDIM * 2);  // reused as msg2
  unsigned short* out1_bf = (unsigned short*)alloc((size_t)N_NODES * HDIM * 2);
  unsigned short* feat_bf = (unsigned short*)alloc((size_t)N_NODES * DIM_IN * 2);
  float*    resid  = (float*)alloc((size_t)N_NODES * DIM_OUT * 4);
  float*    asrc1  = (float*)alloc((size_t)N_NODES * NHEADS * 4); // reused as asrc2
  float*    adst1  = (float*)alloc((size_t)N_NODES * NHEADS * 4); // reused as adst2
  int*      counts = (int*)alloc((size_t)N_NODES * 4);            // zeroed region start
  int*      cursor = (int*)alloc((size_t)N_NODES * 4);
  float*    bias2  = (float*)alloc(DIM_OUT * 4);                  // zeroed (end of region)
  int*      rowptr = (int*)alloc((size_t)(N_NODES + 1) * 4);
  int*      colsrc = (int*)alloc((size_t)N_EDGES * 4);
  int*      bsum   = (int*)alloc(64 * 4);
  float*    partmx = (float*)alloc((size_t)NMBLK * 16 * 4);
  float*    maxv1  = (float*)alloc(8 * 4);
  float*    maxv2  = (float*)alloc(4);
  float*    colsum = (float*)alloc(HDIM * 4);
  float*    colsq  = (float*)alloc(HDIM * 4);   // adjacent to colsum
  unsigned short* Bt1 = (unsigned short*)alloc((size_t)HDIM * DIM_IN * 2);
  unsigned short* Bt2 = (unsigned short*)alloc((size_t)DIM_OUT * HDIM * 2);
  unsigned short* Btr = (unsigned short*)alloc((size_t)DIM_OUT * DIM_IN * 2);
  unsigned short* msg2 = msg1;
  float* asrc2 = asrc1; float* adst2 = adst1;
  (void)n_in; (void)in_sizes; (void)out_size; (void)ws_size;

  hipMemsetAsync(counts, 0, (char*)rowptr - (char*)counts, stream);  // counts+cursor+bias2
  hipMemsetAsync(colsum, 0, 4096, stream);

  // ---- prep (cvt + packs + hist fused) ----
  prep_kernel<<<6570 + HISTBLK, 256, 0, stream>>>(feat, W_heads, W_res, edst,
                                                  feat_bf, Bt1, Btr, counts);

  // ---- layer 1: GEMM with fused attn projections ----
  dim3 g1(HDIM / 128, (N_NODES + 127) / 128);
  gemm1_attn_kernel<<<g1, 256, 0, stream>>>(feat_bf, Bt1, msg1, a_heads, asrc1, adst1);
  nodemax_part_kernel<<<NMBLK, 256, 0, stream>>>(asrc1, adst1, partmx, N_NODES * 8);
  nodemax_final_kernel<<<1, 64, 0, stream>>>(partmx, maxv1, 8);

  int nsb = (N_NODES + 1023) / 1024;   // 49
  scan1_kernel<<<nsb, 256, 0, stream>>>(counts, rowptr, bsum, N_NODES);
  scan23_kernel<<<nsb, 256, 0, stream>>>(rowptr, bsum, N_NODES);

  scatter_kernel<<<SCBLK, 256, 0, stream>>>(esrc, edst, rowptr, cursor, colsrc, N_EDGES);
  agg1_kernel<<<N_NODES / 4, 256, 0, stream>>>(msg1, asrc1, adst1, maxv1, rowptr, colsrc, out1_bf);

  colstats_bf512_kernel<<<CSBLK, 256, 0, stream>>>(out1_bf, colsum, colsq, N_NODES);
  foldw2_kernel<<<DIM_OUT * HDIM / 256, 256, 0, stream>>>(W_out, colsum, colsq,
                                                          gamma_h, beta_h, Bt2, bias2);

  // ---- layer 2 (gemm2+attn2 fused, residual gemm; one launch) ----
  dim3 g2d(1, (N_NODES + 127) / 128, 2);
  gemm_dual<<<g2d, 256, 0, stream>>>(out1_bf, Bt2, msg2, bias2, a_out, asrc2, adst2,
                                     feat_bf, Btr, resid, b_res);
  nodemax_part_kernel<<<NMBLK, 256, 0, stream>>>(asrc2, adst2, partmx, N_NODES);
  nodemax_final_kernel<<<1, 64, 0, stream>>>(partmx, maxv2, 1);

  agg2_kernel<<<N_NODES / 4, 256, 0, stream>>>(msg2, asrc2, adst2, maxv2, rowptr, colsrc, out);

  // layer-2 BN stats + fused BN+residual epilogue
  hipMemsetAsync(colsum, 0, 4096, stream);
  colstats_f128_kernel<<<CSBLK, 256, 0, stream>>>(out, colsum, colsq, N_NODES);
  final_kernel<<<2048, 256, 0, stream>>>(out, resid, colsum, colsq, gamma_o, beta_o,
                                         N_NODES * DIM_OUT);
}

// Round 12
// 714.264 us; speedup vs baseline: 1.3225x; 1.0036x over previous
//
#include <hip/hip_runtime.h>
#include <math.h>

#define N_NODES 50000
#define N_EDGES 1600000
#define DIM_IN  128
#define DIM_HID 64
#define NHEADS  8
#define HDIM    (NHEADS*DIM_HID)   // 512
#define DIM_OUT 128
#define SCBLK   1024               // blocks for scatter pass
#define HISTBLK 2048               // hist sub-grid inside prep
#define NBY     391                // (N_NODES+127)/128
#define LDK     72                 // padded LDS row (bf16 elems)
#define INV_N   2e-5f              // 1/N_NODES
#define CSBLK   400                // blocks for column-stats kernels

typedef __attribute__((ext_vector_type(2))) unsigned short us2;
typedef __attribute__((ext_vector_type(4))) unsigned short us4;
typedef __attribute__((ext_vector_type(8))) unsigned short us8;
typedef __attribute__((ext_vector_type(8))) short bf16x8;
typedef __attribute__((ext_vector_type(4))) float f32x4;

__device__ __forceinline__ float leaky(float x) { return x >= 0.f ? x : 0.2f * x; }
__device__ __forceinline__ float bf2f(unsigned short h) {
  return __uint_as_float(((unsigned)h) << 16);
}
__device__ __forceinline__ unsigned short f2bf(float f) {
  unsigned u = __float_as_uint(f);
  unsigned r = (u + 0x7fffu + ((u >> 16) & 1u)) >> 16;
  return (unsigned short)r;
}
__device__ __forceinline__ float bn_scale(float sum, float sq, float g) {
  float mean = sum * INV_N;
  float var = sq * INV_N - mean * mean;
  return g * rsqrtf(var + 1e-5f);
}

// ---------- fused prep: cvt feat->bf16 | pack W_heads | pack W_res | edge histogram ----------
__global__ void prep_kernel(const float* __restrict__ feat, const float* __restrict__ Wh,
                            const float* __restrict__ Wres, const int* __restrict__ edst,
                            unsigned short* __restrict__ feat_bf,
                            unsigned short* __restrict__ Bt1,
                            unsigned short* __restrict__ Btr,
                            int* __restrict__ counts) {
  int b = blockIdx.x;
  if (b < 6250) {
    int i = b * 256 + threadIdx.x;
    float4 v = *reinterpret_cast<const float4*>(&feat[(size_t)i * 4]);
    us4 o;
    o[0] = f2bf(v.x); o[1] = f2bf(v.y); o[2] = f2bf(v.z); o[3] = f2bf(v.w);
    *reinterpret_cast<us4*>(&feat_bf[(size_t)i * 4]) = o;
  } else if (b < 6506) {
    int idx = (b - 6250) * 256 + threadIdx.x;
    int n = idx >> 7, k = idx & 127;
    Bt1[idx] = f2bf(Wh[(n >> 6) * (DIM_IN * DIM_HID) + k * DIM_HID + (n & 63)]);
  } else if (b < 6570) {
    int idx = (b - 6506) * 256 + threadIdx.x;
    int n = idx >> 7, k = idx & 127;
    Btr[idx] = f2bf(Wres[k * DIM_OUT + n]);
  } else {
    int bid = b - 6570;
    for (int e = bid * 256 + threadIdx.x; e < N_EDGES; e += HISTBLK * 256)
      atomicAdd(&counts[edst[e]], 1);
  }
}

// ---------- fold BN1 into W_out -> Bt2 + fused bias2 reduction ----------
__global__ __launch_bounds__(256) void foldw2_kernel(
    const float* __restrict__ W,
    const float* __restrict__ colsum, const float* __restrict__ colsq,
    const float* __restrict__ gamma, const float* __restrict__ beta,
    unsigned short* __restrict__ Bt, float* __restrict__ bias2) {
  int idx = blockIdx.x * 256 + threadIdx.x;
  int n = idx >> 9, k = idx & 511;
  float mean = colsum[k] * INV_N;
  float sc = bn_scale(colsum[k], colsq[k], gamma[k]);
  float w = W[k * DIM_OUT + n];
  Bt[idx] = f2bf(w * sc);
  float shift = beta[k] - mean * sc;
  __shared__ float red[256];
  red[threadIdx.x] = shift * w;
  __syncthreads();
#pragma unroll
  for (int off = 128; off; off >>= 1) {
    if (threadIdx.x < off) red[threadIdx.x] += red[threadIdx.x + off];
    __syncthreads();
  }
  if (threadIdx.x == 0) atomicAdd(&bias2[n], red[0]);
}

// ---------- bf16 MFMA GEMM body (shared mem passed in) ----------
__device__ __forceinline__ void gemm_body(
    unsigned short* As, unsigned short* Bs,
    const unsigned short* __restrict__ A, const unsigned short* __restrict__ Bt,
    void* __restrict__ Cout, const float* __restrict__ bias,
    int M, int N, int K, int outbf) {
  const int tid = threadIdx.x;
  const int lane = tid & 63, wid = tid >> 6;
  const int wr = wid >> 1, wc = wid & 1;
  const int l15 = lane & 15, lhi = lane >> 4;
  const int m0 = blockIdx.y * 128, n0 = blockIdx.x * 128;
  const int srow = tid >> 3;
  const int sc8 = (tid - srow) & 7;
  f32x4 acc[4][4];
#pragma unroll
  for (int i = 0; i < 4; ++i)
#pragma unroll
    for (int j = 0; j < 4; ++j) acc[i][j] = f32x4{0.f, 0.f, 0.f, 0.f};

  for (int k0 = 0; k0 < K; k0 += 64) {
    __syncthreads();
#pragma unroll
    for (int p = 0; p < 4; ++p) {
      int row = p * 32 + srow;
      us8 va = {0, 0, 0, 0, 0, 0, 0, 0};
      int gr = m0 + row;
      if (gr < M) va = *reinterpret_cast<const us8*>(&A[(size_t)gr * K + k0 + sc8 * 8]);
      *reinterpret_cast<us8*>(&As[row * LDK + sc8 * 8]) = va;
      us8 vb = {0, 0, 0, 0, 0, 0, 0, 0};
      int gn = n0 + row;
      if (gn < N) vb = *reinterpret_cast<const us8*>(&Bt[(size_t)gn * K + k0 + sc8 * 8]);
      *reinterpret_cast<us8*>(&Bs[row * LDK + sc8 * 8]) = vb;
    }
    __syncthreads();
#pragma unroll
    for (int kk = 0; kk < 2; ++kk) {
      bf16x8 af[4], bfr[4];
#pragma unroll
      for (int i = 0; i < 4; ++i)
        af[i] = *reinterpret_cast<const bf16x8*>(&As[(wr * 64 + i * 16 + l15) * LDK + kk * 32 + lhi * 8]);
#pragma unroll
      for (int j = 0; j < 4; ++j)
        bfr[j] = *reinterpret_cast<const bf16x8*>(&Bs[(wc * 64 + j * 16 + l15) * LDK + kk * 32 + lhi * 8]);
#pragma unroll
      for (int i = 0; i < 4; ++i)
#pragma unroll
        for (int j = 0; j < 4; ++j)
          acc[i][j] = __builtin_amdgcn_mfma_f32_16x16x32_bf16(af[i], bfr[j], acc[i][j], 0, 0, 0);
    }
  }
#pragma unroll
  for (int j = 0; j < 4; ++j) {
    int col = n0 + wc * 64 + j * 16 + l15;
    float bb = bias ? bias[col] : 0.f;
#pragma unroll
    for (int i = 0; i < 4; ++i) {
      f32x4 v = acc[i][j];
#pragma unroll
      for (int t = 0; t < 4; ++t) {
        int row = m0 + wr * 64 + i * 16 + lhi * 4 + t;
        if (row < M) {
          float o = v[t] + bb;
          if (outbf) ((unsigned short*)Cout)[(size_t)row * N + col] = f2bf(o);
          else       ((float*)Cout)[(size_t)row * N + col] = o;
        }
      }
    }
  }
}

// ---------- gemm1 + fused attn projections + fused per-block node-max partials ----------
__global__ __launch_bounds__(256) void gemm1_attn_kernel(
    const unsigned short* __restrict__ A, const unsigned short* __restrict__ Bt,
    unsigned short* __restrict__ Cout, const float* __restrict__ a_heads,
    float* __restrict__ asrc, float* __restrict__ adst, float* __restrict__ partmx) {
  __shared__ unsigned short As[128 * LDK];
  __shared__ unsigned short Bs[128 * LDK];
  const int M = N_NODES, N = HDIM, K = DIM_IN;
  const int tid = threadIdx.x;
  const int lane = tid & 63, wid = tid >> 6;
  const int wr = wid >> 1, wc = wid & 1;
  const int l15 = lane & 15, lhi = lane >> 4;
  const int m0 = blockIdx.y * 128, n0 = blockIdx.x * 128;
  const int srow = tid >> 3;
  const int sc8 = (tid - srow) & 7;
  f32x4 acc[4][4];
#pragma unroll
  for (int i = 0; i < 4; ++i)
#pragma unroll
    for (int j = 0; j < 4; ++j) acc[i][j] = f32x4{0.f, 0.f, 0.f, 0.f};

  for (int k0 = 0; k0 < K; k0 += 64) {
    __syncthreads();
#pragma unroll
    for (int p = 0; p < 4; ++p) {
      int row = p * 32 + srow;
      us8 va = {0, 0, 0, 0, 0, 0, 0, 0};
      int gr = m0 + row;
      if (gr < M) va = *reinterpret_cast<const us8*>(&A[(size_t)gr * K + k0 + sc8 * 8]);
      *reinterpret_cast<us8*>(&As[row * LDK + sc8 * 8]) = va;
      us8 vb = {0, 0, 0, 0, 0, 0, 0, 0};
      int gn = n0 + row;
      if (gn < N) vb = *reinterpret_cast<const us8*>(&Bt[(size_t)gn * K + k0 + sc8 * 8]);
      *reinterpret_cast<us8*>(&Bs[row * LDK + sc8 * 8]) = vb;
    }
    __syncthreads();
#pragma unroll
    for (int kk = 0; kk < 2; ++kk) {
      bf16x8 af[4], bfr[4];
#pragma unroll
      for (int i = 0; i < 4; ++i)
        af[i] = *reinterpret_cast<const bf16x8*>(&As[(wr * 64 + i * 16 + l15) * LDK + kk * 32 + lhi * 8]);
#pragma unroll
      for (int j = 0; j < 4; ++j)
        bfr[j] = *reinterpret_cast<const bf16x8*>(&Bs[(wc * 64 + j * 16 + l15) * LDK + kk * 32 + lhi * 8]);
#pragma unroll
      for (int i = 0; i < 4; ++i)
#pragma unroll
        for (int j = 0; j < 4; ++j)
          acc[i][j] = __builtin_amdgcn_mfma_f32_16x16x32_bf16(af[i], bfr[j], acc[i][j], 0, 0, 0);
    }
  }
#pragma unroll
  for (int j = 0; j < 4; ++j) {
    int col = n0 + wc * 64 + j * 16 + l15;
#pragma unroll
    for (int i = 0; i < 4; ++i) {
      f32x4 v = acc[i][j];
#pragma unroll
      for (int t = 0; t < 4; ++t) {
        int row = m0 + wr * 64 + i * 16 + lhi * 4 + t;
        if (row < M) Cout[(size_t)row * N + col] = f2bf(v[t]);
      }
    }
  }
  const int h = blockIdx.x * 2 + wc;
  float aS[4], aD[4];
#pragma unroll
  for (int j = 0; j < 4; ++j) {
    aS[j] = a_heads[h * 128 + j * 16 + l15];
    aD[j] = a_heads[h * 128 + 64 + j * 16 + l15];
  }
  float ms = -3.4e38f, md = -3.4e38f;
#pragma unroll
  for (int i = 0; i < 4; ++i) {
#pragma unroll
    for (int t = 0; t < 4; ++t) {
      float s = 0.f, d = 0.f;
#pragma unroll
      for (int j = 0; j < 4; ++j) {
        float v = acc[i][j][t];
        s = fmaf(v, aS[j], s);
        d = fmaf(v, aD[j], d);
      }
      s += __shfl_xor(s, 1, 64); s += __shfl_xor(s, 2, 64);
      s += __shfl_xor(s, 4, 64); s += __shfl_xor(s, 8, 64);
      d += __shfl_xor(d, 1, 64); d += __shfl_xor(d, 2, 64);
      d += __shfl_xor(d, 4, 64); d += __shfl_xor(d, 8, 64);
      int row = m0 + wr * 64 + i * 16 + lhi * 4 + t;
      if (l15 == 0 && row < M) {
        asrc[(size_t)row * 8 + h] = s;
        adst[(size_t)row * 8 + h] = d;
        ms = fmaxf(ms, s); md = fmaxf(md, d);
      }
    }
  }
  // per-block max for this wave's head (only l15==0 lanes hold data)
  ms = fmaxf(ms, __shfl_xor(ms, 16, 64)); ms = fmaxf(ms, __shfl_xor(ms, 32, 64));
  md = fmaxf(md, __shfl_xor(md, 16, 64)); md = fmaxf(md, __shfl_xor(md, 32, 64));
  __shared__ float shmx[2][2][2];   // [wr][wc][s/d]
  if (lane == 0) { shmx[wr][wc][0] = ms; shmx[wr][wc][1] = md; }
  __syncthreads();
  if (tid < 2) {
    size_t base = ((size_t)blockIdx.y * 4 + blockIdx.x) * 4 + tid * 2;
    partmx[base]     = fmaxf(shmx[0][tid][0], shmx[1][tid][0]);
    partmx[base + 1] = fmaxf(shmx[0][tid][1], shmx[1][tid][1]);
  }
}

// ---------- gemm_dual: z=0 gemm2 (+attn2+nodemax partial); z=1 residual ----------
__global__ __launch_bounds__(256) void gemm_dual(
    const unsigned short* __restrict__ A0, const unsigned short* __restrict__ Bt0,
    unsigned short* __restrict__ C0, const float* __restrict__ b0,
    const float* __restrict__ a_out, float* __restrict__ asrc, float* __restrict__ adst,
    float* __restrict__ part2,
    const unsigned short* __restrict__ A1, const unsigned short* __restrict__ Bt1,
    float* __restrict__ C1, const float* __restrict__ b1) {
  __shared__ unsigned short As[128 * LDK];
  __shared__ unsigned short Bs[128 * LDK];
  if (blockIdx.z == 1) {
    gemm_body(As, Bs, A1, Bt1, C1, b1, N_NODES, DIM_OUT, DIM_IN, 0);
    return;
  }
  const int M = N_NODES, N = DIM_OUT, K = HDIM;
  const int tid = threadIdx.x;
  const int lane = tid & 63, wid = tid >> 6;
  const int wr = wid >> 1, wc = wid & 1;
  const int l15 = lane & 15, lhi = lane >> 4;
  const int m0 = blockIdx.y * 128;
  const int srow = tid >> 3;
  const int sc8 = (tid - srow) & 7;
  f32x4 acc[4][4];
#pragma unroll
  for (int i = 0; i < 4; ++i)
#pragma unroll
    for (int j = 0; j < 4; ++j) acc[i][j] = f32x4{0.f, 0.f, 0.f, 0.f};

  for (int k0 = 0; k0 < K; k0 += 64) {
    __syncthreads();
#pragma unroll
    for (int p = 0; p < 4; ++p) {
      int row = p * 32 + srow;
      us8 va = {0, 0, 0, 0, 0, 0, 0, 0};
      int gr = m0 + row;
      if (gr < M) va = *reinterpret_cast<const us8*>(&A0[(size_t)gr * K + k0 + sc8 * 8]);
      *reinterpret_cast<us8*>(&As[row * LDK + sc8 * 8]) = va;
      us8 vb = {0, 0, 0, 0, 0, 0, 0, 0};
      if (row < N) vb = *reinterpret_cast<const us8*>(&Bt0[(size_t)row * K + k0 + sc8 * 8]);
      *reinterpret_cast<us8*>(&Bs[row * LDK + sc8 * 8]) = vb;
    }
    __syncthreads();
#pragma unroll
    for (int kk = 0; kk < 2; ++kk) {
      bf16x8 af[4], bfr[4];
#pragma unroll
      for (int i = 0; i < 4; ++i)
        af[i] = *reinterpret_cast<const bf16x8*>(&As[(wr * 64 + i * 16 + l15) * LDK + kk * 32 + lhi * 8]);
#pragma unroll
      for (int j = 0; j < 4; ++j)
        bfr[j] = *reinterpret_cast<const bf16x8*>(&Bs[(wc * 64 + j * 16 + l15) * LDK + kk * 32 + lhi * 8]);
#pragma unroll
      for (int i = 0; i < 4; ++i)
#pragma unroll
        for (int j = 0; j < 4; ++j)
          acc[i][j] = __builtin_amdgcn_mfma_f32_16x16x32_bf16(af[i], bfr[j], acc[i][j], 0, 0, 0);
    }
  }
#pragma unroll
  for (int j = 0; j < 4; ++j) {
    int col = wc * 64 + j * 16 + l15;
    float bb = b0[col];
#pragma unroll
    for (int i = 0; i < 4; ++i) {
      f32x4 v = acc[i][j];
#pragma unroll
      for (int t = 0; t < 4; ++t) {
        int row = m0 + wr * 64 + i * 16 + lhi * 4 + t;
        if (row < M) C0[(size_t)row * N + col] = f2bf(v[t] + bb);
      }
    }
  }
  __shared__ float att_sh[2][64][2][2];
  float aS[4], aD[4];
#pragma unroll
  for (int j = 0; j < 4; ++j) {
    int col = wc * 64 + j * 16 + l15;
    aS[j] = a_out[col];
    aD[j] = a_out[128 + col];
  }
#pragma unroll
  for (int i = 0; i < 4; ++i) {
#pragma unroll
    for (int t = 0; t < 4; ++t) {
      float s = 0.f, d = 0.f;
#pragma unroll
      for (int j = 0; j < 4; ++j) {
        int col = wc * 64 + j * 16 + l15;
        float v = acc[i][j][t] + b0[col];
        s = fmaf(v, aS[j], s);
        d = fmaf(v, aD[j], d);
      }
      s += __shfl_xor(s, 1, 64); s += __shfl_xor(s, 2, 64);
      s += __shfl_xor(s, 4, 64); s += __shfl_xor(s, 8, 64);
      d += __shfl_xor(d, 1, 64); d += __shfl_xor(d, 2, 64);
      d += __shfl_xor(d, 4, 64); d += __shfl_xor(d, 8, 64);
      if (l15 == 0) {
        att_sh[wr][i * 16 + lhi * 4 + t][wc][0] = s;
        att_sh[wr][i * 16 + lhi * 4 + t][wc][1] = d;
      }
    }
  }
  __syncthreads();
  float s2 = -3.4e38f, d2 = -3.4e38f;
  if (tid < 128) {
    int wrr = tid >> 6, r = tid & 63;
    int row = m0 + wrr * 64 + r;
    if (row < M) {
      float sv = att_sh[wrr][r][0][0] + att_sh[wrr][r][1][0];
      float dv = att_sh[wrr][r][0][1] + att_sh[wrr][r][1][1];
      asrc[row] = sv; adst[row] = dv;
      s2 = sv; d2 = dv;
    }
  }
#pragma unroll
  for (int off = 32; off; off >>= 1) {
    s2 = fmaxf(s2, __shfl_xor(s2, off, 64));
    d2 = fmaxf(d2, __shfl_xor(d2, off, 64));
  }
  __shared__ float shm2[2][2];
  int wvid = tid >> 6, lnn = tid & 63;
  if (wvid < 2 && lnn == 0) { shm2[wvid][0] = s2; shm2[wvid][1] = d2; }
  __syncthreads();
  if (tid == 0) {
    part2[blockIdx.y * 2]     = fmaxf(shm2[0][0], shm2[1][0]);
    part2[blockIdx.y * 2 + 1] = fmaxf(shm2[0][1], shm2[1][1]);
  }
}

// ---------- node-max final: H=8 (layer1 partmx layout) or H=1 (layer2) ----------
__global__ void nodemax_final_kernel(const float* __restrict__ part, float* __restrict__ maxv,
                                     int H, int nby) {
  int t = threadIdx.x;
  if (H == 8) {
    int h = t >> 3, j = t & 7;
    float S = -3.4e38f, D = -3.4e38f;
    for (int by = j; by < nby; by += 8) {
      int base = (by * 4 + (h >> 1)) * 4 + (h & 1) * 2;
      S = fmaxf(S, part[base]);
      D = fmaxf(D, part[base + 1]);
    }
    S = fmaxf(S, __shfl_xor(S, 1, 64)); S = fmaxf(S, __shfl_xor(S, 2, 64));
    S = fmaxf(S, __shfl_xor(S, 4, 64));
    D = fmaxf(D, __shfl_xor(D, 1, 64)); D = fmaxf(D, __shfl_xor(D, 2, 64));
    D = fmaxf(D, __shfl_xor(D, 4, 64));
    if (j == 0) maxv[h] = S + D;
  } else {
    float S = -3.4e38f, D = -3.4e38f;
    for (int by = t; by < nby; by += 64) {
      S = fmaxf(S, part[by * 2]);
      D = fmaxf(D, part[by * 2 + 1]);
    }
#pragma unroll
    for (int off = 32; off; off >>= 1) {
      S = fmaxf(S, __shfl_xor(S, off, 64));
      D = fmaxf(D, __shfl_xor(D, off, 64));
    }
    if (t == 0) maxv[0] = S + D;
  }
}

// ---------- CSR: local scan ----------
__global__ __launch_bounds__(256) void scan1_kernel(
    const int* __restrict__ counts, int* __restrict__ rowptr, int* __restrict__ bsum, int n) {
  __shared__ int wsum[4];
  int b0 = blockIdx.x * 1024;
  int t = threadIdx.x;
  int lane = t & 63, w = t >> 6;
  int v[4]; int s = 0;
#pragma unroll
  for (int i = 0; i < 4; ++i) {
    int idx = b0 + t * 4 + i;
    v[i] = (idx < n) ? counts[idx] : 0;
    s += v[i];
  }
  int x = s;
#pragma unroll
  for (int off = 1; off < 64; off <<= 1) {
    int y = __shfl_up(x, off, 64);
    if (lane >= off) x += y;
  }
  if (lane == 63) wsum[w] = x;
  __syncthreads();
  int wof = 0;
  for (int i = 0; i < w; ++i) wof += wsum[i];
  int run = wof + x - s;
#pragma unroll
  for (int i = 0; i < 4; ++i) {
    int idx = b0 + t * 4 + i;
    if (idx < n) rowptr[idx] = run;
    run += v[i];
  }
  if (t == 255) bsum[blockIdx.x] = wof + x;
}

// ---------- CSR: carry propagate ----------
__global__ __launch_bounds__(256) void scan23_kernel(
    int* __restrict__ rowptr, const int* __restrict__ bsum, int n) {
  __shared__ int carry_sh;
  int b = blockIdx.x, t = threadIdx.x;
  if (t < 64) {
    int v = (t < b) ? bsum[t] : 0;
#pragma unroll
    for (int off = 32; off; off >>= 1) v += __shfl_xor(v, off, 64);
    if (t == 0) carry_sh = v;
  }
  __syncthreads();
  int carry = carry_sh;
  int i0 = b * 1024;
#pragma unroll
  for (int q = 0; q < 4; ++q) {
    int i = i0 + q * 256 + t;
    if (i < n) rowptr[i] += carry;
  }
  if (b == gridDim.x - 1 && t == 0) rowptr[n] = N_EDGES;
}

// ---------- pure scatter ----------
__global__ __launch_bounds__(256) void scatter_kernel(
    const int* __restrict__ esrc, const int* __restrict__ edst,
    const int* __restrict__ rowptr, int* __restrict__ cursor,
    int* __restrict__ colsrc, int E) {
  for (int e = blockIdx.x * blockDim.x + threadIdx.x; e < E; e += gridDim.x * blockDim.x) {
    int d = edst[e];
    int pos = rowptr[d] + atomicAdd(&cursor[d], 1);
    colsrc[pos] = esrc[e];
  }
}

// ---------- layer-1 aggregation: wave-per-node, us8 gathers, shfl coefs ----------
__global__ __launch_bounds__(256) void agg1_kernel(
    const unsigned short* __restrict__ msg, const float* __restrict__ asrc,
    const float* __restrict__ adst, const float* __restrict__ maxv,
    const int* __restrict__ rowptr, const int* __restrict__ colsrc,
    unsigned short* __restrict__ out) {
  int wv = threadIdx.x >> 6, l = threadIdx.x & 63;
  int n = blockIdx.x * 4 + wv;
  const int h = l >> 3;
  const int eloc = l & 7;
  const int hbase = l & 56;
  float M = maxv[h];
  float ad = adst[(size_t)n * 8 + h];
  int e0 = rowptr[n], e1 = rowptr[n + 1];
  float acc[8];
#pragma unroll
  for (int j = 0; j < 8; ++j) acc[j] = 0.f;
  float ds = 0.f;
  int base = e0;
  for (; base + 8 <= e1; base += 8) {
    int sreg = colsrc[base + eloc];
    float x = asrc[(size_t)sreg * 8 + h] + ad;
    x = x >= 0.f ? x : 0.2f * x;
    float creg = __expf(x - M);
#pragma unroll
    for (int e = 0; e < 8; ++e) {
      float c = __shfl(creg, hbase | e, 64);
      int s = __shfl(sreg, e, 64);
      ds += c;
      us8 m = *reinterpret_cast<const us8*>(&msg[(size_t)s * HDIM + l * 8]);
#pragma unroll
      for (int j = 0; j < 8; ++j) acc[j] = fmaf(bf2f(m[j]), c, acc[j]);
    }
  }
  if (base < e1) {
    int cnt = e1 - base;
    int sreg = 0; float creg = 0.f;
    if (eloc < cnt) {
      sreg = colsrc[base + eloc];
      float x = asrc[(size_t)sreg * 8 + h] + ad;
      x = x >= 0.f ? x : 0.2f * x;
      creg = __expf(x - M);
    }
    for (int e = 0; e < cnt; ++e) {
      float c = __shfl(creg, hbase | e, 64);
      int s = __shfl(sreg, e, 64);
      ds += c;
      us8 m = *reinterpret_cast<const us8*>(&msg[(size_t)s * HDIM + l * 8]);
#pragma unroll
      for (int j = 0; j < 8; ++j) acc[j] = fmaf(bf2f(m[j]), c, acc[j]);
    }
  }
  float inv = 1.0f / (ds + 1e-10f);
  us8 o;
#pragma unroll
  for (int j = 0; j < 8; ++j) o[j] = f2bf(acc[j] * inv);
  *reinterpret_cast<us8*>(&out[(size_t)n * HDIM + l * 8]) = o;
}

// ---------- layer-2 aggregation: wave-per-node, us4/2-edge-halves ----------
__global__ __launch_bounds__(256) void agg2_kernel(
    const unsigned short* __restrict__ msg, const float* __restrict__ asrc,
    const float* __restrict__ adst, const float* __restrict__ maxv,
    const int* __restrict__ rowptr, const int* __restrict__ colsrc,
    float* __restrict__ out) {
  int wv = threadIdx.x >> 6, ln = threadIdx.x & 63;
  int n = blockIdx.x * 4 + wv;
  int half = ln >> 5, q = ln & 31;       // q: us4 (8B) column group
  float M = maxv[0];
  float ad = adst[n];
  int e0 = rowptr[n], e1 = rowptr[n + 1];
  float acc[4] = {0.f, 0.f, 0.f, 0.f};
  float ds = 0.f;
  for (int base = e0; base < e1; base += 64) {
    int cnt = min(64, e1 - base);
    int s_reg = 0; float c_reg = 0.f;
    if (ln < cnt) {
      s_reg = colsrc[base + ln];
      float x = asrc[s_reg] + ad;
      x = x >= 0.f ? x : 0.2f * x;
      c_reg = __expf(x - M);
    }
    int cnt4 = cnt & ~3;
    int e = 0;
    for (; e < cnt4; e += 4) {
      int sA = __shfl(s_reg, e + half, 64);
      int sB = __shfl(s_reg, e + 2 + half, 64);
      float cA = __shfl(c_reg, e + half, 64);
      float cB = __shfl(c_reg, e + 2 + half, 64);
      us4 mA = *reinterpret_cast<const us4*>(&msg[(size_t)sA * 128 + q * 4]);
      us4 mB = *reinterpret_cast<const us4*>(&msg[(size_t)sB * 128 + q * 4]);
      ds += cA + cB;
#pragma unroll
      for (int j = 0; j < 4; ++j) {
        acc[j] = fmaf(bf2f(mA[j]), cA, acc[j]);
        acc[j] = fmaf(bf2f(mB[j]), cB, acc[j]);
      }
    }
    for (; e < cnt; e += 2) {
      int idx = e + half;
      int idc = idx < cnt ? idx : 0;
      int s = __shfl(s_reg, idc, 64);
      float c = __shfl(c_reg, idc, 64);
      if (idx >= cnt) c = 0.f;
      us4 m = *reinterpret_cast<const us4*>(&msg[(size_t)s * 128 + q * 4]);
      ds += c;
#pragma unroll
      for (int j = 0; j < 4; ++j) acc[j] = fmaf(bf2f(m[j]), c, acc[j]);
    }
  }
  // combine halves
  ds += __shfl_xor(ds, 32, 64);
#pragma unroll
  for (int j = 0; j < 4; ++j) acc[j] += __shfl_xor(acc[j], 32, 64);
  if (half == 0) {
    float inv = 1.0f / (ds + 1e-10f);
    float4 r;
    r.x = acc[0] * inv; r.y = acc[1] * inv;
    r.z = acc[2] * inv; r.w = acc[3] * inv;
    *reinterpret_cast<float4*>(&out[(size_t)n * 128 + q * 4]) = r;
  }
}

// ---------- column stats, bf16 [M][512] ----------
__global__ __launch_bounds__(256) void colstats_bf512_kernel(
    const unsigned short* __restrict__ X, float* __restrict__ sums,
    float* __restrict__ sqs, int M) {
  int tid = threadIdx.x;
  int cg = tid & 63;
  int wv = tid >> 6;
  int rows = (M + gridDim.x - 1) / gridDim.x;
  int r0 = blockIdx.x * rows;
  int r1 = min(M, r0 + rows);
  float s[8], q[8];
#pragma unroll
  for (int j = 0; j < 8; ++j) { s[j] = 0.f; q[j] = 0.f; }
  for (int r = r0 + wv; r < r1; r += 4) {
    us8 v = *reinterpret_cast<const us8*>(&X[(size_t)r * 512 + cg * 8]);
#pragma unroll
    for (int j = 0; j < 8; ++j) {
      float f = bf2f(v[j]);
      s[j] += f; q[j] = fmaf(f, f, q[j]);
    }
  }
  __shared__ float shs[3][512];
  __shared__ float shq[3][512];
  if (wv > 0) {
#pragma unroll
    for (int j = 0; j < 8; ++j) {
      shs[wv - 1][cg * 8 + j] = s[j];
      shq[wv - 1][cg * 8 + j] = q[j];
    }
  }
  __syncthreads();
  if (wv == 0) {
#pragma unroll
    for (int j = 0; j < 8; ++j) {
      int c = cg * 8 + j;
      atomicAdd(&sums[c], s[j] + shs[0][c] + shs[1][c] + shs[2][c]);
      atomicAdd(&sqs[c],  q[j] + shq[0][c] + shq[1][c] + shq[2][c]);
    }
  }
}

// ---------- column stats, fp32 [M][128] ----------
__global__ __launch_bounds__(256) void colstats_f128_kernel(
    const float* __restrict__ X, float* __restrict__ sums,
    float* __restrict__ sqs, int M) {
  int tid = threadIdx.x;
  int g = tid & 31;
  int slot = tid >> 5;
  int rows = (M + gridDim.x - 1) / gridDim.x;
  int r0 = blockIdx.x * rows;
  int r1 = min(M, r0 + rows);
  float s[4] = {0.f, 0.f, 0.f, 0.f}, q[4] = {0.f, 0.f, 0.f, 0.f};
  for (int r = r0 + slot; r < r1; r += 8) {
    float4 v = *reinterpret_cast<const float4*>(&X[(size_t)r * 128 + g * 4]);
    s[0] += v.x; q[0] = fmaf(v.x, v.x, q[0]);
    s[1] += v.y; q[1] = fmaf(v.y, v.y, q[1]);
    s[2] += v.z; q[2] = fmaf(v.z, v.z, q[2]);
    s[3] += v.w; q[3] = fmaf(v.w, v.w, q[3]);
  }
#pragma unroll
  for (int j = 0; j < 4; ++j) {
    s[j] += __shfl_xor(s[j], 32, 64);
    q[j] += __shfl_xor(q[j], 32, 64);
  }
  __shared__ float shs[3][128];
  __shared__ float shq[3][128];
  int wv = tid >> 6, ln = tid & 63;
  if (wv > 0 && ln < 32) {
#pragma unroll
    for (int j = 0; j < 4; ++j) {
      shs[wv - 1][g * 4 + j] = s[j];
      shq[wv - 1][g * 4 + j] = q[j];
    }
  }
  __syncthreads();
  if (wv == 0 && ln < 32) {
#pragma unroll
    for (int j = 0; j < 4; ++j) {
      int c = g * 4 + j;
      atomicAdd(&sums[c], s[j] + shs[0][c] + shs[1][c] + shs[2][c]);
      atomicAdd(&sqs[c],  q[j] + shq[0][c] + shq[1][c] + shq[2][c]);
    }
  }
}

// ---------- final: BN(out2) + residual ----------
__global__ void final_kernel(float* __restrict__ out, const float* __restrict__ resid,
                             const float* __restrict__ colsum, const float* __restrict__ colsq,
                             const float* __restrict__ gamma, const float* __restrict__ beta,
                             int total) {
  for (int i = blockIdx.x * blockDim.x + threadIdx.x; i < total; i += gridDim.x * blockDim.x) {
    int c = i & 127;
    float mean = colsum[c] * INV_N;
    float sc = bn_scale(colsum[c], colsq[c], gamma[c]);
    float sh = beta[c] - mean * sc;
    out[i] = fmaf(out[i], sc, sh) + resid[i];
  }
}

// ==================== host ====================
extern "C" void kernel_launch(void* const* d_in, const int* in_sizes, int n_in,
                              void* d_out, int out_size, void* d_ws, size_t ws_size,
                              hipStream_t stream) {
  const float* feat    = (const float*)d_in[0];
  const int*   edges   = (const int*)d_in[1];
  const int*   esrc    = edges;
  const int*   edst    = edges + N_EDGES;
  const float* W_heads = (const float*)d_in[2];
  const float* a_heads = (const float*)d_in[3];
  const float* gamma_h = (const float*)d_in[4];
  const float* beta_h  = (const float*)d_in[5];
  const float* W_out   = (const float*)d_in[6];
  const float* a_out   = (const float*)d_in[7];
  const float* gamma_o = (const float*)d_in[8];
  const float* beta_o  = (const float*)d_in[9];
  const float* W_res   = (const float*)d_in[10];
  const float* b_res   = (const float*)d_in[11];
  float* out = (float*)d_out;

  char* ws = (char*)d_ws;
  size_t off = 0;
  auto alloc = [&](size_t bytes) {
    void* p = ws + off;
    off = (off + bytes + 255) & ~(size_t)255;
    return p;
  };
  unsigned short* msg1    = (unsigned short*)alloc((size_t)N_NODES * HDIM * 2);  // reused as msg2
  unsigned short* out1_bf = (unsigned short*)alloc((size_t)N_NODES * HDIM * 2);
  unsigned short* feat_bf = (unsigned short*)alloc((size_t)N_NODES * DIM_IN * 2);
  float*    resid  = (float*)alloc((size_t)N_NODES * DIM_OUT * 4);
  float*    asrc1  = (float*)alloc((size_t)N_NODES * NHEADS * 4); // reused as asrc2
  float*    adst1  = (float*)alloc((size_t)N_NODES * NHEADS * 4); // reused as adst2
  // ---- single zeroed region: counts..colsq2 ----
  int*      counts  = (int*)alloc((size_t)N_NODES * 4);
  int*      cursor  = (int*)alloc((size_t)N_NODES * 4);
  float*    bias2   = (float*)alloc(DIM_OUT * 4);
  float*    colsum1 = (float*)alloc(HDIM * 4);
  float*    colsq1  = (float*)alloc(HDIM * 4);
  float*    colsum2 = (float*)alloc(DIM_OUT * 4);
  float*    colsq2  = (float*)alloc(DIM_OUT * 4);
  int*      rowptr  = (int*)alloc((size_t)(N_NODES + 1) * 4);   // end of zero region
  int*      colsrc  = (int*)alloc((size_t)N_EDGES * 4);
  int*      bsum    = (int*)alloc(64 * 4);
  float*    partmx1 = (float*)alloc((size_t)NBY * 4 * 4 * 4);
  float*    partmx2 = (float*)alloc((size_t)NBY * 2 * 4);
  float*    maxv1   = (float*)alloc(8 * 4);
  float*    maxv2   = (float*)alloc(4);
  unsigned short* Bt1 = (unsigned short*)alloc((size_t)HDIM * DIM_IN * 2);
  unsigned short* Bt2 = (unsigned short*)alloc((size_t)DIM_OUT * HDIM * 2);
  unsigned short* Btr = (unsigned short*)alloc((size_t)DIM_OUT * DIM_IN * 2);
  unsigned short* msg2 = msg1;
  float* asrc2 = asrc1; float* adst2 = adst1;
  (void)n_in; (void)in_sizes; (void)out_size; (void)ws_size;

  hipMemsetAsync(counts, 0, (char*)rowptr - (char*)counts, stream);

  // ---- prep (cvt + packs + hist fused) ----
  prep_kernel<<<6570 + HISTBLK, 256, 0, stream>>>(feat, W_heads, W_res, edst,
                                                  feat_bf, Bt1, Btr, counts);

  // ---- layer 1: GEMM + fused attn + fused nodemax partials ----
  dim3 g1(HDIM / 128, NBY);
  gemm1_attn_kernel<<<g1, 256, 0, stream>>>(feat_bf, Bt1, msg1, a_heads, asrc1, adst1, partmx1);
  nodemax_final_kernel<<<1, 64, 0, stream>>>(partmx1, maxv1, 8, NBY);

  int nsb = (N_NODES + 1023) / 1024;   // 49
  scan1_kernel<<<nsb, 256, 0, stream>>>(counts, rowptr, bsum, N_NODES);
  scan23_kernel<<<nsb, 256, 0, stream>>>(rowptr, bsum, N_NODES);

  scatter_kernel<<<SCBLK, 256, 0, stream>>>(esrc, edst, rowptr, cursor, colsrc, N_EDGES);
  agg1_kernel<<<N_NODES / 4, 256, 0, stream>>>(msg1, asrc1, adst1, maxv1, rowptr, colsrc, out1_bf);

  colstats_bf512_kernel<<<CSBLK, 256, 0, stream>>>(out1_bf, colsum1, colsq1, N_NODES);
  foldw2_kernel<<<DIM_OUT * HDIM / 256, 256, 0, stream>>>(W_out, colsum1, colsq1,
                                                          gamma_h, beta_h, Bt2, bias2);

  // ---- layer 2 (gemm2+attn2+nodemax fused, residual gemm; one launch) ----
  dim3 g2d(1, NBY, 2);
  gemm_dual<<<g2d, 256, 0, stream>>>(out1_bf, Bt2, msg2, bias2, a_out, asrc2, adst2, partmx2,
                                     feat_bf, Btr, resid, b_res);
  nodemax_final_kernel<<<1, 64, 0, stream>>>(partmx2, maxv2, 1, NBY);

  agg2_kernel<<<N_NODES / 4, 256, 0, stream>>>(msg2, asrc2, adst2, maxv2, rowptr, colsrc, out);

  // layer-2 BN stats + fused BN+residual epilogue
  colstats_f128_kernel<<<CSBLK, 256, 0, stream>>>(out, colsum2, colsq2, N_NODES);
  final_kernel<<<2048, 256, 0, stream>>>(out, resid, colsum2, colsq2, gamma_o, beta_o,
                                         N_NODES * DIM_OUT);
}